// Round 1
// baseline (539.928 us; speedup 1.0000x reference)
//
#include <hip/hip_runtime.h>

#define HH 16
#define DH 64
#define DD 1024
#define PP 1024
#define NNLEN 8192
#define BBATCH 2
#define MM (BBATCH*NNLEN)   // 16384 rows
#define CCHUNK 128          // chunks per (b,h)
#define LCH 64              // chunk length
#define EPSV 1e-6f

typedef unsigned short u16;
typedef __attribute__((ext_vector_type(4))) unsigned short u16x4;
typedef __attribute__((ext_vector_type(8))) unsigned short u16x8;
typedef __attribute__((ext_vector_type(8))) __bf16 bf16x8;
typedef __attribute__((ext_vector_type(4))) float f32x4;

__device__ __forceinline__ u16 f2bf(float f) {
  unsigned x = __float_as_uint(f);
  return (u16)((x + 0x7fffu + ((x >> 16) & 1u)) >> 16);
}
__device__ __forceinline__ float bf2f(u16 u) {
  return __uint_as_float(((unsigned)u) << 16);
}

// ---------------------------------------------------------------------------
// f32 -> bf16 elementwise convert (vectorized)
// ---------------------------------------------------------------------------
__global__ __launch_bounds__(256)
void f32_to_bf16_vec(const float* __restrict__ in, u16* __restrict__ out, int n4) {
  int i = blockIdx.x * 256 + threadIdx.x;
  if (i < n4) {
    f32x4 v = *(const f32x4*)(in + (size_t)i * 4);
    u16x4 o;
    o[0] = f2bf(v[0]); o[1] = f2bf(v[1]); o[2] = f2bf(v[2]); o[3] = f2bf(v[3]);
    *(u16x4*)(out + (size_t)i * 4) = o;
  }
}

// ---------------------------------------------------------------------------
// transpose 1024x1024 f32 -> bf16 (out[n][k] = in[k][n])
// ---------------------------------------------------------------------------
__global__ __launch_bounds__(256)
void transpose_f32_bf16(const float* __restrict__ in, u16* __restrict__ out) {
  __shared__ float tile[32][33];
  int bx = blockIdx.x * 32, by = blockIdx.y * 32;
  int tx = threadIdx.x & 31, ty = threadIdx.x >> 5;  // ty 0..7
  for (int i = ty; i < 32; i += 8)
    tile[i][tx] = in[(size_t)(by + i) * 1024 + bx + tx];
  __syncthreads();
  for (int i = ty; i < 32; i += 8)
    out[(size_t)(bx + i) * 1024 + by + tx] = f2bf(tile[tx][i]);
}

// ---------------------------------------------------------------------------
// a = sigmoid(x @ Wa + ba + 2.0)   (M x 16)
// ---------------------------------------------------------------------------
__global__ __launch_bounds__(256)
void compute_a(const float* __restrict__ x, const float* __restrict__ Wa,
               const float* __restrict__ ba, float* __restrict__ abuf) {
  __shared__ __align__(16) float xs[16][64];
  __shared__ __align__(16) float was[64][16];
  const int m0 = blockIdx.x * 16;
  const int tid = threadIdx.x;
  const int rr = tid >> 4, hh = tid & 15;
  float acc = 0.f;
  for (int d0 = 0; d0 < DD; d0 += 64) {
    __syncthreads();
    {
      int row = tid >> 4, col4 = (tid & 15) * 4;
      *(f32x4*)&xs[row][col4] = *(const f32x4*)&x[(size_t)(m0 + row) * DD + d0 + col4];
      int wrow = tid >> 2, wcol4 = (tid & 3) * 4;
      *(f32x4*)&was[wrow][wcol4] = *(const f32x4*)&Wa[(size_t)(d0 + wrow) * HH + wcol4];
    }
    __syncthreads();
#pragma unroll
    for (int dd = 0; dd < 64; ++dd) acc += xs[rr][dd] * was[dd][hh];
  }
  float t = acc + ba[hh] + 2.0f;
  abuf[(size_t)(m0 + rr) * HH + hh] = 1.f / (1.f + __expf(-t));
}

// ---------------------------------------------------------------------------
// bf16 MFMA GEMM: C[M,1024] = A[M,1024] @ B, with Bt = B^T stored N x K.
// 128x128 tile, BK=32, 4 waves, 4x4 16x16x32 fragments per wave.
// ACT=1: elu(x)+1 epilogue. OUTF32=1: f32 output else bf16.
// ---------------------------------------------------------------------------
template<int ACT, int OUTF32>
__global__ __launch_bounds__(256)
void gemm_bt(const u16* __restrict__ A, const u16* __restrict__ Bt,
             void* __restrict__ Cout) {
  __shared__ __align__(16) u16 As[128 * 32];
  __shared__ __align__(16) u16 Bs[128 * 32];
  const int tid = threadIdx.x;
  const int brow = blockIdx.x * 128;
  const int bcol = blockIdx.y * 128;
  const int l = tid & 63;
  const int wid = tid >> 6;
  const int wrow = (wid >> 1) * 64, wcol = (wid & 1) * 64;
  const int sr = tid >> 2;          // staging row 0..63
  const int se = (tid & 3) * 8;     // staging elem offset (u16 units)
  const int K = 1024;

  f32x4 acc[4][4];
#pragma unroll
  for (int i = 0; i < 4; ++i)
#pragma unroll
    for (int j = 0; j < 4; ++j) acc[i][j] = (f32x4){0.f, 0.f, 0.f, 0.f};

  u16x8 a0, a1, b0, b1;
  a0 = *(const u16x8*)(A + (size_t)(brow + sr) * K + se);
  a1 = *(const u16x8*)(A + (size_t)(brow + 64 + sr) * K + se);
  b0 = *(const u16x8*)(Bt + (size_t)(bcol + sr) * K + se);
  b1 = *(const u16x8*)(Bt + (size_t)(bcol + 64 + sr) * K + se);

  const int fa = (wrow + (l & 15)) * 32 + (l >> 4) * 8;
  const int fb = (wcol + (l & 15)) * 32 + (l >> 4) * 8;

  for (int kt = 0; kt < K / 32; ++kt) {
    __syncthreads();
    *(u16x8*)&As[sr * 32 + se] = a0;
    *(u16x8*)&As[(64 + sr) * 32 + se] = a1;
    *(u16x8*)&Bs[sr * 32 + se] = b0;
    *(u16x8*)&Bs[(64 + sr) * 32 + se] = b1;
    __syncthreads();
    if (kt + 1 < K / 32) {
      const int k0 = (kt + 1) * 32;
      a0 = *(const u16x8*)(A + (size_t)(brow + sr) * K + k0 + se);
      a1 = *(const u16x8*)(A + (size_t)(brow + 64 + sr) * K + k0 + se);
      b0 = *(const u16x8*)(Bt + (size_t)(bcol + sr) * K + k0 + se);
      b1 = *(const u16x8*)(Bt + (size_t)(bcol + 64 + sr) * K + k0 + se);
    }
    bf16x8 af[4], bfr[4];
#pragma unroll
    for (int mi = 0; mi < 4; ++mi) {
      union { u16x8 u; bf16x8 b; } cva, cvb;
      cva.u = *(const u16x8*)&As[fa + mi * 16 * 32];
      af[mi] = cva.b;
      cvb.u = *(const u16x8*)&Bs[fb + mi * 16 * 32];
      bfr[mi] = cvb.b;
    }
#pragma unroll
    for (int mi = 0; mi < 4; ++mi)
#pragma unroll
      for (int ni = 0; ni < 4; ++ni)
        acc[mi][ni] = __builtin_amdgcn_mfma_f32_16x16x32_bf16(af[mi], bfr[ni], acc[mi][ni], 0, 0, 0);
  }

#pragma unroll
  for (int mi = 0; mi < 4; ++mi)
#pragma unroll
    for (int ni = 0; ni < 4; ++ni)
#pragma unroll
      for (int rr = 0; rr < 4; ++rr) {
        int row = brow + wrow + mi * 16 + ((l >> 4) << 2) + rr;
        int col = bcol + wcol + ni * 16 + (l & 15);
        float v = acc[mi][ni][rr];
        if (ACT) v = v > 0.f ? v + 1.f : __expf(v);
        if (OUTF32) ((float*)Cout)[(size_t)row * 1024 + col] = v;
        else        ((u16*)Cout)[(size_t)row * 1024 + col] = f2bf(v);
      }
}

// ---------------------------------------------------------------------------
// Kernel A: per-chunk local state.
// Sloc[dk][dv] = sum_t exp(cA[63]-cA[t]) k_t[dk] v_t[dv]; zloc likewise.
// ---------------------------------------------------------------------------
__global__ __launch_bounds__(256)
void chunk_local(const u16* __restrict__ kb, const u16* __restrict__ vb,
                 const float* __restrict__ abuf,
                 float* __restrict__ Sbuf, float* __restrict__ zbuf,
                 float* __restrict__ cAbuf) {
  const int blk = blockIdx.x;
  const int c = blk & (CCHUNK - 1);
  const int h = (blk >> 7) & (HH - 1);
  const int b = blk >> 11;
  const int rowbase = b * NNLEN + c * LCH;
  __shared__ __align__(16) u16 ksh[64][64];
  __shared__ __align__(16) u16 vsh[64][64];
  __shared__ float cA[64];
  __shared__ float wsh[64];
  const int tid = threadIdx.x;
  const int r = tid >> 2, e = (tid & 3) * 16;
  {
    const u16* kp = kb + (size_t)(rowbase + r) * PP + h * DH + e;
    const u16* vp = vb + (size_t)(rowbase + r) * PP + h * DH + e;
    *(u16x8*)&ksh[r][e]     = *(const u16x8*)kp;
    *(u16x8*)&ksh[r][e + 8] = *(const u16x8*)(kp + 8);
    *(u16x8*)&vsh[r][e]     = *(const u16x8*)vp;
    *(u16x8*)&vsh[r][e + 8] = *(const u16x8*)(vp + 8);
  }
  if (tid < 64) cA[tid] = __logf(abuf[(size_t)(rowbase + tid) * HH + h]);
  __syncthreads();
  if (tid == 0) {
    float s = 0.f;
    for (int i = 0; i < 64; ++i) { s += cA[i]; cA[i] = s; }
  }
  __syncthreads();
  if (tid < 64) {
    wsh[tid] = __expf(cA[63] - cA[tid]);
    cAbuf[(size_t)blk * 64 + tid] = cA[tid];
  }
  __syncthreads();

  const int ty = tid >> 4, tx = tid & 15;
  float accS[4][4] = {};
  for (int t = 0; t < 64; ++t) {
    float wt = wsh[t];
    u16x4 ku = *(const u16x4*)&ksh[t][ty * 4];
    u16x4 vu = *(const u16x4*)&vsh[t][tx * 4];
    float kk[4], vv[4];
#pragma unroll
    for (int i = 0; i < 4; ++i) { kk[i] = bf2f(ku[i]) * wt; vv[i] = bf2f(vu[i]); }
#pragma unroll
    for (int i = 0; i < 4; ++i)
#pragma unroll
      for (int j = 0; j < 4; ++j) accS[i][j] += kk[i] * vv[j];
  }
  float* Sc = Sbuf + (size_t)blk * 4096;
#pragma unroll
  for (int i = 0; i < 4; ++i) {
    f32x4 row;
#pragma unroll
    for (int j = 0; j < 4; ++j) row[j] = accS[i][j];
    *(f32x4*)&Sc[(ty * 4 + i) * 64 + tx * 4] = row;
  }
  if (tid < 64) {
    float z = 0.f;
    for (int t = 0; t < 64; ++t) z += wsh[t] * bf2f(ksh[t][tid]);
    zbuf[(size_t)blk * 64 + tid] = z;
  }
}

// ---------------------------------------------------------------------------
// Kernel B: inter-chunk scan (in-place: Sloc -> S_begin).
// grid = B*H*16; each thread owns one state element across all 128 chunks.
// ---------------------------------------------------------------------------
__global__ __launch_bounds__(256)
void chunk_scan(float* __restrict__ Sbuf, float* __restrict__ zbuf,
                const float* __restrict__ cAbuf) {
  const int j = blockIdx.x & 15;
  const int bh = blockIdx.x >> 4;
  const size_t cb = (size_t)bh * CCHUNK;
  const int elem = j * 256 + threadIdx.x;
  const bool doz = (j == 0) && (threadIdx.x < 64);
  float s = 0.f, z = 0.f;
  float loc = Sbuf[cb * 4096 + elem];
  float lz = doz ? zbuf[cb * 64 + threadIdx.x] : 0.f;
  for (int c2 = 0; c2 < CCHUNK; ++c2) {
    const float d = __expf(cAbuf[(cb + c2) * 64 + 63]);
    float nloc = 0.f, nlz = 0.f;
    if (c2 + 1 < CCHUNK) {
      nloc = Sbuf[(cb + c2 + 1) * 4096 + elem];
      if (doz) nlz = zbuf[(cb + c2 + 1) * 64 + threadIdx.x];
    }
    Sbuf[(cb + c2) * 4096 + elem] = s;
    s = d * s + loc; loc = nloc;
    if (doz) {
      zbuf[(cb + c2) * 64 + threadIdx.x] = z;
      z = d * z + lz; lz = nlz;
    }
  }
}

// ---------------------------------------------------------------------------
// Kernel C: per-chunk output.
// O_t = exp(cA[t]) * q_t@S0 + sum_{s<=t} exp(cA[t]-cA[s]) (q_t.k_s) v_s
// den_t = exp(cA[t]) * q_t.z0 + rowsum + eps ; out = O/den (bf16, in-place q)
// ---------------------------------------------------------------------------
__global__ __launch_bounds__(256)
void chunk_out(u16* __restrict__ qb, const u16* __restrict__ kb,
               const u16* __restrict__ vb, const float* __restrict__ Sbuf,
               const float* __restrict__ zbuf, const float* __restrict__ cAbuf) {
  const int blk = blockIdx.x;
  const int c = blk & (CCHUNK - 1);
  const int h = (blk >> 7) & (HH - 1);
  const int b = blk >> 11;
  const int rowbase = b * NNLEN + c * LCH;
  __shared__ __align__(16) float qT[64][64];   // qT[d][t]
  __shared__ __align__(16) u16   kT[64][64];   // kT[d][s] (bf16)
  __shared__ __align__(16) u16   vsh[64][64];  // vsh[s][dv] (bf16)
  __shared__ __align__(16) float PT[64][64];   // PT[s][t]
  __shared__ float cA[64], esh[64], zsh[64], den[64];
  const int tid = threadIdx.x;
  const int r = tid >> 2, e = (tid & 3) * 16;
  {
    const u16* qp = qb + (size_t)(rowbase + r) * PP + h * DH + e;
    const u16* kp = kb + (size_t)(rowbase + r) * PP + h * DH + e;
    const u16* vp = vb + (size_t)(rowbase + r) * PP + h * DH + e;
    u16x8 q0 = *(const u16x8*)qp, q1 = *(const u16x8*)(qp + 8);
    u16x8 k0 = *(const u16x8*)kp, k1 = *(const u16x8*)(kp + 8);
#pragma unroll
    for (int jj = 0; jj < 8; ++jj) {
      qT[e + jj][r] = bf2f(q0[jj]); qT[e + 8 + jj][r] = bf2f(q1[jj]);
      kT[e + jj][r] = k0[jj];       kT[e + 8 + jj][r] = k1[jj];
    }
    *(u16x8*)&vsh[r][e]     = *(const u16x8*)vp;
    *(u16x8*)&vsh[r][e + 8] = *(const u16x8*)(vp + 8);
  }
  if (tid < 64) {
    float ca = cAbuf[(size_t)blk * 64 + tid];
    cA[tid] = ca; esh[tid] = __expf(ca);
    zsh[tid] = zbuf[(size_t)blk * 64 + tid];
  }
  __syncthreads();

  const int ty = tid >> 4, tx = tid & 15;
  const float* S0 = Sbuf + (size_t)blk * 4096;

  // step 1: acc = Q @ S0 (S0 streamed from global)
  float acc[4][4] = {};
  for (int dk = 0; dk < 64; ++dk) {
    f32x4 qq = *(const f32x4*)&qT[dk][ty * 4];
    f32x4 ss = *(const f32x4*)&S0[dk * 64 + tx * 4];
#pragma unroll
    for (int i = 0; i < 4; ++i)
#pragma unroll
      for (int j = 0; j < 4; ++j) acc[i][j] += qq[i] * ss[j];
  }

  // step 2: P = maskdecay(Q K^T), stored transposed PT[s][t]
  float pacc[4][4] = {};
  for (int d = 0; d < 64; ++d) {
    f32x4 qq = *(const f32x4*)&qT[d][ty * 4];
    u16x4 ku = *(const u16x4*)&kT[d][tx * 4];
    float kk[4];
#pragma unroll
    for (int j = 0; j < 4; ++j) kk[j] = bf2f(ku[j]);
#pragma unroll
    for (int i = 0; i < 4; ++i)
#pragma unroll
      for (int j = 0; j < 4; ++j) pacc[i][j] += qq[i] * kk[j];
  }
  {
    float cat[4], cas[4];
#pragma unroll
    for (int i = 0; i < 4; ++i) cat[i] = cA[ty * 4 + i];
#pragma unroll
    for (int j = 0; j < 4; ++j) cas[j] = cA[tx * 4 + j];
#pragma unroll
    for (int j = 0; j < 4; ++j) {
      f32x4 col;
#pragma unroll
      for (int i = 0; i < 4; ++i) {
        int t = ty * 4 + i, s = tx * 4 + j;
        col[i] = (s <= t) ? pacc[i][j] * __expf(cat[i] - cas[j]) : 0.f;
      }
      *(f32x4*)&PT[tx * 4 + j][ty * 4] = col;
    }
  }
  __syncthreads();

  // step 3: den
  if (tid < 64) {
    float qz = 0.f;
    for (int d = 0; d < 64; ++d) qz += qT[d][tid] * zsh[d];
    float dsum = esh[tid] * qz + EPSV;
    for (int s = 0; s < 64; ++s) dsum += PT[s][tid];
    den[tid] = dsum;
  }
  __syncthreads();

  // step 4: O = e[t]*acc + P@V ; out = O/den
  float et[4], dn[4];
#pragma unroll
  for (int i = 0; i < 4; ++i) { et[i] = esh[ty * 4 + i]; dn[i] = den[ty * 4 + i]; }
#pragma unroll
  for (int i = 0; i < 4; ++i)
#pragma unroll
    for (int j = 0; j < 4; ++j) acc[i][j] *= et[i];
  for (int s = 0; s < 64; ++s) {
    f32x4 pv = *(const f32x4*)&PT[s][ty * 4];
    u16x4 vu = *(const u16x4*)&vsh[s][tx * 4];
    float vv[4];
#pragma unroll
    for (int j = 0; j < 4; ++j) vv[j] = bf2f(vu[j]);
#pragma unroll
    for (int i = 0; i < 4; ++i)
#pragma unroll
      for (int j = 0; j < 4; ++j) acc[i][j] += pv[i] * vv[j];
  }
#pragma unroll
  for (int i = 0; i < 4; ++i) {
    u16x4 o;
#pragma unroll
    for (int j = 0; j < 4; ++j) o[j] = f2bf(acc[i][j] / dn[i]);
    *(u16x4*)&qb[(size_t)(rowbase + ty * 4 + i) * PP + h * DH + tx * 4] = o;
  }
}

// ---------------------------------------------------------------------------
extern "C" void kernel_launch(void* const* d_in, const int* in_sizes, int n_in,
                              void* d_out, int out_size, void* d_ws, size_t ws_size,
                              hipStream_t stream) {
  const float* x  = (const float*)d_in[0];
  const float* Wq = (const float*)d_in[1];
  const float* Wk = (const float*)d_in[2];
  const float* Wv = (const float*)d_in[3];
  const float* Wo = (const float*)d_in[4];
  const float* Wa = (const float*)d_in[5];
  const float* ba = (const float*)d_in[6];

  char* ws = (char*)d_ws;
  size_t off = 0;
  auto carve = [&](size_t bytes) {
    void* p = ws + off;
    off += (bytes + 255) & ~(size_t)255;
    return p;
  };
  u16* xb   = (u16*)carve((size_t)MM * DD * 2);
  u16* WqT  = (u16*)carve((size_t)PP * DD * 2);
  u16* WkT  = (u16*)carve((size_t)PP * DD * 2);
  u16* WvT  = (u16*)carve((size_t)PP * DD * 2);
  u16* WoT  = (u16*)carve((size_t)DD * PP * 2);
  u16* qb   = (u16*)carve((size_t)MM * PP * 2);
  u16* kb   = (u16*)carve((size_t)MM * PP * 2);
  u16* vb   = (u16*)carve((size_t)MM * PP * 2);
  float* abuf  = (float*)carve((size_t)MM * HH * 4);
  float* Sbuf  = (float*)carve((size_t)BBATCH * HH * CCHUNK * 4096 * 4);
  float* zbuf  = (float*)carve((size_t)BBATCH * HH * CCHUNK * 64 * 4);
  float* cAbuf = (float*)carve((size_t)BBATCH * HH * CCHUNK * 64 * 4);

  f32_to_bf16_vec<<<(MM * DD / 4 + 255) / 256, 256, 0, stream>>>(x, xb, MM * DD / 4);
  transpose_f32_bf16<<<dim3(32, 32), 256, 0, stream>>>(Wq, WqT);
  transpose_f32_bf16<<<dim3(32, 32), 256, 0, stream>>>(Wk, WkT);
  transpose_f32_bf16<<<dim3(32, 32), 256, 0, stream>>>(Wv, WvT);
  transpose_f32_bf16<<<dim3(32, 32), 256, 0, stream>>>(Wo, WoT);
  compute_a<<<MM / 16, 256, 0, stream>>>(x, Wa, ba, abuf);

  gemm_bt<1, 0><<<dim3(MM / 128, PP / 128), 256, 0, stream>>>(xb, WqT, qb);
  gemm_bt<1, 0><<<dim3(MM / 128, PP / 128), 256, 0, stream>>>(xb, WkT, kb);
  gemm_bt<0, 0><<<dim3(MM / 128, PP / 128), 256, 0, stream>>>(xb, WvT, vb);

  chunk_local<<<BBATCH * HH * CCHUNK, 256, 0, stream>>>(kb, vb, abuf, Sbuf, zbuf, cAbuf);
  chunk_scan<<<BBATCH * HH * 16, 256, 0, stream>>>(Sbuf, zbuf, cAbuf);
  chunk_out<<<BBATCH * HH * CCHUNK, 256, 0, stream>>>(qb, kb, vb, Sbuf, zbuf, cAbuf);

  gemm_bt<0, 1><<<dim3(MM / 128, DD / 128), 256, 0, stream>>>(qb, WoT, (float*)d_out);
}

// Round 2
// 437.791 us; speedup vs baseline: 1.2333x; 1.2333x over previous
//
#include <hip/hip_runtime.h>
#include <stdint.h>

#define HH 16
#define DH 64
#define DD 1024
#define PP 1024
#define NNLEN 8192
#define BBATCH 2
#define MM (BBATCH*NNLEN)   // 16384 rows
#define CCHUNK 128          // chunks per (b,h)
#define LCH 64              // chunk length
#define EPSV 1e-6f

typedef unsigned short u16;
typedef __attribute__((ext_vector_type(4))) unsigned short u16x4;
typedef __attribute__((ext_vector_type(8))) unsigned short u16x8;
typedef __attribute__((ext_vector_type(8))) __bf16 bf16x8;
typedef __attribute__((ext_vector_type(4))) float f32x4;

__device__ __forceinline__ u16 f2bf(float f) {
  unsigned x = __float_as_uint(f);
  return (u16)((x + 0x7fffu + ((x >> 16) & 1u)) >> 16);
}
__device__ __forceinline__ float bf2f(u16 u) {
  return __uint_as_float(((unsigned)u) << 16);
}

// async global->LDS, 16B per lane. LDS dest must be wave-uniform base.
__device__ __forceinline__ void gl2lds16(const void* g, void* l) {
  __builtin_amdgcn_global_load_lds(
      reinterpret_cast<__attribute__((address_space(1))) void*>(
          reinterpret_cast<uintptr_t>(g)),
      reinterpret_cast<__attribute__((address_space(3))) void*>(
          reinterpret_cast<uintptr_t>(l)),
      16, 0, 0);
}

// swizzled LDS read of a bf16x8 fragment from a [64][64] u16 tile.
// byte ^= ((row&7)<<4)  <=>  u16 col ^= ((row&7)<<3) on the 8-granule.
__device__ __forceinline__ bf16x8 ldsw(const u16* base, int row, int col) {
  union { u16x8 u; bf16x8 b; } cv;
  cv.u = *(const u16x8*)&base[row * 64 + (col ^ ((row & 7) << 3))];
  return cv.b;
}

// ---------------------------------------------------------------------------
// f32 -> bf16 elementwise convert (vectorized)
// ---------------------------------------------------------------------------
__global__ __launch_bounds__(256)
void f32_to_bf16_vec(const float* __restrict__ in, u16* __restrict__ out, int n4) {
  int i = blockIdx.x * 256 + threadIdx.x;
  if (i < n4) {
    f32x4 v = *(const f32x4*)(in + (size_t)i * 4);
    u16x4 o;
    o[0] = f2bf(v[0]); o[1] = f2bf(v[1]); o[2] = f2bf(v[2]); o[3] = f2bf(v[3]);
    *(u16x4*)(out + (size_t)i * 4) = o;
  }
}

// ---------------------------------------------------------------------------
// transpose 1024x1024 f32 -> bf16 (out[n][k] = in[k][n])
// ---------------------------------------------------------------------------
__global__ __launch_bounds__(256)
void transpose_f32_bf16(const float* __restrict__ in, u16* __restrict__ out) {
  __shared__ float tile[32][33];
  int bx = blockIdx.x * 32, by = blockIdx.y * 32;
  int tx = threadIdx.x & 31, ty = threadIdx.x >> 5;  // ty 0..7
  for (int i = ty; i < 32; i += 8)
    tile[i][tx] = in[(size_t)(by + i) * 1024 + bx + tx];
  __syncthreads();
  for (int i = ty; i < 32; i += 8)
    out[(size_t)(bx + i) * 1024 + by + tx] = f2bf(tile[tx][i]);
}

// ---------------------------------------------------------------------------
// a = sigmoid(x @ Wa + ba + 2.0)   (M x 16)
// ---------------------------------------------------------------------------
__global__ __launch_bounds__(256)
void compute_a(const float* __restrict__ x, const float* __restrict__ Wa,
               const float* __restrict__ ba, float* __restrict__ abuf) {
  __shared__ __align__(16) float xs[16][64];
  __shared__ __align__(16) float was[64][16];
  const int m0 = blockIdx.x * 16;
  const int tid = threadIdx.x;
  const int rr = tid >> 4, hh = tid & 15;
  float acc = 0.f;
  for (int d0 = 0; d0 < DD; d0 += 64) {
    __syncthreads();
    {
      int row = tid >> 4, col4 = (tid & 15) * 4;
      *(f32x4*)&xs[row][col4] = *(const f32x4*)&x[(size_t)(m0 + row) * DD + d0 + col4];
      int wrow = tid >> 2, wcol4 = (tid & 3) * 4;
      *(f32x4*)&was[wrow][wcol4] = *(const f32x4*)&Wa[(size_t)(d0 + wrow) * HH + wcol4];
    }
    __syncthreads();
#pragma unroll
    for (int dd = 0; dd < 64; ++dd) acc += xs[rr][dd] * was[dd][hh];
  }
  float t = acc + ba[hh] + 2.0f;
  abuf[(size_t)(m0 + rr) * HH + hh] = 1.f / (1.f + __expf(-t));
}

// ---------------------------------------------------------------------------
// bf16 MFMA GEMM (m97 structure): 128x128 tile, BK=32, global_load_lds x16B.
// ---------------------------------------------------------------------------
template<int ACT, int OUTF32>
__global__ __launch_bounds__(256)
void gemm_bt(const u16* __restrict__ A, const u16* __restrict__ Bt,
             void* __restrict__ Cout) {
  __shared__ __align__(16) u16 As[128 * 32];
  __shared__ __align__(16) u16 Bs[128 * 32];
  const int tid = threadIdx.x;
  const int brow = blockIdx.x * 128;
  const int bcol = blockIdx.y * 128;
  const int l = tid & 63;
  const int wid = tid >> 6;
  const int wrow = (wid >> 1) * 64, wcol = (wid & 1) * 64;
  const int sr = tid >> 2;          // staging row 0..63
  const int se = (tid & 3) * 8;     // staging elem offset (u16 units)
  const int K = 1024;
  const int wb = wid * 512;         // wave-uniform LDS base (u16 units)

  f32x4 acc[4][4];
#pragma unroll
  for (int i = 0; i < 4; ++i)
#pragma unroll
    for (int j = 0; j < 4; ++j) acc[i][j] = (f32x4){0.f, 0.f, 0.f, 0.f};

  const int fa = (wrow + (l & 15)) * 32 + (l >> 4) * 8;
  const int fb = (wcol + (l & 15)) * 32 + (l >> 4) * 8;

  const u16* a0p = A + (size_t)(brow + sr) * K + se;
  const u16* a1p = A + (size_t)(brow + 64 + sr) * K + se;
  const u16* b0p = Bt + (size_t)(bcol + sr) * K + se;
  const u16* b1p = Bt + (size_t)(bcol + 64 + sr) * K + se;

  for (int kt = 0; kt < K / 32; ++kt) {
    const int k0 = kt * 32;
    __syncthreads();                 // prior ds_reads done before overwrite
    gl2lds16(a0p + k0, &As[wb]);
    gl2lds16(a1p + k0, &As[2048 + wb]);
    gl2lds16(b0p + k0, &Bs[wb]);
    gl2lds16(b1p + k0, &Bs[2048 + wb]);
    __syncthreads();                 // implicit vmcnt(0) drain -> LDS valid
    bf16x8 af[4], bfr[4];
#pragma unroll
    for (int mi = 0; mi < 4; ++mi) {
      union { u16x8 u; bf16x8 b; } cva, cvb;
      cva.u = *(const u16x8*)&As[fa + mi * 512];
      af[mi] = cva.b;
      cvb.u = *(const u16x8*)&Bs[fb + mi * 512];
      bfr[mi] = cvb.b;
    }
#pragma unroll
    for (int mi = 0; mi < 4; ++mi)
#pragma unroll
      for (int ni = 0; ni < 4; ++ni)
        acc[mi][ni] = __builtin_amdgcn_mfma_f32_16x16x32_bf16(af[mi], bfr[ni], acc[mi][ni], 0, 0, 0);
  }

#pragma unroll
  for (int mi = 0; mi < 4; ++mi)
#pragma unroll
    for (int ni = 0; ni < 4; ++ni)
#pragma unroll
      for (int rr = 0; rr < 4; ++rr) {
        int row = brow + wrow + mi * 16 + ((l >> 4) << 2) + rr;
        int col = bcol + wcol + ni * 16 + (l & 15);
        float v = acc[mi][ni][rr];
        if (ACT) v = v > 0.f ? v + 1.f : __expf(v);
        if (OUTF32) ((float*)Cout)[(size_t)row * 1024 + col] = v;
        else        ((u16*)Cout)[(size_t)row * 1024 + col] = f2bf(v);
      }
}

// ---------------------------------------------------------------------------
// Kernel A (MFMA): per-chunk local state, stored TRANSPOSED:
// S^T[dv][dk] = sum_t v[t][dv] * (w_t k[t][dk]),  w_t = exp(cA[63]-cA[t])
// z[dk] = sum_t w_t k[t][dk]
// Also computes cA (wave-parallel prefix scan) and writes cAbuf.
// ---------------------------------------------------------------------------
__global__ __launch_bounds__(256)
void chunk_local(const u16* __restrict__ kb, const u16* __restrict__ vb,
                 const float* __restrict__ abuf,
                 float* __restrict__ Sbuf, float* __restrict__ zbuf,
                 float* __restrict__ cAbuf) {
  const int blk = blockIdx.x;
  const int c = blk & (CCHUNK - 1);
  const int h = (blk >> 7) & (HH - 1);
  const int b = blk >> 11;
  const int rowbase = b * NNLEN + c * LCH;
  __shared__ __align__(16) u16 KT[64 * 64];   // KT[dk][t] = w_t*k (swizzled)
  __shared__ __align__(16) u16 VTl[64 * 64];  // VTl[dv][t] (swizzled)
  __shared__ float wsh[64];
  const int tid = threadIdx.x;
  const int r = tid >> 2, e = (tid & 3) * 16;

  const u16* kp = kb + (size_t)(rowbase + r) * PP + h * DH + e;
  const u16* vp = vb + (size_t)(rowbase + r) * PP + h * DH + e;
  u16x8 k0 = *(const u16x8*)kp, k1 = *(const u16x8*)(kp + 8);
  u16x8 v0 = *(const u16x8*)vp, v1 = *(const u16x8*)(vp + 8);

  if (tid < 64) {
    float v = __logf(abuf[(size_t)(rowbase + tid) * HH + h]);
#pragma unroll
    for (int d = 1; d < 64; d <<= 1) {
      float u = __shfl_up(v, d);
      if (tid >= d) v += u;
    }
    cAbuf[(size_t)blk * 64 + tid] = v;
    float tot = __shfl(v, 63);
    wsh[tid] = __expf(tot - v);
  }
  __syncthreads();

  {
    const float wt = wsh[r];
#pragma unroll
    for (int j = 0; j < 8; ++j) {
      int d0 = e + j, d1 = e + 8 + j;
      KT[d0 * 64 + (r ^ ((d0 & 7) << 3))] = f2bf(bf2f(k0[j]) * wt);
      KT[d1 * 64 + (r ^ ((d1 & 7) << 3))] = f2bf(bf2f(k1[j]) * wt);
      VTl[d0 * 64 + (r ^ ((d0 & 7) << 3))] = v0[j];
      VTl[d1 * 64 + (r ^ ((d1 & 7) << 3))] = v1[j];
    }
  }
  __syncthreads();

  const int l = tid & 63, w = tid >> 6;
  const int kb8 = (l >> 4) << 3, la = l & 15;
  f32x4 s[4];
#pragma unroll
  for (int ni = 0; ni < 4; ++ni) s[ni] = (f32x4){0.f, 0.f, 0.f, 0.f};
#pragma unroll
  for (int kk = 0; kk < 2; ++kk) {
    bf16x8 av = ldsw(VTl, 16 * w + la, kk * 32 + kb8);
#pragma unroll
    for (int ni = 0; ni < 4; ++ni)
      s[ni] = __builtin_amdgcn_mfma_f32_16x16x32_bf16(
          av, ldsw(KT, 16 * ni + la, kk * 32 + kb8), s[ni], 0, 0, 0);
  }
  float* Sc = Sbuf + (size_t)blk * 4096;
  const int dw = 16 * w + ((l >> 4) << 2);
#pragma unroll
  for (int ni = 0; ni < 4; ++ni)
#pragma unroll
    for (int rr = 0; rr < 4; ++rr)
      Sc[(dw + rr) * 64 + 16 * ni + la] = s[ni][rr];

  {
    const int dk = tid >> 2, tq = (tid & 3) * 16, swk = (dk & 7) << 3;
    float zp = 0.f;
#pragma unroll
    for (int i = 0; i < 16; ++i) zp += bf2f(KT[dk * 64 + ((tq + i) ^ swk)]);
    zp += __shfl_xor(zp, 1);
    zp += __shfl_xor(zp, 2);
    if ((tid & 3) == 0) zbuf[(size_t)blk * 64 + dk] = zp;
  }
}

// ---------------------------------------------------------------------------
// Kernel B: inter-chunk scan (in-place: Sloc -> S_begin). Layout-agnostic.
// ---------------------------------------------------------------------------
__global__ __launch_bounds__(256)
void chunk_scan(float* __restrict__ Sbuf, float* __restrict__ zbuf,
                const float* __restrict__ cAbuf) {
  const int j = blockIdx.x & 15;
  const int bh = blockIdx.x >> 4;
  const size_t cb = (size_t)bh * CCHUNK;
  const int elem = j * 256 + threadIdx.x;
  const bool doz = (j == 0) && (threadIdx.x < 64);
  float s = 0.f, z = 0.f;
  float loc = Sbuf[cb * 4096 + elem];
  float lz = doz ? zbuf[cb * 64 + threadIdx.x] : 0.f;
  for (int c2 = 0; c2 < CCHUNK; ++c2) {
    const float d = __expf(cAbuf[(cb + c2) * 64 + 63]);
    float nloc = 0.f, nlz = 0.f;
    if (c2 + 1 < CCHUNK) {
      nloc = Sbuf[(cb + c2 + 1) * 4096 + elem];
      if (doz) nlz = zbuf[(cb + c2 + 1) * 64 + threadIdx.x];
    }
    Sbuf[(cb + c2) * 4096 + elem] = s;
    s = d * s + loc; loc = nloc;
    if (doz) {
      zbuf[(cb + c2) * 64 + threadIdx.x] = z;
      z = d * z + lz; lz = nlz;
    }
  }
}

// ---------------------------------------------------------------------------
// Kernel C (MFMA): per-chunk output.
// Decay folded into operands around c0 = cA[31]:
//   Qe[t][d] = q*e^{cA[t]-c0}, Ke[s][d] = k*e^{c0-cA[s]},
//   S0e^T = S^T*e^{c0},        z0e = z0*e^{c0}
//   P = mask(Qe@Ke^T);  O = P@V + Qe@S0e^T;  den = rowsum(P) + Qe.z0e + eps
//   out = O/den  (bf16, in-place over q)
// ---------------------------------------------------------------------------
__global__ __launch_bounds__(256)
void chunk_out(u16* __restrict__ qb, const u16* __restrict__ kb,
               const u16* __restrict__ vb, const float* __restrict__ Sbuf,
               const float* __restrict__ zbuf, const float* __restrict__ cAbuf) {
  const int blk = blockIdx.x;
  const int c = blk & (CCHUNK - 1);
  const int h = (blk >> 7) & (HH - 1);
  const int b = blk >> 11;
  const int rowbase = b * NNLEN + c * LCH;

  __shared__ __align__(16) u16 Qs[64 * 64];   // Qe[t][d]   swizzled
  __shared__ __align__(16) u16 Ke[64 * 64];   // Ke[s][d]   swizzled
  __shared__ __align__(16) u16 VT[64 * 64];   // V^T[dv][s] swizzled
  __shared__ __align__(16) u16 STs[64 * 64];  // S0e^T[dv][dk] bf16 swizzled
  __shared__ __align__(16) u16 Pb[64 * 64];   // P[t][s] bf16 swizzled
  __shared__ float cAsh[64], zsh[64], denP[64], qzs[64];

  const int tid = threadIdx.x;
  const int r = tid >> 2, e = (tid & 3) * 16;

  const u16* qp = qb + (size_t)(rowbase + r) * PP + h * DH + e;
  const u16* kp = kb + (size_t)(rowbase + r) * PP + h * DH + e;
  const u16* vp = vb + (size_t)(rowbase + r) * PP + h * DH + e;
  u16x8 q0 = *(const u16x8*)qp, q1 = *(const u16x8*)(qp + 8);
  u16x8 k0 = *(const u16x8*)kp, k1 = *(const u16x8*)(kp + 8);
  u16x8 v0 = *(const u16x8*)vp, v1 = *(const u16x8*)(vp + 8);
  const float* sp = Sbuf + (size_t)blk * 4096 + r * 64 + e;
  f32x4 s0 = *(const f32x4*)sp, s1 = *(const f32x4*)(sp + 4),
        s2 = *(const f32x4*)(sp + 8), s3 = *(const f32x4*)(sp + 12);
  if (tid < 64) {
    cAsh[tid] = cAbuf[(size_t)blk * 64 + tid];
    zsh[tid] = zbuf[(size_t)blk * 64 + tid];
  }
  __syncthreads();

  {
    const float c0 = cAsh[31];
    const int sw = (r & 7) << 3;
    const float qsc = __expf(cAsh[r] - c0);
    const float ksc = __expf(c0 - cAsh[r]);
    const float ssc = __expf(c0);
    u16x8 t0, t1, u0, u1, w0, w1;
#pragma unroll
    for (int j = 0; j < 8; ++j) {
      t0[j] = f2bf(bf2f(q0[j]) * qsc);
      t1[j] = f2bf(bf2f(q1[j]) * qsc);
      u0[j] = f2bf(bf2f(k0[j]) * ksc);
      u1[j] = f2bf(bf2f(k1[j]) * ksc);
    }
#pragma unroll
    for (int j = 0; j < 4; ++j) {
      w0[j]     = f2bf(s0[j] * ssc);
      w0[4 + j] = f2bf(s1[j] * ssc);
      w1[j]     = f2bf(s2[j] * ssc);
      w1[4 + j] = f2bf(s3[j] * ssc);
    }
    *(u16x8*)&Qs[r * 64 + (e ^ sw)] = t0;
    *(u16x8*)&Qs[r * 64 + ((e + 8) ^ sw)] = t1;
    *(u16x8*)&Ke[r * 64 + (e ^ sw)] = u0;
    *(u16x8*)&Ke[r * 64 + ((e + 8) ^ sw)] = u1;
    *(u16x8*)&STs[r * 64 + (e ^ sw)] = w0;
    *(u16x8*)&STs[r * 64 + ((e + 8) ^ sw)] = w1;
#pragma unroll
    for (int j = 0; j < 8; ++j) {
      int d0 = e + j, d1 = e + 8 + j;
      VT[d0 * 64 + (r ^ ((d0 & 7) << 3))] = v0[j];
      VT[d1 * 64 + (r ^ ((d1 & 7) << 3))] = v1[j];
    }
    if (tid < 64) zsh[tid] *= ssc;
  }
  __syncthreads();

  const int l = tid & 63, w = tid >> 6;
  const int kb8 = (l >> 4) << 3, la = l & 15;

  // --- MFMA1: P = Qe @ Ke^T ---
  bf16x8 aq[2];
  f32x4 p[4];
#pragma unroll
  for (int ni = 0; ni < 4; ++ni) p[ni] = (f32x4){0.f, 0.f, 0.f, 0.f};
#pragma unroll
  for (int kk = 0; kk < 2; ++kk) {
    aq[kk] = ldsw(Qs, 16 * w + la, kk * 32 + kb8);
#pragma unroll
    for (int ni = 0; ni < 4; ++ni)
      p[ni] = __builtin_amdgcn_mfma_f32_16x16x32_bf16(
          aq[kk], ldsw(Ke, 16 * ni + la, kk * 32 + kb8), p[ni], 0, 0, 0);
  }

  // mask + rowsum
  const int tw = 16 * w + ((l >> 4) << 2);
  float rsum[4] = {0.f, 0.f, 0.f, 0.f};
#pragma unroll
  for (int ni = 0; ni < 4; ++ni)
#pragma unroll
    for (int rr = 0; rr < 4; ++rr) {
      int s = 16 * ni + la, t = tw + rr;
      float v = (s <= t) ? p[ni][rr] : 0.f;
      p[ni][rr] = v;
      rsum[rr] += v;
    }
#pragma unroll
  for (int d = 1; d < 16; d <<= 1)
#pragma unroll
    for (int rr = 0; rr < 4; ++rr) rsum[rr] += __shfl_xor(rsum[rr], d);
  if (la == 0)
#pragma unroll
    for (int rr = 0; rr < 4; ++rr) denP[tw + rr] = rsum[rr];

  // write P (bf16, swizzled)
#pragma unroll
  for (int ni = 0; ni < 4; ++ni)
#pragma unroll
    for (int rr = 0; rr < 4; ++rr) {
      int t = tw + rr, s = 16 * ni + la;
      Pb[t * 64 + (s ^ ((t & 7) << 3))] = f2bf(p[ni][rr]);
    }

  // qz[t] = Qe[t] . z0e   (VALU, overlaps with MFMA phase)
  {
    const int tq = tid >> 2, dq = (tid & 3) * 16, swq = (tq & 7) << 3;
    float qzp = 0.f;
#pragma unroll
    for (int i = 0; i < 16; ++i)
      qzp += bf2f(Qs[tq * 64 + ((dq + i) ^ swq)]) * zsh[dq + i];
    qzp += __shfl_xor(qzp, 1);
    qzp += __shfl_xor(qzp, 2);
    if ((tid & 3) == 0) qzs[tq] = qzp;
  }
  __syncthreads();

  // --- MFMA2: O = P@V + Qe@S0e^T ---
  f32x4 o[4];
#pragma unroll
  for (int ni = 0; ni < 4; ++ni) o[ni] = (f32x4){0.f, 0.f, 0.f, 0.f};
#pragma unroll
  for (int kk = 0; kk < 2; ++kk) {
    bf16x8 ap = ldsw(Pb, 16 * w + la, kk * 32 + kb8);
#pragma unroll
    for (int ni = 0; ni < 4; ++ni)
      o[ni] = __builtin_amdgcn_mfma_f32_16x16x32_bf16(
          ap, ldsw(VT, 16 * ni + la, kk * 32 + kb8), o[ni], 0, 0, 0);
  }
#pragma unroll
  for (int kk = 0; kk < 2; ++kk)
#pragma unroll
    for (int ni = 0; ni < 4; ++ni)
      o[ni] = __builtin_amdgcn_mfma_f32_16x16x32_bf16(
          aq[kk], ldsw(STs, 16 * ni + la, kk * 32 + kb8), o[ni], 0, 0, 0);

  // epilogue
  float dn[4];
#pragma unroll
  for (int rr = 0; rr < 4; ++rr) dn[rr] = qzs[tw + rr] + denP[tw + rr] + EPSV;
#pragma unroll
  for (int ni = 0; ni < 4; ++ni)
#pragma unroll
    for (int rr = 0; rr < 4; ++rr) {
      int t = tw + rr, dv = 16 * ni + la;
      qb[(size_t)(rowbase + t) * PP + h * DH + dv] = f2bf(o[ni][rr] / dn[rr]);
    }
}

// ---------------------------------------------------------------------------
extern "C" void kernel_launch(void* const* d_in, const int* in_sizes, int n_in,
                              void* d_out, int out_size, void* d_ws, size_t ws_size,
                              hipStream_t stream) {
  const float* x  = (const float*)d_in[0];
  const float* Wq = (const float*)d_in[1];
  const float* Wk = (const float*)d_in[2];
  const float* Wv = (const float*)d_in[3];
  const float* Wo = (const float*)d_in[4];
  const float* Wa = (const float*)d_in[5];
  const float* ba = (const float*)d_in[6];

  char* ws = (char*)d_ws;
  size_t off = 0;
  auto carve = [&](size_t bytes) {
    void* p = ws + off;
    off += (bytes + 255) & ~(size_t)255;
    return p;
  };
  u16* xb   = (u16*)carve((size_t)MM * DD * 2);
  u16* WqT  = (u16*)carve((size_t)PP * DD * 2);
  u16* WkT  = (u16*)carve((size_t)PP * DD * 2);
  u16* WvT  = (u16*)carve((size_t)PP * DD * 2);
  u16* WoT  = (u16*)carve((size_t)DD * PP * 2);
  u16* qb   = (u16*)carve((size_t)MM * PP * 2);
  u16* kb   = (u16*)carve((size_t)MM * PP * 2);
  u16* vb   = (u16*)carve((size_t)MM * PP * 2);
  float* abuf  = (float*)carve((size_t)MM * HH * 4);
  float* Sbuf  = (float*)carve((size_t)BBATCH * HH * CCHUNK * 4096 * 4);
  float* zbuf  = (float*)carve((size_t)BBATCH * HH * CCHUNK * 64 * 4);
  float* cAbuf = (float*)carve((size_t)BBATCH * HH * CCHUNK * 64 * 4);

  f32_to_bf16_vec<<<(MM * DD / 4 + 255) / 256, 256, 0, stream>>>(x, xb, MM * DD / 4);
  transpose_f32_bf16<<<dim3(32, 32), 256, 0, stream>>>(Wq, WqT);
  transpose_f32_bf16<<<dim3(32, 32), 256, 0, stream>>>(Wk, WkT);
  transpose_f32_bf16<<<dim3(32, 32), 256, 0, stream>>>(Wv, WvT);
  transpose_f32_bf16<<<dim3(32, 32), 256, 0, stream>>>(Wo, WoT);
  compute_a<<<MM / 16, 256, 0, stream>>>(x, Wa, ba, abuf);

  gemm_bt<1, 0><<<dim3(MM / 128, PP / 128), 256, 0, stream>>>(xb, WqT, qb);
  gemm_bt<1, 0><<<dim3(MM / 128, PP / 128), 256, 0, stream>>>(xb, WkT, kb);
  gemm_bt<0, 0><<<dim3(MM / 128, PP / 128), 256, 0, stream>>>(xb, WvT, vb);

  chunk_local<<<BBATCH * HH * CCHUNK, 256, 0, stream>>>(kb, vb, abuf, Sbuf, zbuf, cAbuf);
  chunk_scan<<<BBATCH * HH * 16, 256, 0, stream>>>(Sbuf, zbuf, cAbuf);
  chunk_out<<<BBATCH * HH * CCHUNK, 256, 0, stream>>>(qb, kb, vb, Sbuf, zbuf, cAbuf);

  gemm_bt<0, 1><<<dim3(MM / 128, DD / 128), 256, 0, stream>>>(qb, WoT, (float*)d_out);
}

// Round 3
// 354.517 us; speedup vs baseline: 1.5230x; 1.2349x over previous
//
#include <hip/hip_runtime.h>
#include <stdint.h>

#define HH 16
#define DH 64
#define DD 1024
#define PP 1024
#define NNLEN 8192
#define BBATCH 2
#define MM (BBATCH*NNLEN)   // 16384 rows
#define CCHUNK 128          // chunks per (b,h)
#define LCH 64              // chunk length
#define NGRP 16             // scan groups per (b,h)
#define GCH 8               // chunks per group
#define EPSV 1e-6f

typedef unsigned short u16;
typedef __attribute__((ext_vector_type(4))) unsigned short u16x4;
typedef __attribute__((ext_vector_type(8))) unsigned short u16x8;
typedef __attribute__((ext_vector_type(8))) __bf16 bf16x8;
typedef __attribute__((ext_vector_type(4))) float f32x4;

__device__ __forceinline__ u16 f2bf(float f) {
  unsigned x = __float_as_uint(f);
  return (u16)((x + 0x7fffu + ((x >> 16) & 1u)) >> 16);
}
__device__ __forceinline__ float bf2f(u16 u) {
  return __uint_as_float(((unsigned)u) << 16);
}

// async global->LDS, 16B per lane. LDS dest must be wave-uniform base.
__device__ __forceinline__ void gl2lds16(const void* g, void* l) {
  __builtin_amdgcn_global_load_lds(
      reinterpret_cast<__attribute__((address_space(1))) void*>(
          reinterpret_cast<uintptr_t>(g)),
      reinterpret_cast<__attribute__((address_space(3))) void*>(
          reinterpret_cast<uintptr_t>(l)),
      16, 0, 0);
}

// swizzled LDS read of a bf16x8 fragment from a [64][64] u16 tile.
// byte ^= ((row&7)<<4)  <=>  u16 col ^= ((row&7)<<3) on the 8-granule.
__device__ __forceinline__ bf16x8 ldsw(const u16* base, int row, int col) {
  union { u16x8 u; bf16x8 b; } cv;
  cv.u = *(const u16x8*)&base[row * 64 + (col ^ ((row & 7) << 3))];
  return cv.b;
}

// ---------------------------------------------------------------------------
// transpose 1024x1024 f32 -> bf16 (out[n][k] = in[k][n])
// ---------------------------------------------------------------------------
__global__ __launch_bounds__(256)
void transpose_f32_bf16(const float* __restrict__ in, u16* __restrict__ out) {
  __shared__ float tile[32][33];
  int bx = blockIdx.x * 32, by = blockIdx.y * 32;
  int tx = threadIdx.x & 31, ty = threadIdx.x >> 5;  // ty 0..7
  for (int i = ty; i < 32; i += 8)
    tile[i][tx] = in[(size_t)(by + i) * 1024 + bx + tx];
  __syncthreads();
  for (int i = ty; i < 32; i += 8)
    out[(size_t)(bx + i) * 1024 + by + tx] = f2bf(tile[tx][i]);
}

// ---------------------------------------------------------------------------
// a = sigmoid(x @ Wa + ba + 2.0)   (M x 16)  + fused x f32->bf16 conversion
// ---------------------------------------------------------------------------
__global__ __launch_bounds__(256)
void compute_a(const float* __restrict__ x, const float* __restrict__ Wa,
               const float* __restrict__ ba, float* __restrict__ abuf,
               u16* __restrict__ xb) {
  __shared__ __align__(16) float xs[16][64];
  __shared__ __align__(16) float was[64][16];
  const int m0 = blockIdx.x * 16;
  const int tid = threadIdx.x;
  const int rr = tid >> 4, hh = tid & 15;
  float acc = 0.f;
  for (int d0 = 0; d0 < DD; d0 += 64) {
    __syncthreads();
    {
      int row = tid >> 4, col4 = (tid & 15) * 4;
      f32x4 xv = *(const f32x4*)&x[(size_t)(m0 + row) * DD + d0 + col4];
      *(f32x4*)&xs[row][col4] = xv;
      u16x4 o;
      o[0] = f2bf(xv[0]); o[1] = f2bf(xv[1]); o[2] = f2bf(xv[2]); o[3] = f2bf(xv[3]);
      *(u16x4*)&xb[(size_t)(m0 + row) * DD + d0 + col4] = o;
      int wrow = tid >> 2, wcol4 = (tid & 3) * 4;
      *(f32x4*)&was[wrow][wcol4] = *(const f32x4*)&Wa[(size_t)(d0 + wrow) * HH + wcol4];
    }
    __syncthreads();
#pragma unroll
    for (int dd = 0; dd < 64; ++dd) acc += xs[rr][dd] * was[dd][hh];
  }
  float t = acc + ba[hh] + 2.0f;
  abuf[(size_t)(m0 + rr) * HH + hh] = 1.f / (1.f + __expf(-t));
}

// ---------------------------------------------------------------------------
// bf16 MFMA GEMM (m97 structure): 128x128 tile, BK=32, global_load_lds x16B.
// 1D grid + XCD-aware swizzle (nwg%8==0): each XCD owns contiguous row-blocks
// with the 8 col-blocks adjacent -> A fetched once, B L2-resident.
// ---------------------------------------------------------------------------
template<int ACT, int OUTF32>
__global__ __launch_bounds__(256)
void gemm_bt(const u16* __restrict__ A, const u16* __restrict__ Bt,
             void* __restrict__ Cout) {
  __shared__ __align__(16) u16 As[128 * 32];
  __shared__ __align__(16) u16 Bs[128 * 32];
  const int tid = threadIdx.x;
  const int nwg = gridDim.x;
  const int f = blockIdx.x;
  const int swz = (f & 7) * (nwg >> 3) + (f >> 3);
  const int brow = (swz >> 3) * 128;
  const int bcol = (swz & 7) * 128;
  const int l = tid & 63;
  const int wid = tid >> 6;
  const int wrow = (wid >> 1) * 64, wcol = (wid & 1) * 64;
  const int sr = tid >> 2;          // staging row 0..63
  const int se = (tid & 3) * 8;     // staging elem offset (u16 units)
  const int K = 1024;
  const int wb = wid * 512;         // wave-uniform LDS base (u16 units)

  f32x4 acc[4][4];
#pragma unroll
  for (int i = 0; i < 4; ++i)
#pragma unroll
    for (int j = 0; j < 4; ++j) acc[i][j] = (f32x4){0.f, 0.f, 0.f, 0.f};

  const int fa = (wrow + (l & 15)) * 32 + (l >> 4) * 8;
  const int fb = (wcol + (l & 15)) * 32 + (l >> 4) * 8;

  const u16* a0p = A + (size_t)(brow + sr) * K + se;
  const u16* a1p = A + (size_t)(brow + 64 + sr) * K + se;
  const u16* b0p = Bt + (size_t)(bcol + sr) * K + se;
  const u16* b1p = Bt + (size_t)(bcol + 64 + sr) * K + se;

  for (int kt = 0; kt < K / 32; ++kt) {
    const int k0 = kt * 32;
    __syncthreads();                 // prior ds_reads done before overwrite
    gl2lds16(a0p + k0, &As[wb]);
    gl2lds16(a1p + k0, &As[2048 + wb]);
    gl2lds16(b0p + k0, &Bs[wb]);
    gl2lds16(b1p + k0, &Bs[2048 + wb]);
    __syncthreads();                 // implicit vmcnt(0) drain -> LDS valid
    bf16x8 af[4], bfr[4];
#pragma unroll
    for (int mi = 0; mi < 4; ++mi) {
      union { u16x8 u; bf16x8 b; } cva, cvb;
      cva.u = *(const u16x8*)&As[fa + mi * 512];
      af[mi] = cva.b;
      cvb.u = *(const u16x8*)&Bs[fb + mi * 512];
      bfr[mi] = cvb.b;
    }
#pragma unroll
    for (int mi = 0; mi < 4; ++mi)
#pragma unroll
      for (int ni = 0; ni < 4; ++ni)
        acc[mi][ni] = __builtin_amdgcn_mfma_f32_16x16x32_bf16(af[mi], bfr[ni], acc[mi][ni], 0, 0, 0);
  }

#pragma unroll
  for (int mi = 0; mi < 4; ++mi)
#pragma unroll
    for (int ni = 0; ni < 4; ++ni)
#pragma unroll
      for (int rr = 0; rr < 4; ++rr) {
        int row = brow + wrow + mi * 16 + ((l >> 4) << 2) + rr;
        int col = bcol + wcol + ni * 16 + (l & 15);
        float v = acc[mi][ni][rr];
        if (ACT) v = v > 0.f ? v + 1.f : __expf(v);
        if (OUTF32) ((float*)Cout)[(size_t)row * 1024 + col] = v;
        else        ((u16*)Cout)[(size_t)row * 1024 + col] = f2bf(v);
      }
}

// ---------------------------------------------------------------------------
// Kernel A (MFMA): per-chunk local state, stored TRANSPOSED in bf16:
// S^T[dv][dk] = sum_t v[t][dv] * (w_t k[t][dk]),  w_t = exp(cA[63]-cA[t])
// z[dk] = sum_t w_t k[t][dk]
// ---------------------------------------------------------------------------
__global__ __launch_bounds__(256)
void chunk_local(const u16* __restrict__ kb, const u16* __restrict__ vb,
                 const float* __restrict__ abuf,
                 u16* __restrict__ Sbuf, float* __restrict__ zbuf,
                 float* __restrict__ cAbuf) {
  const int blk = blockIdx.x;
  const int c = blk & (CCHUNK - 1);
  const int h = (blk >> 7) & (HH - 1);
  const int b = blk >> 11;
  const int rowbase = b * NNLEN + c * LCH;
  __shared__ __align__(16) u16 KT[64 * 64];   // KT[dk][t] = w_t*k (swizzled)
  __shared__ __align__(16) u16 VTl[64 * 64];  // VTl[dv][t] (swizzled)
  __shared__ float wsh[64];
  const int tid = threadIdx.x;
  const int r = tid >> 2, e = (tid & 3) * 16;

  const u16* kp = kb + (size_t)(rowbase + r) * PP + h * DH + e;
  const u16* vp = vb + (size_t)(rowbase + r) * PP + h * DH + e;
  u16x8 k0 = *(const u16x8*)kp, k1 = *(const u16x8*)(kp + 8);
  u16x8 v0 = *(const u16x8*)vp, v1 = *(const u16x8*)(vp + 8);

  if (tid < 64) {
    float v = __logf(abuf[(size_t)(rowbase + tid) * HH + h]);
#pragma unroll
    for (int d = 1; d < 64; d <<= 1) {
      float u = __shfl_up(v, d);
      if (tid >= d) v += u;
    }
    cAbuf[(size_t)blk * 64 + tid] = v;
    float tot = __shfl(v, 63);
    wsh[tid] = __expf(tot - v);
  }
  __syncthreads();

  {
    const float wt = wsh[r];
#pragma unroll
    for (int j = 0; j < 8; ++j) {
      int d0 = e + j, d1 = e + 8 + j;
      KT[d0 * 64 + (r ^ ((d0 & 7) << 3))] = f2bf(bf2f(k0[j]) * wt);
      KT[d1 * 64 + (r ^ ((d1 & 7) << 3))] = f2bf(bf2f(k1[j]) * wt);
      VTl[d0 * 64 + (r ^ ((d0 & 7) << 3))] = v0[j];
      VTl[d1 * 64 + (r ^ ((d1 & 7) << 3))] = v1[j];
    }
  }
  __syncthreads();

  const int l = tid & 63, w = tid >> 6;
  const int kb8 = (l >> 4) << 3, la = l & 15;
  f32x4 s[4];
#pragma unroll
  for (int ni = 0; ni < 4; ++ni) s[ni] = (f32x4){0.f, 0.f, 0.f, 0.f};
#pragma unroll
  for (int kk = 0; kk < 2; ++kk) {
    bf16x8 av = ldsw(VTl, 16 * w + la, kk * 32 + kb8);
#pragma unroll
    for (int ni = 0; ni < 4; ++ni)
      s[ni] = __builtin_amdgcn_mfma_f32_16x16x32_bf16(
          av, ldsw(KT, 16 * ni + la, kk * 32 + kb8), s[ni], 0, 0, 0);
  }
  u16* Sc = Sbuf + (size_t)blk * 4096;
  const int dw = 16 * w + ((l >> 4) << 2);
#pragma unroll
  for (int ni = 0; ni < 4; ++ni)
#pragma unroll
    for (int rr = 0; rr < 4; ++rr)
      Sc[(dw + rr) * 64 + 16 * ni + la] = f2bf(s[ni][rr]);

  {
    const int dk = tid >> 2, tq = (tid & 3) * 16, swk = (dk & 7) << 3;
    float zp = 0.f;
#pragma unroll
    for (int i = 0; i < 16; ++i) zp += bf2f(KT[dk * 64 + ((tq + i) ^ swk)]);
    zp += __shfl_xor(zp, 1);
    zp += __shfl_xor(zp, 2);
    if ((tid & 3) == 0) zbuf[(size_t)blk * 64 + dk] = zp;
  }
}

// ---------------------------------------------------------------------------
// Scan level 1: within-group (GCH=8 chunks) prefix, in place over Sbuf/zbuf.
// Writes group aggregates (f32) + per-chunk within-group begin-decay dp.
// grid = bh(32) * group(16) * jsplit(4)
// ---------------------------------------------------------------------------
__global__ __launch_bounds__(256)
void scan_group(u16* __restrict__ Sbuf, float* __restrict__ zbuf,
                const float* __restrict__ cAbuf,
                float* __restrict__ GAgg, float* __restrict__ zGAgg,
                float* __restrict__ dpbuf) {
  const int j = blockIdx.x & 3;
  const int g = (blockIdx.x >> 2) & (NGRP - 1);
  const int bh = blockIdx.x >> 6;
  const int c0 = g * GCH;
  const size_t cb = (size_t)bh * CCHUNK;
  const int elem = j * 1024 + threadIdx.x * 4;

  float dch[GCH];
#pragma unroll
  for (int i = 0; i < GCH; ++i)
    dch[i] = __expf(cAbuf[(cb + c0 + i) * 64 + 63]);
  if (j == 0 && threadIdx.x == 0) {
    float rp = 1.f;
#pragma unroll
    for (int i = 0; i < GCH; ++i) { dpbuf[cb + c0 + i] = rp; rp *= dch[i]; }
  }

  f32x4 run = (f32x4){0.f, 0.f, 0.f, 0.f};
  u16x4 cur = *(const u16x4*)&Sbuf[(cb + c0) * 4096 + elem];
#pragma unroll
  for (int i = 0; i < GCH; ++i) {
    u16x4 nxt;
    if (i + 1 < GCH) nxt = *(const u16x4*)&Sbuf[(cb + c0 + i + 1) * 4096 + elem];
    u16x4 o;
#pragma unroll
    for (int jj = 0; jj < 4; ++jj) o[jj] = f2bf(run[jj]);
    *(u16x4*)&Sbuf[(cb + c0 + i) * 4096 + elem] = o;
#pragma unroll
    for (int jj = 0; jj < 4; ++jj) run[jj] = dch[i] * run[jj] + bf2f(cur[jj]);
    cur = nxt;
  }
  *(f32x4*)&GAgg[((size_t)bh * NGRP + g) * 4096 + elem] = run;

  if (j == 0 && threadIdx.x < 64) {
    const int t = threadIdx.x;
    float zr = 0.f;
#pragma unroll
    for (int i = 0; i < GCH; ++i) {
      float curz = zbuf[(cb + c0 + i) * 64 + t];
      zbuf[(cb + c0 + i) * 64 + t] = zr;
      zr = dch[i] * zr + curz;
    }
    zGAgg[((size_t)bh * NGRP + g) * 64 + t] = zr;
  }
}

// ---------------------------------------------------------------------------
// Scan level 2: across the 16 group aggregates, in place (GAgg -> Gbegin).
// grid = 32 (one block per bh), 1024 threads * f32x4.
// ---------------------------------------------------------------------------
__global__ __launch_bounds__(1024)
void scan_top(float* __restrict__ GAgg, float* __restrict__ zGAgg,
              const float* __restrict__ cAbuf) {
  const int bh = blockIdx.x;
  const size_t cb = (size_t)bh * CCHUNK;
  __shared__ float Dsh[NGRP];
  if (threadIdx.x < NGRP) {
    float s = 0.f;
#pragma unroll
    for (int i = 0; i < GCH; ++i)
      s += cAbuf[(cb + threadIdx.x * GCH + i) * 64 + 63];
    Dsh[threadIdx.x] = __expf(s);
  }
  __syncthreads();
  const int elem = threadIdx.x * 4;
  float* base = GAgg + (size_t)bh * NGRP * 4096;
  f32x4 run = (f32x4){0.f, 0.f, 0.f, 0.f};
  f32x4 cur = *(const f32x4*)&base[elem];
#pragma unroll
  for (int gg = 0; gg < NGRP; ++gg) {
    f32x4 nxt;
    if (gg + 1 < NGRP) nxt = *(const f32x4*)&base[(gg + 1) * 4096 + elem];
    *(f32x4*)&base[gg * 4096 + elem] = run;
    const float D = Dsh[gg];
#pragma unroll
    for (int jj = 0; jj < 4; ++jj) run[jj] = D * run[jj] + cur[jj];
    cur = nxt;
  }
  if (threadIdx.x < 64) {
    float* zb = zGAgg + (size_t)bh * NGRP * 64;
    float zr = 0.f;
#pragma unroll
    for (int gg = 0; gg < NGRP; ++gg) {
      float a = zb[gg * 64 + threadIdx.x];
      zb[gg * 64 + threadIdx.x] = zr;
      zr = Dsh[gg] * zr + a;
    }
  }
}

// ---------------------------------------------------------------------------
// Kernel C (MFMA): per-chunk output.
// S0 = prefix(bf16) + dp * Gbegin(f32);  z0 = zprefix + dp * zGbegin
// Decay folded into operands around c0 = cA[31].
// ---------------------------------------------------------------------------
__global__ __launch_bounds__(256)
void chunk_out(u16* __restrict__ qb, const u16* __restrict__ kb,
               const u16* __restrict__ vb, const u16* __restrict__ Sbuf,
               const float* __restrict__ zbuf, const float* __restrict__ cAbuf,
               const float* __restrict__ GAgg, const float* __restrict__ zGAgg,
               const float* __restrict__ dpbuf) {
  const int blk = blockIdx.x;
  const int c = blk & (CCHUNK - 1);
  const int h = (blk >> 7) & (HH - 1);
  const int b = blk >> 11;
  const int bh = blk >> 7;
  const int g = c >> 3;
  const int rowbase = b * NNLEN + c * LCH;

  __shared__ __align__(16) u16 Qs[64 * 64];   // Qe[t][d]   swizzled
  __shared__ __align__(16) u16 Ke[64 * 64];   // Ke[s][d]   swizzled
  __shared__ __align__(16) u16 VT[64 * 64];   // V^T[dv][s] swizzled
  __shared__ __align__(16) u16 STs[64 * 64];  // S0e^T[dv][dk] bf16 swizzled
  __shared__ __align__(16) u16 Pb[64 * 64];   // P[t][s] bf16 swizzled
  __shared__ float cAsh[64], zsh[64], denP[64], qzs[64];

  const int tid = threadIdx.x;
  const int r = tid >> 2, e = (tid & 3) * 16;
  const float dp = dpbuf[blk];

  const u16* qp = qb + (size_t)(rowbase + r) * PP + h * DH + e;
  const u16* kp = kb + (size_t)(rowbase + r) * PP + h * DH + e;
  const u16* vp = vb + (size_t)(rowbase + r) * PP + h * DH + e;
  u16x8 q0 = *(const u16x8*)qp, q1 = *(const u16x8*)(qp + 8);
  u16x8 k0 = *(const u16x8*)kp, k1 = *(const u16x8*)(kp + 8);
  u16x8 v0 = *(const u16x8*)vp, v1 = *(const u16x8*)(vp + 8);
  const u16* sp = Sbuf + (size_t)blk * 4096 + r * 64 + e;
  u16x8 p0 = *(const u16x8*)sp, p1 = *(const u16x8*)(sp + 8);
  const float* gp = GAgg + ((size_t)bh * NGRP + g) * 4096 + r * 64 + e;
  f32x4 g0 = *(const f32x4*)gp, g1 = *(const f32x4*)(gp + 4),
        g2 = *(const f32x4*)(gp + 8), g3 = *(const f32x4*)(gp + 12);
  if (tid < 64) {
    cAsh[tid] = cAbuf[(size_t)blk * 64 + tid];
    zsh[tid] = zbuf[(size_t)blk * 64 + tid]
             + dp * zGAgg[((size_t)bh * NGRP + g) * 64 + tid];
  }
  __syncthreads();

  {
    const float c0c = cAsh[31];
    const int sw = (r & 7) << 3;
    const float qsc = __expf(cAsh[r] - c0c);
    const float ksc = __expf(c0c - cAsh[r]);
    const float ssc = __expf(c0c);
    u16x8 t0, t1, u0, u1, w0, w1;
#pragma unroll
    for (int j = 0; j < 8; ++j) {
      t0[j] = f2bf(bf2f(q0[j]) * qsc);
      t1[j] = f2bf(bf2f(q1[j]) * qsc);
      u0[j] = f2bf(bf2f(k0[j]) * ksc);
      u1[j] = f2bf(bf2f(k1[j]) * ksc);
    }
#pragma unroll
    for (int j = 0; j < 4; ++j) {
      w0[j]     = f2bf((bf2f(p0[j])     + dp * g0[j]) * ssc);
      w0[4 + j] = f2bf((bf2f(p0[4 + j]) + dp * g1[j]) * ssc);
      w1[j]     = f2bf((bf2f(p1[j])     + dp * g2[j]) * ssc);
      w1[4 + j] = f2bf((bf2f(p1[4 + j]) + dp * g3[j]) * ssc);
    }
    *(u16x8*)&Qs[r * 64 + (e ^ sw)] = t0;
    *(u16x8*)&Qs[r * 64 + ((e + 8) ^ sw)] = t1;
    *(u16x8*)&Ke[r * 64 + (e ^ sw)] = u0;
    *(u16x8*)&Ke[r * 64 + ((e + 8) ^ sw)] = u1;
    *(u16x8*)&STs[r * 64 + (e ^ sw)] = w0;
    *(u16x8*)&STs[r * 64 + ((e + 8) ^ sw)] = w1;
#pragma unroll
    for (int j = 0; j < 8; ++j) {
      int d0 = e + j, d1 = e + 8 + j;
      VT[d0 * 64 + (r ^ ((d0 & 7) << 3))] = v0[j];
      VT[d1 * 64 + (r ^ ((d1 & 7) << 3))] = v1[j];
    }
    if (tid < 64) zsh[tid] *= ssc;
  }
  __syncthreads();

  const int l = tid & 63, w = tid >> 6;
  const int kb8 = (l >> 4) << 3, la = l & 15;

  // --- MFMA1: P = Qe @ Ke^T ---
  bf16x8 aq[2];
  f32x4 p[4];
#pragma unroll
  for (int ni = 0; ni < 4; ++ni) p[ni] = (f32x4){0.f, 0.f, 0.f, 0.f};
#pragma unroll
  for (int kk = 0; kk < 2; ++kk) {
    aq[kk] = ldsw(Qs, 16 * w + la, kk * 32 + kb8);
#pragma unroll
    for (int ni = 0; ni < 4; ++ni)
      p[ni] = __builtin_amdgcn_mfma_f32_16x16x32_bf16(
          aq[kk], ldsw(Ke, 16 * ni + la, kk * 32 + kb8), p[ni], 0, 0, 0);
  }

  // mask + rowsum
  const int tw = 16 * w + ((l >> 4) << 2);
  float rsum[4] = {0.f, 0.f, 0.f, 0.f};
#pragma unroll
  for (int ni = 0; ni < 4; ++ni)
#pragma unroll
    for (int rr = 0; rr < 4; ++rr) {
      int s = 16 * ni + la, t = tw + rr;
      float v = (s <= t) ? p[ni][rr] : 0.f;
      p[ni][rr] = v;
      rsum[rr] += v;
    }
#pragma unroll
  for (int d = 1; d < 16; d <<= 1)
#pragma unroll
    for (int rr = 0; rr < 4; ++rr) rsum[rr] += __shfl_xor(rsum[rr], d);
  if (la == 0)
#pragma unroll
    for (int rr = 0; rr < 4; ++rr) denP[tw + rr] = rsum[rr];

  // write P (bf16, swizzled)
#pragma unroll
  for (int ni = 0; ni < 4; ++ni)
#pragma unroll
    for (int rr = 0; rr < 4; ++rr) {
      int t = tw + rr, s = 16 * ni + la;
      Pb[t * 64 + (s ^ ((t & 7) << 3))] = f2bf(p[ni][rr]);
    }

  // qz[t] = Qe[t] . z0e
  {
    const int tq = tid >> 2, dq = (tid & 3) * 16, swq = (tq & 7) << 3;
    float qzp = 0.f;
#pragma unroll
    for (int i = 0; i < 16; ++i)
      qzp += bf2f(Qs[tq * 64 + ((dq + i) ^ swq)]) * zsh[dq + i];
    qzp += __shfl_xor(qzp, 1);
    qzp += __shfl_xor(qzp, 2);
    if ((tid & 3) == 0) qzs[tq] = qzp;
  }
  __syncthreads();

  // --- MFMA2: O = P@V + Qe@S0e^T ---
  f32x4 o[4];
#pragma unroll
  for (int ni = 0; ni < 4; ++ni) o[ni] = (f32x4){0.f, 0.f, 0.f, 0.f};
#pragma unroll
  for (int kk = 0; kk < 2; ++kk) {
    bf16x8 ap = ldsw(Pb, 16 * w + la, kk * 32 + kb8);
#pragma unroll
    for (int ni = 0; ni < 4; ++ni)
      o[ni] = __builtin_amdgcn_mfma_f32_16x16x32_bf16(
          ap, ldsw(VT, 16 * ni + la, kk * 32 + kb8), o[ni], 0, 0, 0);
  }
#pragma unroll
  for (int kk = 0; kk < 2; ++kk)
#pragma unroll
    for (int ni = 0; ni < 4; ++ni)
      o[ni] = __builtin_amdgcn_mfma_f32_16x16x32_bf16(
          aq[kk], ldsw(STs, 16 * ni + la, kk * 32 + kb8), o[ni], 0, 0, 0);

  // epilogue
  float dn[4];
#pragma unroll
  for (int rr = 0; rr < 4; ++rr) dn[rr] = qzs[tw + rr] + denP[tw + rr] + EPSV;
#pragma unroll
  for (int ni = 0; ni < 4; ++ni)
#pragma unroll
    for (int rr = 0; rr < 4; ++rr) {
      int t = tw + rr, dv = 16 * ni + la;
      qb[(size_t)(rowbase + t) * PP + h * DH + dv] = f2bf(o[ni][rr] / dn[rr]);
    }
}

// ---------------------------------------------------------------------------
extern "C" void kernel_launch(void* const* d_in, const int* in_sizes, int n_in,
                              void* d_out, int out_size, void* d_ws, size_t ws_size,
                              hipStream_t stream) {
  const float* x  = (const float*)d_in[0];
  const float* Wq = (const float*)d_in[1];
  const float* Wk = (const float*)d_in[2];
  const float* Wv = (const float*)d_in[3];
  const float* Wo = (const float*)d_in[4];
  const float* Wa = (const float*)d_in[5];
  const float* ba = (const float*)d_in[6];

  char* ws = (char*)d_ws;
  size_t off = 0;
  auto carve = [&](size_t bytes) {
    void* p = ws + off;
    off += (bytes + 255) & ~(size_t)255;
    return p;
  };
  u16* xb   = (u16*)carve((size_t)MM * DD * 2);
  u16* WqT  = (u16*)carve((size_t)PP * DD * 2);
  u16* WkT  = (u16*)carve((size_t)PP * DD * 2);
  u16* WvT  = (u16*)carve((size_t)PP * DD * 2);
  u16* WoT  = (u16*)carve((size_t)DD * PP * 2);
  u16* qb   = (u16*)carve((size_t)MM * PP * 2);
  u16* kb   = (u16*)carve((size_t)MM * PP * 2);
  u16* vb   = (u16*)carve((size_t)MM * PP * 2);
  float* abuf  = (float*)carve((size_t)MM * HH * 4);
  u16*  Sbuf   = (u16*)carve((size_t)BBATCH * HH * CCHUNK * 4096 * 2);
  float* zbuf  = (float*)carve((size_t)BBATCH * HH * CCHUNK * 64 * 4);
  float* cAbuf = (float*)carve((size_t)BBATCH * HH * CCHUNK * 64 * 4);
  float* GAgg  = (float*)carve((size_t)BBATCH * HH * NGRP * 4096 * 4);
  float* zGAgg = (float*)carve((size_t)BBATCH * HH * NGRP * 64 * 4);
  float* dpbuf = (float*)carve((size_t)BBATCH * HH * CCHUNK * 4);

  transpose_f32_bf16<<<dim3(32, 32), 256, 0, stream>>>(Wq, WqT);
  transpose_f32_bf16<<<dim3(32, 32), 256, 0, stream>>>(Wk, WkT);
  transpose_f32_bf16<<<dim3(32, 32), 256, 0, stream>>>(Wv, WvT);
  transpose_f32_bf16<<<dim3(32, 32), 256, 0, stream>>>(Wo, WoT);
  compute_a<<<MM / 16, 256, 0, stream>>>(x, Wa, ba, abuf, xb);

  gemm_bt<1, 0><<<(MM / 128) * (PP / 128), 256, 0, stream>>>(xb, WqT, qb);
  gemm_bt<1, 0><<<(MM / 128) * (PP / 128), 256, 0, stream>>>(xb, WkT, kb);
  gemm_bt<0, 0><<<(MM / 128) * (PP / 128), 256, 0, stream>>>(xb, WvT, vb);

  chunk_local<<<BBATCH * HH * CCHUNK, 256, 0, stream>>>(kb, vb, abuf, Sbuf, zbuf, cAbuf);
  scan_group<<<BBATCH * HH * NGRP * 4, 256, 0, stream>>>(Sbuf, zbuf, cAbuf, GAgg, zGAgg, dpbuf);
  scan_top<<<BBATCH * HH, 1024, 0, stream>>>(GAgg, zGAgg, cAbuf);
  chunk_out<<<BBATCH * HH * CCHUNK, 256, 0, stream>>>(qb, kb, vb, Sbuf, zbuf, cAbuf,
                                                      GAgg, zGAgg, dpbuf);

  gemm_bt<0, 1><<<(MM / 128) * (DD / 128), 256, 0, stream>>>(qb, WoT, (float*)d_out);
}

// Round 4
// 325.378 us; speedup vs baseline: 1.6594x; 1.0896x over previous
//
#include <hip/hip_runtime.h>
#include <stdint.h>

#define HH 16
#define DH 64
#define DD 1024
#define PP 1024
#define NNLEN 8192
#define BBATCH 2
#define MM (BBATCH*NNLEN)   // 16384 rows
#define CCHUNK 128          // chunks per (b,h)
#define LCH 64              // chunk length
#define NGRP 16             // scan groups per (b,h)
#define GCH 8               // chunks per group
#define EPSV 1e-6f

typedef unsigned short u16;
typedef __attribute__((ext_vector_type(4))) unsigned short u16x4;
typedef __attribute__((ext_vector_type(8))) unsigned short u16x8;
typedef __attribute__((ext_vector_type(8))) __bf16 bf16x8;
typedef __attribute__((ext_vector_type(4))) float f32x4;

__device__ __forceinline__ u16 f2bf(float f) {
  unsigned x = __float_as_uint(f);
  return (u16)((x + 0x7fffu + ((x >> 16) & 1u)) >> 16);
}
__device__ __forceinline__ float bf2f(u16 u) {
  return __uint_as_float(((unsigned)u) << 16);
}

// async global->LDS, 16B per lane. LDS dest must be wave-uniform base.
__device__ __forceinline__ void gl2lds16(const void* g, void* l) {
  __builtin_amdgcn_global_load_lds(
      reinterpret_cast<__attribute__((address_space(1))) void*>(
          reinterpret_cast<uintptr_t>(g)),
      reinterpret_cast<__attribute__((address_space(3))) void*>(
          reinterpret_cast<uintptr_t>(l)),
      16, 0, 0);
}

// swizzled LDS read of a bf16x8 fragment from a [64][64] u16 tile.
__device__ __forceinline__ bf16x8 ldsw(const u16* base, int row, int col) {
  union { u16x8 u; bf16x8 b; } cv;
  cv.u = *(const u16x8*)&base[row * 64 + (col ^ ((row & 7) << 3))];
  return cv.b;
}

// ---------------------------------------------------------------------------
// x f32 -> bf16, pure streaming (8 elems/thread)
// ---------------------------------------------------------------------------
__global__ __launch_bounds__(256)
void convert_x(const float* __restrict__ in, u16* __restrict__ out) {
  size_t i = ((size_t)blockIdx.x * 256 + threadIdx.x) * 8;
  f32x4 a = *(const f32x4*)(in + i);
  f32x4 b = *(const f32x4*)(in + i + 4);
  u16x8 o;
  o[0] = f2bf(a[0]); o[1] = f2bf(a[1]); o[2] = f2bf(a[2]); o[3] = f2bf(a[3]);
  o[4] = f2bf(b[0]); o[5] = f2bf(b[1]); o[6] = f2bf(b[2]); o[7] = f2bf(b[3]);
  *(u16x8*)(out + i) = o;
}

// Wa[1024][16] f32 -> WaT[16][1024] bf16
__global__ __launch_bounds__(256)
void wa_prep(const float* __restrict__ Wa, u16* __restrict__ WaT) {
  int idx = blockIdx.x * 256 + threadIdx.x;  // 16384
  WaT[idx] = f2bf(Wa[(idx & 1023) * 16 + (idx >> 10)]);
}

// ---------------------------------------------------------------------------
// transpose 1024x1024 f32 -> bf16 (out[n][k] = in[k][n])
// ---------------------------------------------------------------------------
__global__ __launch_bounds__(256)
void transpose_f32_bf16(const float* __restrict__ in, u16* __restrict__ out) {
  __shared__ float tile[32][33];
  int bx = blockIdx.x * 32, by = blockIdx.y * 32;
  int tx = threadIdx.x & 31, ty = threadIdx.x >> 5;  // ty 0..7
  for (int i = ty; i < 32; i += 8)
    tile[i][tx] = in[(size_t)(by + i) * 1024 + bx + tx];
  __syncthreads();
  for (int i = ty; i < 32; i += 8)
    out[(size_t)(bx + i) * 1024 + by + tx] = f2bf(tile[tx][i]);
}

// ---------------------------------------------------------------------------
// a_proj (MFMA skinny GEMM): abuf = sigmoid(xb @ Wa + ba + 2), M=16384 N=16
// block = 256 thr (4 waves), BM=256, BK=32.
// ---------------------------------------------------------------------------
__global__ __launch_bounds__(256)
void a_proj(const u16* __restrict__ xb, const u16* __restrict__ WaT,
            const float* __restrict__ ba, float* __restrict__ abuf) {
  __shared__ __align__(16) u16 As[256 * 32];
  __shared__ __align__(16) u16 Bs[16 * 32];
  const int tid = threadIdx.x;
  const int brow = blockIdx.x * 256;
  const int l = tid & 63, wid = tid >> 6;
  const int la = l & 15, kb8 = (l >> 4) * 8;
  const int sr = tid >> 2, se = (tid & 3) * 8;

  f32x4 acc[4];
#pragma unroll
  for (int mi = 0; mi < 4; ++mi) acc[mi] = (f32x4){0.f, 0.f, 0.f, 0.f};

  for (int kt = 0; kt < 32; ++kt) {
    const int k0 = kt * 32;
    __syncthreads();
#pragma unroll
    for (int i = 0; i < 4; ++i)
      gl2lds16(xb + (size_t)(brow + i * 64 + sr) * DD + k0 + se,
               &As[i * 2048 + wid * 512]);
    if (wid == 0)
      gl2lds16(WaT + (size_t)(l >> 2) * DD + k0 + (l & 3) * 8, &Bs[0]);
    __syncthreads();
    union { u16x8 u; bf16x8 b; } cvb;
    cvb.u = *(const u16x8*)&Bs[la * 32 + kb8];
#pragma unroll
    for (int mi = 0; mi < 4; ++mi) {
      union { u16x8 u; bf16x8 b; } cva;
      cva.u = *(const u16x8*)&As[(wid * 64 + mi * 16 + la) * 32 + kb8];
      acc[mi] = __builtin_amdgcn_mfma_f32_16x16x32_bf16(cva.b, cvb.b, acc[mi], 0, 0, 0);
    }
  }
  const float bav = ba[la];
#pragma unroll
  for (int mi = 0; mi < 4; ++mi)
#pragma unroll
    for (int rr = 0; rr < 4; ++rr) {
      int row = brow + wid * 64 + mi * 16 + ((l >> 4) << 2) + rr;
      float t = acc[mi][rr] + bav + 2.0f;
      abuf[(size_t)row * HH + la] = 1.f / (1.f + __expf(-t));
    }
}

// ---------------------------------------------------------------------------
// bf16 MFMA GEMM, 256x256 tile, 8 waves (512 thr), BK=32, global_load_lds.
// ROUTE=1: fused QKV (N=3072): route cols to qkv buffer, elu+1 on q/k.
// ROUTE=0: f32 output (Wo).  NCT = col-tile count for swizzle.
// ---------------------------------------------------------------------------
template<int NCT, int ROUTE>
__global__ __launch_bounds__(512)
void gemm256(const u16* __restrict__ A, const u16* __restrict__ Bt,
             void* __restrict__ Cout) {
  __shared__ __align__(16) u16 As[256 * 32];
  __shared__ __align__(16) u16 Bs[256 * 32];
  const int tid = threadIdx.x;
  const int nwg = gridDim.x;
  const int f = blockIdx.x;
  const int swz = (f & 7) * (nwg >> 3) + (f >> 3);
  const int brow = (swz / NCT) * 256;
  const int bcol = (swz % NCT) * 256;
  const int l = tid & 63;
  const int wid = tid >> 6;
  const int wrow = (wid >> 2) * 128, wcol = (wid & 3) * 64;
  const int la = l & 15, kb8 = (l >> 4) * 8;
  const int sr = tid >> 2, se = (tid & 3) * 8;
  const int K = 1024;
  const int wb = wid * 512;   // wave-uniform LDS base (u16)

  f32x4 acc[8][4];
#pragma unroll
  for (int i = 0; i < 8; ++i)
#pragma unroll
    for (int j = 0; j < 4; ++j) acc[i][j] = (f32x4){0.f, 0.f, 0.f, 0.f};

  const u16* a0p = A + (size_t)(brow + sr) * K + se;
  const u16* a1p = A + (size_t)(brow + 128 + sr) * K + se;
  const u16* b0p = Bt + (size_t)(bcol + sr) * K + se;
  const u16* b1p = Bt + (size_t)(bcol + 128 + sr) * K + se;

  for (int kt = 0; kt < K / 32; ++kt) {
    const int k0 = kt * 32;
    __syncthreads();
    gl2lds16(a0p + k0, &As[wb]);
    gl2lds16(a1p + k0, &As[4096 + wb]);
    gl2lds16(b0p + k0, &Bs[wb]);
    gl2lds16(b1p + k0, &Bs[4096 + wb]);
    __syncthreads();
    bf16x8 bfr[4];
#pragma unroll
    for (int ni = 0; ni < 4; ++ni) {
      union { u16x8 u; bf16x8 b; } cvb;
      cvb.u = *(const u16x8*)&Bs[(wcol + ni * 16 + la) * 32 + kb8];
      bfr[ni] = cvb.b;
    }
#pragma unroll
    for (int mi = 0; mi < 8; ++mi) {
      union { u16x8 u; bf16x8 b; } cva;
      cva.u = *(const u16x8*)&As[(wrow + mi * 16 + la) * 32 + kb8];
#pragma unroll
      for (int ni = 0; ni < 4; ++ni)
        acc[mi][ni] = __builtin_amdgcn_mfma_f32_16x16x32_bf16(cva.b, bfr[ni], acc[mi][ni], 0, 0, 0);
    }
  }

  if (ROUTE) {
    // per-block uniform: which of q/k/v this 256-col tile belongs to
    u16* base = (u16*)Cout + (size_t)(bcol >> 10) * ((size_t)MM * 1024);
    const bool act = (bcol < 2048);
#pragma unroll
    for (int mi = 0; mi < 8; ++mi)
#pragma unroll
      for (int ni = 0; ni < 4; ++ni)
#pragma unroll
        for (int rr = 0; rr < 4; ++rr) {
          int row = brow + wrow + mi * 16 + ((l >> 4) << 2) + rr;
          int c2 = (bcol & 1023) + wcol + ni * 16 + la;
          float v = acc[mi][ni][rr];
          if (act) v = v > 0.f ? v + 1.f : __expf(v);
          base[(size_t)row * 1024 + c2] = f2bf(v);
        }
  } else {
#pragma unroll
    for (int mi = 0; mi < 8; ++mi)
#pragma unroll
      for (int ni = 0; ni < 4; ++ni)
#pragma unroll
        for (int rr = 0; rr < 4; ++rr) {
          int row = brow + wrow + mi * 16 + ((l >> 4) << 2) + rr;
          int col = bcol + wcol + ni * 16 + la;
          ((float*)Cout)[(size_t)row * 1024 + col] = acc[mi][ni][rr];
        }
  }
}

// ---------------------------------------------------------------------------
// Kernel A (MFMA): per-chunk local state, stored TRANSPOSED in bf16:
// S^T[dv][dk] = sum_t v[t][dv] * (w_t k[t][dk]),  w_t = exp(cA[63]-cA[t])
// ---------------------------------------------------------------------------
__global__ __launch_bounds__(256)
void chunk_local(const u16* __restrict__ kb, const u16* __restrict__ vb,
                 const float* __restrict__ abuf,
                 u16* __restrict__ Sbuf, float* __restrict__ zbuf,
                 float* __restrict__ cAbuf) {
  const int blk = blockIdx.x;
  const int c = blk & (CCHUNK - 1);
  const int h = (blk >> 7) & (HH - 1);
  const int b = blk >> 11;
  const int rowbase = b * NNLEN + c * LCH;
  __shared__ __align__(16) u16 KT[64 * 64];   // KT[dk][t] = w_t*k (swizzled)
  __shared__ __align__(16) u16 VTl[64 * 64];  // VTl[dv][t] (swizzled)
  __shared__ float wsh[64];
  const int tid = threadIdx.x;
  const int r = tid >> 2, e = (tid & 3) * 16;

  const u16* kp = kb + (size_t)(rowbase + r) * PP + h * DH + e;
  const u16* vp = vb + (size_t)(rowbase + r) * PP + h * DH + e;
  u16x8 k0 = *(const u16x8*)kp, k1 = *(const u16x8*)(kp + 8);
  u16x8 v0 = *(const u16x8*)vp, v1 = *(const u16x8*)(vp + 8);

  if (tid < 64) {
    float v = __logf(abuf[(size_t)(rowbase + tid) * HH + h]);
#pragma unroll
    for (int d = 1; d < 64; d <<= 1) {
      float u = __shfl_up(v, d);
      if (tid >= d) v += u;
    }
    cAbuf[(size_t)blk * 64 + tid] = v;
    float tot = __shfl(v, 63);
    wsh[tid] = __expf(tot - v);
  }
  __syncthreads();

  {
    const float wt = wsh[r];
#pragma unroll
    for (int j = 0; j < 8; ++j) {
      int d0 = e + j, d1 = e + 8 + j;
      KT[d0 * 64 + (r ^ ((d0 & 7) << 3))] = f2bf(bf2f(k0[j]) * wt);
      KT[d1 * 64 + (r ^ ((d1 & 7) << 3))] = f2bf(bf2f(k1[j]) * wt);
      VTl[d0 * 64 + (r ^ ((d0 & 7) << 3))] = v0[j];
      VTl[d1 * 64 + (r ^ ((d1 & 7) << 3))] = v1[j];
    }
  }
  __syncthreads();

  const int l = tid & 63, w = tid >> 6;
  const int kb8 = (l >> 4) << 3, la = l & 15;
  f32x4 s[4];
#pragma unroll
  for (int ni = 0; ni < 4; ++ni) s[ni] = (f32x4){0.f, 0.f, 0.f, 0.f};
#pragma unroll
  for (int kk = 0; kk < 2; ++kk) {
    bf16x8 av = ldsw(VTl, 16 * w + la, kk * 32 + kb8);
#pragma unroll
    for (int ni = 0; ni < 4; ++ni)
      s[ni] = __builtin_amdgcn_mfma_f32_16x16x32_bf16(
          av, ldsw(KT, 16 * ni + la, kk * 32 + kb8), s[ni], 0, 0, 0);
  }
  u16* Sc = Sbuf + (size_t)blk * 4096;
  const int dw = 16 * w + ((l >> 4) << 2);
#pragma unroll
  for (int ni = 0; ni < 4; ++ni)
#pragma unroll
    for (int rr = 0; rr < 4; ++rr)
      Sc[(dw + rr) * 64 + 16 * ni + la] = f2bf(s[ni][rr]);

  {
    const int dk = tid >> 2, tq = (tid & 3) * 16, swk = (dk & 7) << 3;
    float zp = 0.f;
#pragma unroll
    for (int i = 0; i < 16; ++i) zp += bf2f(KT[dk * 64 + ((tq + i) ^ swk)]);
    zp += __shfl_xor(zp, 1);
    zp += __shfl_xor(zp, 2);
    if ((tid & 3) == 0) zbuf[(size_t)blk * 64 + dk] = zp;
  }
}

// ---------------------------------------------------------------------------
// Scan level 1: within-group (GCH=8 chunks) prefix, in place over Sbuf/zbuf.
// ---------------------------------------------------------------------------
__global__ __launch_bounds__(256)
void scan_group(u16* __restrict__ Sbuf, float* __restrict__ zbuf,
                const float* __restrict__ cAbuf,
                float* __restrict__ GAgg, float* __restrict__ zGAgg,
                float* __restrict__ dpbuf) {
  const int j = blockIdx.x & 3;
  const int g = (blockIdx.x >> 2) & (NGRP - 1);
  const int bh = blockIdx.x >> 6;
  const int c0 = g * GCH;
  const size_t cb = (size_t)bh * CCHUNK;
  const int elem = j * 1024 + threadIdx.x * 4;

  float dch[GCH];
#pragma unroll
  for (int i = 0; i < GCH; ++i)
    dch[i] = __expf(cAbuf[(cb + c0 + i) * 64 + 63]);
  if (j == 0 && threadIdx.x == 0) {
    float rp = 1.f;
#pragma unroll
    for (int i = 0; i < GCH; ++i) { dpbuf[cb + c0 + i] = rp; rp *= dch[i]; }
  }

  f32x4 run = (f32x4){0.f, 0.f, 0.f, 0.f};
  u16x4 cur = *(const u16x4*)&Sbuf[(cb + c0) * 4096 + elem];
#pragma unroll
  for (int i = 0; i < GCH; ++i) {
    u16x4 nxt;
    if (i + 1 < GCH) nxt = *(const u16x4*)&Sbuf[(cb + c0 + i + 1) * 4096 + elem];
    u16x4 o;
#pragma unroll
    for (int jj = 0; jj < 4; ++jj) o[jj] = f2bf(run[jj]);
    *(u16x4*)&Sbuf[(cb + c0 + i) * 4096 + elem] = o;
#pragma unroll
    for (int jj = 0; jj < 4; ++jj) run[jj] = dch[i] * run[jj] + bf2f(cur[jj]);
    cur = nxt;
  }
  *(f32x4*)&GAgg[((size_t)bh * NGRP + g) * 4096 + elem] = run;

  if (j == 0 && threadIdx.x < 64) {
    const int t = threadIdx.x;
    float zr = 0.f;
#pragma unroll
    for (int i = 0; i < GCH; ++i) {
      float curz = zbuf[(cb + c0 + i) * 64 + t];
      zbuf[(cb + c0 + i) * 64 + t] = zr;
      zr = dch[i] * zr + curz;
    }
    zGAgg[((size_t)bh * NGRP + g) * 64 + t] = zr;
  }
}

// ---------------------------------------------------------------------------
// Scan level 2: across the 16 group aggregates, in place (GAgg -> Gbegin).
// ---------------------------------------------------------------------------
__global__ __launch_bounds__(1024)
void scan_top(float* __restrict__ GAgg, float* __restrict__ zGAgg,
              const float* __restrict__ cAbuf) {
  const int bh = blockIdx.x;
  const size_t cb = (size_t)bh * CCHUNK;
  __shared__ float Dsh[NGRP];
  if (threadIdx.x < NGRP) {
    float s = 0.f;
#pragma unroll
    for (int i = 0; i < GCH; ++i)
      s += cAbuf[(cb + threadIdx.x * GCH + i) * 64 + 63];
    Dsh[threadIdx.x] = __expf(s);
  }
  __syncthreads();
  const int elem = threadIdx.x * 4;
  float* base = GAgg + (size_t)bh * NGRP * 4096;
  f32x4 run = (f32x4){0.f, 0.f, 0.f, 0.f};
  f32x4 cur = *(const f32x4*)&base[elem];
#pragma unroll
  for (int gg = 0; gg < NGRP; ++gg) {
    f32x4 nxt;
    if (gg + 1 < NGRP) nxt = *(const f32x4*)&base[(gg + 1) * 4096 + elem];
    *(f32x4*)&base[gg * 4096 + elem] = run;
    const float D = Dsh[gg];
#pragma unroll
    for (int jj = 0; jj < 4; ++jj) run[jj] = D * run[jj] + cur[jj];
    cur = nxt;
  }
  if (threadIdx.x < 64) {
    float* zb = zGAgg + (size_t)bh * NGRP * 64;
    float zr = 0.f;
#pragma unroll
    for (int gg = 0; gg < NGRP; ++gg) {
      float a = zb[gg * 64 + threadIdx.x];
      zb[gg * 64 + threadIdx.x] = zr;
      zr = Dsh[gg] * zr + a;
    }
  }
}

// ---------------------------------------------------------------------------
// Kernel C (MFMA): per-chunk output.
// S0 = prefix(bf16) + dp * Gbegin(f32);  z0 = zprefix + dp * zGbegin
// ---------------------------------------------------------------------------
__global__ __launch_bounds__(256)
void chunk_out(u16* __restrict__ qb, const u16* __restrict__ kb,
               const u16* __restrict__ vb, const u16* __restrict__ Sbuf,
               const float* __restrict__ zbuf, const float* __restrict__ cAbuf,
               const float* __restrict__ GAgg, const float* __restrict__ zGAgg,
               const float* __restrict__ dpbuf) {
  const int blk = blockIdx.x;
  const int c = blk & (CCHUNK - 1);
  const int h = (blk >> 7) & (HH - 1);
  const int b = blk >> 11;
  const int bh = blk >> 7;
  const int g = c >> 3;
  const int rowbase = b * NNLEN + c * LCH;

  __shared__ __align__(16) u16 Qs[64 * 64];
  __shared__ __align__(16) u16 Ke[64 * 64];
  __shared__ __align__(16) u16 VT[64 * 64];
  __shared__ __align__(16) u16 STs[64 * 64];
  __shared__ __align__(16) u16 Pb[64 * 64];
  __shared__ float cAsh[64], zsh[64], denP[64], qzs[64];

  const int tid = threadIdx.x;
  const int r = tid >> 2, e = (tid & 3) * 16;
  const float dp = dpbuf[blk];

  const u16* qp = qb + (size_t)(rowbase + r) * PP + h * DH + e;
  const u16* kp = kb + (size_t)(rowbase + r) * PP + h * DH + e;
  const u16* vp = vb + (size_t)(rowbase + r) * PP + h * DH + e;
  u16x8 q0 = *(const u16x8*)qp, q1 = *(const u16x8*)(qp + 8);
  u16x8 k0 = *(const u16x8*)kp, k1 = *(const u16x8*)(kp + 8);
  u16x8 v0 = *(const u16x8*)vp, v1 = *(const u16x8*)(vp + 8);
  const u16* sp = Sbuf + (size_t)blk * 4096 + r * 64 + e;
  u16x8 p0 = *(const u16x8*)sp, p1 = *(const u16x8*)(sp + 8);
  const float* gp = GAgg + ((size_t)bh * NGRP + g) * 4096 + r * 64 + e;
  f32x4 g0 = *(const f32x4*)gp, g1 = *(const f32x4*)(gp + 4),
        g2 = *(const f32x4*)(gp + 8), g3 = *(const f32x4*)(gp + 12);
  if (tid < 64) {
    cAsh[tid] = cAbuf[(size_t)blk * 64 + tid];
    zsh[tid] = zbuf[(size_t)blk * 64 + tid]
             + dp * zGAgg[((size_t)bh * NGRP + g) * 64 + tid];
  }
  __syncthreads();

  {
    const float c0c = cAsh[31];
    const int sw = (r & 7) << 3;
    const float qsc = __expf(cAsh[r] - c0c);
    const float ksc = __expf(c0c - cAsh[r]);
    const float ssc = __expf(c0c);
    u16x8 t0, t1, u0, u1, w0, w1;
#pragma unroll
    for (int j = 0; j < 8; ++j) {
      t0[j] = f2bf(bf2f(q0[j]) * qsc);
      t1[j] = f2bf(bf2f(q1[j]) * qsc);
      u0[j] = f2bf(bf2f(k0[j]) * ksc);
      u1[j] = f2bf(bf2f(k1[j]) * ksc);
    }
#pragma unroll
    for (int j = 0; j < 4; ++j) {
      w0[j]     = f2bf((bf2f(p0[j])     + dp * g0[j]) * ssc);
      w0[4 + j] = f2bf((bf2f(p0[4 + j]) + dp * g1[j]) * ssc);
      w1[j]     = f2bf((bf2f(p1[j])     + dp * g2[j]) * ssc);
      w1[4 + j] = f2bf((bf2f(p1[4 + j]) + dp * g3[j]) * ssc);
    }
    *(u16x8*)&Qs[r * 64 + (e ^ sw)] = t0;
    *(u16x8*)&Qs[r * 64 + ((e + 8) ^ sw)] = t1;
    *(u16x8*)&Ke[r * 64 + (e ^ sw)] = u0;
    *(u16x8*)&Ke[r * 64 + ((e + 8) ^ sw)] = u1;
    *(u16x8*)&STs[r * 64 + (e ^ sw)] = w0;
    *(u16x8*)&STs[r * 64 + ((e + 8) ^ sw)] = w1;
#pragma unroll
    for (int j = 0; j < 8; ++j) {
      int d0 = e + j, d1 = e + 8 + j;
      VT[d0 * 64 + (r ^ ((d0 & 7) << 3))] = v0[j];
      VT[d1 * 64 + (r ^ ((d1 & 7) << 3))] = v1[j];
    }
    if (tid < 64) zsh[tid] *= ssc;
  }
  __syncthreads();

  const int l = tid & 63, w = tid >> 6;
  const int kb8 = (l >> 4) << 3, la = l & 15;

  // --- MFMA1: P = Qe @ Ke^T ---
  bf16x8 aq[2];
  f32x4 p[4];
#pragma unroll
  for (int ni = 0; ni < 4; ++ni) p[ni] = (f32x4){0.f, 0.f, 0.f, 0.f};
#pragma unroll
  for (int kk = 0; kk < 2; ++kk) {
    aq[kk] = ldsw(Qs, 16 * w + la, kk * 32 + kb8);
#pragma unroll
    for (int ni = 0; ni < 4; ++ni)
      p[ni] = __builtin_amdgcn_mfma_f32_16x16x32_bf16(
          aq[kk], ldsw(Ke, 16 * ni + la, kk * 32 + kb8), p[ni], 0, 0, 0);
  }

  const int tw = 16 * w + ((l >> 4) << 2);
  float rsum[4] = {0.f, 0.f, 0.f, 0.f};
#pragma unroll
  for (int ni = 0; ni < 4; ++ni)
#pragma unroll
    for (int rr = 0; rr < 4; ++rr) {
      int s = 16 * ni + la, t = tw + rr;
      float v = (s <= t) ? p[ni][rr] : 0.f;
      p[ni][rr] = v;
      rsum[rr] += v;
    }
#pragma unroll
  for (int d = 1; d < 16; d <<= 1)
#pragma unroll
    for (int rr = 0; rr < 4; ++rr) rsum[rr] += __shfl_xor(rsum[rr], d);
  if (la == 0)
#pragma unroll
    for (int rr = 0; rr < 4; ++rr) denP[tw + rr] = rsum[rr];

#pragma unroll
  for (int ni = 0; ni < 4; ++ni)
#pragma unroll
    for (int rr = 0; rr < 4; ++rr) {
      int t = tw + rr, s = 16 * ni + la;
      Pb[t * 64 + (s ^ ((t & 7) << 3))] = f2bf(p[ni][rr]);
    }

  {
    const int tq = tid >> 2, dq = (tid & 3) * 16, swq = (tq & 7) << 3;
    float qzp = 0.f;
#pragma unroll
    for (int i = 0; i < 16; ++i)
      qzp += bf2f(Qs[tq * 64 + ((dq + i) ^ swq)]) * zsh[dq + i];
    qzp += __shfl_xor(qzp, 1);
    qzp += __shfl_xor(qzp, 2);
    if ((tid & 3) == 0) qzs[tq] = qzp;
  }
  __syncthreads();

  // --- MFMA2: O = P@V + Qe@S0e^T ---
  f32x4 o[4];
#pragma unroll
  for (int ni = 0; ni < 4; ++ni) o[ni] = (f32x4){0.f, 0.f, 0.f, 0.f};
#pragma unroll
  for (int kk = 0; kk < 2; ++kk) {
    bf16x8 ap = ldsw(Pb, 16 * w + la, kk * 32 + kb8);
#pragma unroll
    for (int ni = 0; ni < 4; ++ni)
      o[ni] = __builtin_amdgcn_mfma_f32_16x16x32_bf16(
          ap, ldsw(VT, 16 * ni + la, kk * 32 + kb8), o[ni], 0, 0, 0);
  }
#pragma unroll
  for (int kk = 0; kk < 2; ++kk)
#pragma unroll
    for (int ni = 0; ni < 4; ++ni)
      o[ni] = __builtin_amdgcn_mfma_f32_16x16x32_bf16(
          aq[kk], ldsw(STs, 16 * ni + la, kk * 32 + kb8), o[ni], 0, 0, 0);

  float dn[4];
#pragma unroll
  for (int rr = 0; rr < 4; ++rr) dn[rr] = qzs[tw + rr] + denP[tw + rr] + EPSV;
#pragma unroll
  for (int ni = 0; ni < 4; ++ni)
#pragma unroll
    for (int rr = 0; rr < 4; ++rr) {
      int t = tw + rr, dv = 16 * ni + la;
      qb[(size_t)(rowbase + t) * PP + h * DH + dv] = f2bf(o[ni][rr] / dn[rr]);
    }
}

// ---------------------------------------------------------------------------
extern "C" void kernel_launch(void* const* d_in, const int* in_sizes, int n_in,
                              void* d_out, int out_size, void* d_ws, size_t ws_size,
                              hipStream_t stream) {
  const float* x  = (const float*)d_in[0];
  const float* Wq = (const float*)d_in[1];
  const float* Wk = (const float*)d_in[2];
  const float* Wv = (const float*)d_in[3];
  const float* Wo = (const float*)d_in[4];
  const float* Wa = (const float*)d_in[5];
  const float* ba = (const float*)d_in[6];

  char* ws = (char*)d_ws;
  size_t off = 0;
  auto carve = [&](size_t bytes) {
    void* p = ws + off;
    off += (bytes + 255) & ~(size_t)255;
    return p;
  };
  u16* xb   = (u16*)carve((size_t)MM * DD * 2);
  u16* WqT  = (u16*)carve((size_t)PP * DD * 2);  // WqT/WkT/WvT contiguous
  u16* WkT  = (u16*)carve((size_t)PP * DD * 2);
  u16* WvT  = (u16*)carve((size_t)PP * DD * 2);
  u16* WoT  = (u16*)carve((size_t)DD * PP * 2);
  u16* WaT  = (u16*)carve((size_t)HH * DD * 2);
  u16* qb   = (u16*)carve((size_t)MM * PP * 2);  // qb/kb/vb contiguous
  u16* kb   = (u16*)carve((size_t)MM * PP * 2);
  u16* vb   = (u16*)carve((size_t)MM * PP * 2);
  float* abuf  = (float*)carve((size_t)MM * HH * 4);
  u16*  Sbuf   = (u16*)carve((size_t)BBATCH * HH * CCHUNK * 4096 * 2);
  float* zbuf  = (float*)carve((size_t)BBATCH * HH * CCHUNK * 64 * 4);
  float* cAbuf = (float*)carve((size_t)BBATCH * HH * CCHUNK * 64 * 4);
  float* GAgg  = (float*)carve((size_t)BBATCH * HH * NGRP * 4096 * 4);
  float* zGAgg = (float*)carve((size_t)BBATCH * HH * NGRP * 64 * 4);
  float* dpbuf = (float*)carve((size_t)BBATCH * HH * CCHUNK * 4);

  transpose_f32_bf16<<<dim3(32, 32), 256, 0, stream>>>(Wq, WqT);
  transpose_f32_bf16<<<dim3(32, 32), 256, 0, stream>>>(Wk, WkT);
  transpose_f32_bf16<<<dim3(32, 32), 256, 0, stream>>>(Wv, WvT);
  transpose_f32_bf16<<<dim3(32, 32), 256, 0, stream>>>(Wo, WoT);
  wa_prep<<<64, 256, 0, stream>>>(Wa, WaT);
  convert_x<<<MM * DD / 8 / 256, 256, 0, stream>>>(x, xb);
  a_proj<<<MM / 256, 256, 0, stream>>>(xb, WaT, ba, abuf);

  // fused QKV: M=16384, N=3072 (WqT/WkT/WvT contiguous), routed epilogue
  gemm256<12, 1><<<(MM / 256) * 12, 512, 0, stream>>>(xb, WqT, qb);

  chunk_local<<<BBATCH * HH * CCHUNK, 256, 0, stream>>>(kb, vb, abuf, Sbuf, zbuf, cAbuf);
  scan_group<<<BBATCH * HH * NGRP * 4, 256, 0, stream>>>(Sbuf, zbuf, cAbuf, GAgg, zGAgg, dpbuf);
  scan_top<<<BBATCH * HH, 1024, 0, stream>>>(GAgg, zGAgg, cAbuf);
  chunk_out<<<BBATCH * HH * CCHUNK, 256, 0, stream>>>(qb, kb, vb, Sbuf, zbuf, cAbuf,
                                                      GAgg, zGAgg, dpbuf);

  gemm256<4, 0><<<(MM / 256) * 4, 512, 0, stream>>>(qb, WoT, (float*)d_out);
}

// Round 5
// 284.990 us; speedup vs baseline: 1.8945x; 1.1417x over previous
//
#include <hip/hip_runtime.h>
#include <stdint.h>

#define HH 16
#define DH 64
#define DD 1024
#define PP 1024
#define NNLEN 8192
#define BBATCH 2
#define MM (BBATCH*NNLEN)   // 16384 rows
#define CCHUNK 128          // chunks per (b,h)
#define LCH 64              // chunk length
#define NGRP 16             // scan groups per (b,h)
#define GCH 8               // chunks per group
#define EPSV 1e-6f

typedef unsigned short u16;
typedef __attribute__((ext_vector_type(4))) unsigned short u16x4;
typedef __attribute__((ext_vector_type(8))) unsigned short u16x8;
typedef __attribute__((ext_vector_type(8))) __bf16 bf16x8;
typedef __attribute__((ext_vector_type(4))) float f32x4;

__device__ __forceinline__ u16 f2bf(float f) {
  unsigned x = __float_as_uint(f);
  return (u16)((x + 0x7fffu + ((x >> 16) & 1u)) >> 16);
}
__device__ __forceinline__ float bf2f(u16 u) {
  return __uint_as_float(((unsigned)u) << 16);
}

// async global->LDS, 16B per lane. LDS dest must be wave-uniform base.
__device__ __forceinline__ void gl2lds16(const void* g, void* l) {
  __builtin_amdgcn_global_load_lds(
      reinterpret_cast<__attribute__((address_space(1))) void*>(
          reinterpret_cast<uintptr_t>(g)),
      reinterpret_cast<__attribute__((address_space(3))) void*>(
          reinterpret_cast<uintptr_t>(l)),
      16, 0, 0);
}

// swizzled LDS read of a bf16x8 fragment from a [*][64] u16 tile.
// u16 col ^= ((row&7)<<3)  (16B granule involution)
__device__ __forceinline__ bf16x8 ldsw(const u16* base, int row, int col) {
  union { u16x8 u; bf16x8 b; } cv;
  cv.u = *(const u16x8*)&base[row * 64 + (col ^ ((row & 7) << 3))];
  return cv.b;
}

// ---------------------------------------------------------------------------
// x f32 -> bf16, pure streaming (8 elems/thread)
// ---------------------------------------------------------------------------
__global__ __launch_bounds__(256)
void convert_x(const float* __restrict__ in, u16* __restrict__ out) {
  size_t i = ((size_t)blockIdx.x * 256 + threadIdx.x) * 8;
  f32x4 a = *(const f32x4*)(in + i);
  f32x4 b = *(const f32x4*)(in + i + 4);
  u16x8 o;
  o[0] = f2bf(a[0]); o[1] = f2bf(a[1]); o[2] = f2bf(a[2]); o[3] = f2bf(a[3]);
  o[4] = f2bf(b[0]); o[5] = f2bf(b[1]); o[6] = f2bf(b[2]); o[7] = f2bf(b[3]);
  *(u16x8*)(out + i) = o;
}

// Wa[1024][16] f32 -> WaT[16][1024] bf16
__global__ __launch_bounds__(256)
void wa_prep(const float* __restrict__ Wa, u16* __restrict__ WaT) {
  int idx = blockIdx.x * 256 + threadIdx.x;  // 16384
  WaT[idx] = f2bf(Wa[(idx & 1023) * 16 + (idx >> 10)]);
}

// ---------------------------------------------------------------------------
// transpose 1024x1024 f32 -> bf16 (out[n][k] = in[k][n])
// ---------------------------------------------------------------------------
__global__ __launch_bounds__(256)
void transpose_f32_bf16(const float* __restrict__ in, u16* __restrict__ out) {
  __shared__ float tile[32][33];
  int bx = blockIdx.x * 32, by = blockIdx.y * 32;
  int tx = threadIdx.x & 31, ty = threadIdx.x >> 5;  // ty 0..7
  for (int i = ty; i < 32; i += 8)
    tile[i][tx] = in[(size_t)(by + i) * 1024 + bx + tx];
  __syncthreads();
  for (int i = ty; i < 32; i += 8)
    out[(size_t)(bx + i) * 1024 + by + tx] = f2bf(tile[tx][i]);
}

// ---------------------------------------------------------------------------
// a_proj (MFMA skinny GEMM): abuf = sigmoid(xb @ Wa + ba + 2), M=16384 N=16
// ---------------------------------------------------------------------------
__global__ __launch_bounds__(256)
void a_proj(const u16* __restrict__ xb, const u16* __restrict__ WaT,
            const float* __restrict__ ba, float* __restrict__ abuf) {
  __shared__ __align__(16) u16 As[256 * 32];
  __shared__ __align__(16) u16 Bs[16 * 32];
  const int tid = threadIdx.x;
  const int brow = blockIdx.x * 256;
  const int l = tid & 63, wid = tid >> 6;
  const int la = l & 15, kb8 = (l >> 4) * 8;
  const int sr = tid >> 2, se = (tid & 3) * 8;

  f32x4 acc[4];
#pragma unroll
  for (int mi = 0; mi < 4; ++mi) acc[mi] = (f32x4){0.f, 0.f, 0.f, 0.f};

  for (int kt = 0; kt < 32; ++kt) {
    const int k0 = kt * 32;
    __syncthreads();
#pragma unroll
    for (int i = 0; i < 4; ++i)
      gl2lds16(xb + (size_t)(brow + i * 64 + sr) * DD + k0 + se,
               &As[i * 2048 + wid * 512]);
    if (wid == 0)
      gl2lds16(WaT + (size_t)(l >> 2) * DD + k0 + (l & 3) * 8, &Bs[0]);
    __syncthreads();
    union { u16x8 u; bf16x8 b; } cvb;
    cvb.u = *(const u16x8*)&Bs[la * 32 + kb8];
#pragma unroll
    for (int mi = 0; mi < 4; ++mi) {
      union { u16x8 u; bf16x8 b; } cva;
      cva.u = *(const u16x8*)&As[(wid * 64 + mi * 16 + la) * 32 + kb8];
      acc[mi] = __builtin_amdgcn_mfma_f32_16x16x32_bf16(cva.b, cvb.b, acc[mi], 0, 0, 0);
    }
  }
  const float bav = ba[la];
#pragma unroll
  for (int mi = 0; mi < 4; ++mi)
#pragma unroll
    for (int rr = 0; rr < 4; ++rr) {
      int row = brow + wid * 64 + mi * 16 + ((l >> 4) << 2) + rr;
      float t = acc[mi][rr] + bav + 2.0f;
      abuf[(size_t)row * HH + la] = 1.f / (1.f + __expf(-t));
    }
}

// ---------------------------------------------------------------------------
// bf16 MFMA GEMM, 8-phase (T2+T3+T4+T5): 256x256 tile, BK=64, 8 waves,
// 128KiB dbuf LDS, raw s_barrier + counted vmcnt (drain once per K-tile),
// XOR-swizzled LDS via pre-swizzled global source, setprio around MFMA.
// ROUTE=1: fused QKV (N=3072) routed bf16 epilogue w/ elu+1 on q/k.
// ROUTE=0: f32 output.  NCT = col-tile count.
// ---------------------------------------------------------------------------
template<int NCT, int ROUTE>
__global__ __launch_bounds__(512)
void gemm8p(const u16* __restrict__ A, const u16* __restrict__ Bt,
            void* __restrict__ Cout) {
  __shared__ __align__(16) u16 As[2][256 * 64];
  __shared__ __align__(16) u16 Bs[2][256 * 64];
  const int tid = threadIdx.x;
  const int nwg = gridDim.x;
  const int f = blockIdx.x;
  const int swz = (f & 7) * (nwg >> 3) + (f >> 3);
  const int brow = (swz / NCT) * 256;
  const int bcol = (swz % NCT) * 256;
  const int l = tid & 63;
  const int wid = tid >> 6;       // 0..7
  const int wr = wid >> 2;        // 0..1  (M half)
  const int wc = wid & 3;         // 0..3  (N quarter)
  const int la = l & 15, kb8 = (l >> 4) * 8;
  const int K = 1024;
  // staging geometry: wave stages 2x 1KB chunks per half-tile
  const int srow = l >> 3;                       // row within 8-row chunk
  const int scol = ((l & 7) * 8) ^ (srow << 3);  // pre-swizzled global col (u16)
  const int ldso = (wid * 2) * 512;              // wave chunk base (u16) within half

  f32x4 acc[8][4];
#pragma unroll
  for (int i = 0; i < 8; ++i)
#pragma unroll
    for (int j = 0; j < 4; ++j) acc[i][j] = (f32x4){0.f, 0.f, 0.f, 0.f};

  // prologue: stage K-tile 0 (A and B, both halves) into buf 0
#pragma unroll
  for (int h = 0; h < 2; ++h)
#pragma unroll
    for (int j = 0; j < 2; ++j) {
      const int r0 = h * 128 + (wid * 2 + j) * 8 + srow;
      gl2lds16(A  + (size_t)(brow + r0) * K + scol, &As[0][h * 8192 + ldso + j * 512]);
      gl2lds16(Bt + (size_t)(bcol + r0) * K + scol, &Bs[0][h * 8192 + ldso + j * 512]);
    }
  asm volatile("s_waitcnt vmcnt(0)" ::: "memory");
  __builtin_amdgcn_s_barrier();

  const int NKT = K / 64;
  for (int kt = 0; kt < NKT; ++kt) {
    const u16* lA = As[kt & 1];
    const u16* lB = Bs[kt & 1];
    u16* nA = As[(kt + 1) & 1];
    u16* nB = Bs[(kt + 1) & 1];
    const int knext = (kt + 1) * 64;
    const bool more = (kt + 1 < NKT);

    bf16x8 af[4][2], bfr[2][2];
    // gray-ordered quadrant phases: (miH,niH) = (0,0),(0,1),(1,1),(1,0)
#pragma unroll
    for (int p = 0; p < 4; ++p) {
      const int miH = (p >> 1);
      const int niH = (p == 1 || p == 2) ? 1 : 0;
      const bool doA = (p == 0 || p == 2);
      const bool doB = (p != 2);
      if (doA) {
#pragma unroll
        for (int m2 = 0; m2 < 4; ++m2)
#pragma unroll
          for (int kk = 0; kk < 2; ++kk)
            af[m2][kk] = ldsw(lA, wr * 128 + miH * 64 + m2 * 16 + la, kk * 32 + kb8);
      }
      if (doB) {
#pragma unroll
        for (int n2 = 0; n2 < 2; ++n2)
#pragma unroll
          for (int kk = 0; kk < 2; ++kk)
            bfr[n2][kk] = ldsw(lB, wc * 64 + niH * 32 + n2 * 16 + la, kk * 32 + kb8);
      }
      if (more && p == 0) {
#pragma unroll
        for (int h = 0; h < 2; ++h)
#pragma unroll
          for (int j = 0; j < 2; ++j) {
            const int r0 = h * 128 + (wid * 2 + j) * 8 + srow;
            gl2lds16(A + (size_t)(brow + r0) * K + knext + scol,
                     nA + h * 8192 + ldso + j * 512);
          }
      }
      if (more && p == 1) {
#pragma unroll
        for (int h = 0; h < 2; ++h)
#pragma unroll
          for (int j = 0; j < 2; ++j) {
            const int r0 = h * 128 + (wid * 2 + j) * 8 + srow;
            gl2lds16(Bt + (size_t)(bcol + r0) * K + knext + scol,
                     nB + h * 8192 + ldso + j * 512);
          }
      }
      __builtin_amdgcn_s_barrier();
      __builtin_amdgcn_s_setprio(1);
#pragma unroll
      for (int m2 = 0; m2 < 4; ++m2)
#pragma unroll
        for (int n2 = 0; n2 < 2; ++n2)
#pragma unroll
          for (int kk = 0; kk < 2; ++kk)
            acc[miH * 4 + m2][niH * 2 + n2] = __builtin_amdgcn_mfma_f32_16x16x32_bf16(
                af[m2][kk], bfr[n2][kk], acc[miH * 4 + m2][niH * 2 + n2], 0, 0, 0);
      __builtin_amdgcn_s_setprio(0);
      if (p == 3) asm volatile("s_waitcnt vmcnt(0)" ::: "memory");
      __builtin_amdgcn_s_barrier();
    }
  }

  const int wrow = wr * 128, wcol = wc * 64;
  if (ROUTE) {
    u16* base = (u16*)Cout + (size_t)(bcol >> 10) * ((size_t)MM * 1024);
    const bool act = (bcol < 2048);
#pragma unroll
    for (int mi = 0; mi < 8; ++mi)
#pragma unroll
      for (int ni = 0; ni < 4; ++ni)
#pragma unroll
        for (int rr = 0; rr < 4; ++rr) {
          int row = brow + wrow + mi * 16 + ((l >> 4) << 2) + rr;
          int c2 = (bcol & 1023) + wcol + ni * 16 + la;
          float v = acc[mi][ni][rr];
          if (act) v = v > 0.f ? v + 1.f : __expf(v);
          base[(size_t)row * 1024 + c2] = f2bf(v);
        }
  } else {
#pragma unroll
    for (int mi = 0; mi < 8; ++mi)
#pragma unroll
      for (int ni = 0; ni < 4; ++ni)
#pragma unroll
        for (int rr = 0; rr < 4; ++rr) {
          int row = brow + wrow + mi * 16 + ((l >> 4) << 2) + rr;
          int col = bcol + wcol + ni * 16 + la;
          ((float*)Cout)[(size_t)row * 1024 + col] = acc[mi][ni][rr];
        }
  }
}

// ---------------------------------------------------------------------------
// Kernel A (MFMA): per-chunk local state, stored TRANSPOSED in bf16:
// S^T[dv][dk] = sum_t v[t][dv] * (w_t k[t][dk]),  w_t = exp(cA[63]-cA[t])
// ---------------------------------------------------------------------------
__global__ __launch_bounds__(256)
void chunk_local(const u16* __restrict__ kb, const u16* __restrict__ vb,
                 const float* __restrict__ abuf,
                 u16* __restrict__ Sbuf, float* __restrict__ zbuf,
                 float* __restrict__ cAbuf) {
  const int blk = blockIdx.x;
  const int c = blk & (CCHUNK - 1);
  const int h = (blk >> 7) & (HH - 1);
  const int b = blk >> 11;
  const int rowbase = b * NNLEN + c * LCH;
  __shared__ __align__(16) u16 KT[64 * 64];   // KT[dk][t] = w_t*k (swizzled)
  __shared__ __align__(16) u16 VTl[64 * 64];  // VTl[dv][t] (swizzled)
  __shared__ float wsh[64];
  const int tid = threadIdx.x;
  const int r = tid >> 2, e = (tid & 3) * 16;

  const u16* kp = kb + (size_t)(rowbase + r) * PP + h * DH + e;
  const u16* vp = vb + (size_t)(rowbase + r) * PP + h * DH + e;
  u16x8 k0 = *(const u16x8*)kp, k1 = *(const u16x8*)(kp + 8);
  u16x8 v0 = *(const u16x8*)vp, v1 = *(const u16x8*)(vp + 8);

  if (tid < 64) {
    float v = __logf(abuf[(size_t)(rowbase + tid) * HH + h]);
#pragma unroll
    for (int d = 1; d < 64; d <<= 1) {
      float u = __shfl_up(v, d);
      if (tid >= d) v += u;
    }
    cAbuf[(size_t)blk * 64 + tid] = v;
    float tot = __shfl(v, 63);
    wsh[tid] = __expf(tot - v);
  }
  __syncthreads();

  {
    const float wt = wsh[r];
#pragma unroll
    for (int j = 0; j < 8; ++j) {
      int d0 = e + j, d1 = e + 8 + j;
      KT[d0 * 64 + (r ^ ((d0 & 7) << 3))] = f2bf(bf2f(k0[j]) * wt);
      KT[d1 * 64 + (r ^ ((d1 & 7) << 3))] = f2bf(bf2f(k1[j]) * wt);
      VTl[d0 * 64 + (r ^ ((d0 & 7) << 3))] = v0[j];
      VTl[d1 * 64 + (r ^ ((d1 & 7) << 3))] = v1[j];
    }
  }
  __syncthreads();

  const int l = tid & 63, w = tid >> 6;
  const int kb8 = (l >> 4) << 3, la = l & 15;
  f32x4 s[4];
#pragma unroll
  for (int ni = 0; ni < 4; ++ni) s[ni] = (f32x4){0.f, 0.f, 0.f, 0.f};
#pragma unroll
  for (int kk = 0; kk < 2; ++kk) {
    bf16x8 av = ldsw(VTl, 16 * w + la, kk * 32 + kb8);
#pragma unroll
    for (int ni = 0; ni < 4; ++ni)
      s[ni] = __builtin_amdgcn_mfma_f32_16x16x32_bf16(
          av, ldsw(KT, 16 * ni + la, kk * 32 + kb8), s[ni], 0, 0, 0);
  }
  u16* Sc = Sbuf + (size_t)blk * 4096;
  const int dw = 16 * w + ((l >> 4) << 2);
#pragma unroll
  for (int ni = 0; ni < 4; ++ni)
#pragma unroll
    for (int rr = 0; rr < 4; ++rr)
      Sc[(dw + rr) * 64 + 16 * ni + la] = f2bf(s[ni][rr]);

  {
    const int dk = tid >> 2, tq = (tid & 3) * 16, swk = (dk & 7) << 3;
    float zp = 0.f;
#pragma unroll
    for (int i = 0; i < 16; ++i) zp += bf2f(KT[dk * 64 + ((tq + i) ^ swk)]);
    zp += __shfl_xor(zp, 1);
    zp += __shfl_xor(zp, 2);
    if ((tid & 3) == 0) zbuf[(size_t)blk * 64 + dk] = zp;
  }
}

// ---------------------------------------------------------------------------
// Scan level 1: within-group (GCH=8 chunks) prefix, in place over Sbuf/zbuf.
// ---------------------------------------------------------------------------
__global__ __launch_bounds__(256)
void scan_group(u16* __restrict__ Sbuf, float* __restrict__ zbuf,
                const float* __restrict__ cAbuf,
                float* __restrict__ GAgg, float* __restrict__ zGAgg,
                float* __restrict__ dpbuf) {
  const int j = blockIdx.x & 3;
  const int g = (blockIdx.x >> 2) & (NGRP - 1);
  const int bh = blockIdx.x >> 6;
  const int c0 = g * GCH;
  const size_t cb = (size_t)bh * CCHUNK;
  const int elem = j * 1024 + threadIdx.x * 4;

  float dch[GCH];
#pragma unroll
  for (int i = 0; i < GCH; ++i)
    dch[i] = __expf(cAbuf[(cb + c0 + i) * 64 + 63]);
  if (j == 0 && threadIdx.x == 0) {
    float rp = 1.f;
#pragma unroll
    for (int i = 0; i < GCH; ++i) { dpbuf[cb + c0 + i] = rp; rp *= dch[i]; }
  }

  f32x4 run = (f32x4){0.f, 0.f, 0.f, 0.f};
  u16x4 cur = *(const u16x4*)&Sbuf[(cb + c0) * 4096 + elem];
#pragma unroll
  for (int i = 0; i < GCH; ++i) {
    u16x4 nxt;
    if (i + 1 < GCH) nxt = *(const u16x4*)&Sbuf[(cb + c0 + i + 1) * 4096 + elem];
    u16x4 o;
#pragma unroll
    for (int jj = 0; jj < 4; ++jj) o[jj] = f2bf(run[jj]);
    *(u16x4*)&Sbuf[(cb + c0 + i) * 4096 + elem] = o;
#pragma unroll
    for (int jj = 0; jj < 4; ++jj) run[jj] = dch[i] * run[jj] + bf2f(cur[jj]);
    cur = nxt;
  }
  *(f32x4*)&GAgg[((size_t)bh * NGRP + g) * 4096 + elem] = run;

  if (j == 0 && threadIdx.x < 64) {
    const int t = threadIdx.x;
    float zr = 0.f;
#pragma unroll
    for (int i = 0; i < GCH; ++i) {
      float curz = zbuf[(cb + c0 + i) * 64 + t];
      zbuf[(cb + c0 + i) * 64 + t] = zr;
      zr = dch[i] * zr + curz;
    }
    zGAgg[((size_t)bh * NGRP + g) * 64 + t] = zr;
  }
}

// ---------------------------------------------------------------------------
// Scan level 2: across the 16 group aggregates, in place (GAgg -> Gbegin).
// ---------------------------------------------------------------------------
__global__ __launch_bounds__(1024)
void scan_top(float* __restrict__ GAgg, float* __restrict__ zGAgg,
              const float* __restrict__ cAbuf) {
  const int bh = blockIdx.x;
  const size_t cb = (size_t)bh * CCHUNK;
  __shared__ float Dsh[NGRP];
  if (threadIdx.x < NGRP) {
    float s = 0.f;
#pragma unroll
    for (int i = 0; i < GCH; ++i)
      s += cAbuf[(cb + threadIdx.x * GCH + i) * 64 + 63];
    Dsh[threadIdx.x] = __expf(s);
  }
  __syncthreads();
  const int elem = threadIdx.x * 4;
  float* base = GAgg + (size_t)bh * NGRP * 4096;
  f32x4 run = (f32x4){0.f, 0.f, 0.f, 0.f};
  f32x4 cur = *(const f32x4*)&base[elem];
#pragma unroll
  for (int gg = 0; gg < NGRP; ++gg) {
    f32x4 nxt;
    if (gg + 1 < NGRP) nxt = *(const f32x4*)&base[(gg + 1) * 4096 + elem];
    *(f32x4*)&base[gg * 4096 + elem] = run;
    const float D = Dsh[gg];
#pragma unroll
    for (int jj = 0; jj < 4; ++jj) run[jj] = D * run[jj] + cur[jj];
    cur = nxt;
  }
  if (threadIdx.x < 64) {
    float* zb = zGAgg + (size_t)bh * NGRP * 64;
    float zr = 0.f;
#pragma unroll
    for (int gg = 0; gg < NGRP; ++gg) {
      float a = zb[gg * 64 + threadIdx.x];
      zb[gg * 64 + threadIdx.x] = zr;
      zr = Dsh[gg] * zr + a;
    }
  }
}

// ---------------------------------------------------------------------------
// Kernel C (MFMA): per-chunk output.
// S0 = prefix(bf16) + dp * Gbegin(f32);  z0 = zprefix + dp * zGbegin
// ---------------------------------------------------------------------------
__global__ __launch_bounds__(256)
void chunk_out(u16* __restrict__ qb, const u16* __restrict__ kb,
               const u16* __restrict__ vb, const u16* __restrict__ Sbuf,
               const float* __restrict__ zbuf, const float* __restrict__ cAbuf,
               const float* __restrict__ GAgg, const float* __restrict__ zGAgg,
               const float* __restrict__ dpbuf) {
  const int blk = blockIdx.x;
  const int c = blk & (CCHUNK - 1);
  const int h = (blk >> 7) & (HH - 1);
  const int b = blk >> 11;
  const int bh = blk >> 7;
  const int g = c >> 3;
  const int rowbase = b * NNLEN + c * LCH;

  __shared__ __align__(16) u16 Qs[64 * 64];
  __shared__ __align__(16) u16 Ke[64 * 64];
  __shared__ __align__(16) u16 VT[64 * 64];
  __shared__ __align__(16) u16 STs[64 * 64];
  __shared__ __align__(16) u16 Pb[64 * 64];
  __shared__ float cAsh[64], zsh[64], denP[64], qzs[64];

  const int tid = threadIdx.x;
  const int r = tid >> 2, e = (tid & 3) * 16;
  const float dp = dpbuf[blk];

  const u16* qp = qb + (size_t)(rowbase + r) * PP + h * DH + e;
  const u16* kp = kb + (size_t)(rowbase + r) * PP + h * DH + e;
  const u16* vp = vb + (size_t)(rowbase + r) * PP + h * DH + e;
  u16x8 q0 = *(const u16x8*)qp, q1 = *(const u16x8*)(qp + 8);
  u16x8 k0 = *(const u16x8*)kp, k1 = *(const u16x8*)(kp + 8);
  u16x8 v0 = *(const u16x8*)vp, v1 = *(const u16x8*)(vp + 8);
  const u16* sp = Sbuf + (size_t)blk * 4096 + r * 64 + e;
  u16x8 p0 = *(const u16x8*)sp, p1 = *(const u16x8*)(sp + 8);
  const float* gp = GAgg + ((size_t)bh * NGRP + g) * 4096 + r * 64 + e;
  f32x4 g0 = *(const f32x4*)gp, g1 = *(const f32x4*)(gp + 4),
        g2 = *(const f32x4*)(gp + 8), g3 = *(const f32x4*)(gp + 12);
  if (tid < 64) {
    cAsh[tid] = cAbuf[(size_t)blk * 64 + tid];
    zsh[tid] = zbuf[(size_t)blk * 64 + tid]
             + dp * zGAgg[((size_t)bh * NGRP + g) * 64 + tid];
  }
  __syncthreads();

  {
    const float c0c = cAsh[31];
    const int sw = (r & 7) << 3;
    const float qsc = __expf(cAsh[r] - c0c);
    const float ksc = __expf(c0c - cAsh[r]);
    const float ssc = __expf(c0c);
    u16x8 t0, t1, u0, u1, w0, w1;
#pragma unroll
    for (int j = 0; j < 8; ++j) {
      t0[j] = f2bf(bf2f(q0[j]) * qsc);
      t1[j] = f2bf(bf2f(q1[j]) * qsc);
      u0[j] = f2bf(bf2f(k0[j]) * ksc);
      u1[j] = f2bf(bf2f(k1[j]) * ksc);
    }
#pragma unroll
    for (int j = 0; j < 4; ++j) {
      w0[j]     = f2bf((bf2f(p0[j])     + dp * g0[j]) * ssc);
      w0[4 + j] = f2bf((bf2f(p0[4 + j]) + dp * g1[j]) * ssc);
      w1[j]     = f2bf((bf2f(p1[j])     + dp * g2[j]) * ssc);
      w1[4 + j] = f2bf((bf2f(p1[4 + j]) + dp * g3[j]) * ssc);
    }
    *(u16x8*)&Qs[r * 64 + (e ^ sw)] = t0;
    *(u16x8*)&Qs[r * 64 + ((e + 8) ^ sw)] = t1;
    *(u16x8*)&Ke[r * 64 + (e ^ sw)] = u0;
    *(u16x8*)&Ke[r * 64 + ((e + 8) ^ sw)] = u1;
    *(u16x8*)&STs[r * 64 + (e ^ sw)] = w0;
    *(u16x8*)&STs[r * 64 + ((e + 8) ^ sw)] = w1;
#pragma unroll
    for (int j = 0; j < 8; ++j) {
      int d0 = e + j, d1 = e + 8 + j;
      VT[d0 * 64 + (r ^ ((d0 & 7) << 3))] = v0[j];
      VT[d1 * 64 + (r ^ ((d1 & 7) << 3))] = v1[j];
    }
    if (tid < 64) zsh[tid] *= ssc;
  }
  __syncthreads();

  const int l = tid & 63, w = tid >> 6;
  const int kb8 = (l >> 4) << 3, la = l & 15;

  // --- MFMA1: P = Qe @ Ke^T ---
  bf16x8 aq[2];
  f32x4 p[4];
#pragma unroll
  for (int ni = 0; ni < 4; ++ni) p[ni] = (f32x4){0.f, 0.f, 0.f, 0.f};
#pragma unroll
  for (int kk = 0; kk < 2; ++kk) {
    aq[kk] = ldsw(Qs, 16 * w + la, kk * 32 + kb8);
#pragma unroll
    for (int ni = 0; ni < 4; ++ni)
      p[ni] = __builtin_amdgcn_mfma_f32_16x16x32_bf16(
          aq[kk], ldsw(Ke, 16 * ni + la, kk * 32 + kb8), p[ni], 0, 0, 0);
  }

  const int tw = 16 * w + ((l >> 4) << 2);
  float rsum[4] = {0.f, 0.f, 0.f, 0.f};
#pragma unroll
  for (int ni = 0; ni < 4; ++ni)
#pragma unroll
    for (int rr = 0; rr < 4; ++rr) {
      int s = 16 * ni + la, t = tw + rr;
      float v = (s <= t) ? p[ni][rr] : 0.f;
      p[ni][rr] = v;
      rsum[rr] += v;
    }
#pragma unroll
  for (int d = 1; d < 16; d <<= 1)
#pragma unroll
    for (int rr = 0; rr < 4; ++rr) rsum[rr] += __shfl_xor(rsum[rr], d);
  if (la == 0)
#pragma unroll
    for (int rr = 0; rr < 4; ++rr) denP[tw + rr] = rsum[rr];

#pragma unroll
  for (int ni = 0; ni < 4; ++ni)
#pragma unroll
    for (int rr = 0; rr < 4; ++rr) {
      int t = tw + rr, s = 16 * ni + la;
      Pb[t * 64 + (s ^ ((t & 7) << 3))] = f2bf(p[ni][rr]);
    }

  {
    const int tq = tid >> 2, dq = (tid & 3) * 16, swq = (tq & 7) << 3;
    float qzp = 0.f;
#pragma unroll
    for (int i = 0; i < 16; ++i)
      qzp += bf2f(Qs[tq * 64 + ((dq + i) ^ swq)]) * zsh[dq + i];
    qzp += __shfl_xor(qzp, 1);
    qzp += __shfl_xor(qzp, 2);
    if ((tid & 3) == 0) qzs[tq] = qzp;
  }
  __syncthreads();

  // --- MFMA2: O = P@V + Qe@S0e^T ---
  f32x4 o[4];
#pragma unroll
  for (int ni = 0; ni < 4; ++ni) o[ni] = (f32x4){0.f, 0.f, 0.f, 0.f};
#pragma unroll
  for (int kk = 0; kk < 2; ++kk) {
    bf16x8 ap = ldsw(Pb, 16 * w + la, kk * 32 + kb8);
#pragma unroll
    for (int ni = 0; ni < 4; ++ni)
      o[ni] = __builtin_amdgcn_mfma_f32_16x16x32_bf16(
          ap, ldsw(VT, 16 * ni + la, kk * 32 + kb8), o[ni], 0, 0, 0);
  }
#pragma unroll
  for (int kk = 0; kk < 2; ++kk)
#pragma unroll
    for (int ni = 0; ni < 4; ++ni)
      o[ni] = __builtin_amdgcn_mfma_f32_16x16x32_bf16(
          aq[kk], ldsw(STs, 16 * ni + la, kk * 32 + kb8), o[ni], 0, 0, 0);

  float dn[4];
#pragma unroll
  for (int rr = 0; rr < 4; ++rr) dn[rr] = qzs[tw + rr] + denP[tw + rr] + EPSV;
#pragma unroll
  for (int ni = 0; ni < 4; ++ni)
#pragma unroll
    for (int rr = 0; rr < 4; ++rr) {
      int t = tw + rr, dv = 16 * ni + la;
      qb[(size_t)(rowbase + t) * PP + h * DH + dv] = f2bf(o[ni][rr] / dn[rr]);
    }
}

// ---------------------------------------------------------------------------
extern "C" void kernel_launch(void* const* d_in, const int* in_sizes, int n_in,
                              void* d_out, int out_size, void* d_ws, size_t ws_size,
                              hipStream_t stream) {
  const float* x  = (const float*)d_in[0];
  const float* Wq = (const float*)d_in[1];
  const float* Wk = (const float*)d_in[2];
  const float* Wv = (const float*)d_in[3];
  const float* Wo = (const float*)d_in[4];
  const float* Wa = (const float*)d_in[5];
  const float* ba = (const float*)d_in[6];

  char* ws = (char*)d_ws;
  size_t off = 0;
  auto carve = [&](size_t bytes) {
    void* p = ws + off;
    off += (bytes + 255) & ~(size_t)255;
    return p;
  };
  u16* xb   = (u16*)carve((size_t)MM * DD * 2);
  u16* WqT  = (u16*)carve((size_t)PP * DD * 2);  // WqT/WkT/WvT contiguous
  u16* WkT  = (u16*)carve((size_t)PP * DD * 2);
  u16* WvT  = (u16*)carve((size_t)PP * DD * 2);
  u16* WoT  = (u16*)carve((size_t)DD * PP * 2);
  u16* WaT  = (u16*)carve((size_t)HH * DD * 2);
  u16* qb   = (u16*)carve((size_t)MM * PP * 2);  // qb/kb/vb contiguous
  u16* kb   = (u16*)carve((size_t)MM * PP * 2);
  u16* vb   = (u16*)carve((size_t)MM * PP * 2);
  float* abuf  = (float*)carve((size_t)MM * HH * 4);
  u16*  Sbuf   = (u16*)carve((size_t)BBATCH * HH * CCHUNK * 4096 * 2);
  float* zbuf  = (float*)carve((size_t)BBATCH * HH * CCHUNK * 64 * 4);
  float* cAbuf = (float*)carve((size_t)BBATCH * HH * CCHUNK * 64 * 4);
  float* GAgg  = (float*)carve((size_t)BBATCH * HH * NGRP * 4096 * 4);
  float* zGAgg = (float*)carve((size_t)BBATCH * HH * NGRP * 64 * 4);
  float* dpbuf = (float*)carve((size_t)BBATCH * HH * CCHUNK * 4);

  transpose_f32_bf16<<<dim3(32, 32), 256, 0, stream>>>(Wq, WqT);
  transpose_f32_bf16<<<dim3(32, 32), 256, 0, stream>>>(Wk, WkT);
  transpose_f32_bf16<<<dim3(32, 32), 256, 0, stream>>>(Wv, WvT);
  transpose_f32_bf16<<<dim3(32, 32), 256, 0, stream>>>(Wo, WoT);
  wa_prep<<<64, 256, 0, stream>>>(Wa, WaT);
  convert_x<<<MM * DD / 8 / 256, 256, 0, stream>>>(x, xb);
  a_proj<<<MM / 256, 256, 0, stream>>>(xb, WaT, ba, abuf);

  // fused QKV: M=16384, N=3072 (WqT/WkT/WvT contiguous), routed epilogue
  gemm8p<12, 1><<<(MM / 256) * 12, 512, 0, stream>>>(xb, WqT, qb);

  chunk_local<<<BBATCH * HH * CCHUNK, 256, 0, stream>>>(kb, vb, abuf, Sbuf, zbuf, cAbuf);
  scan_group<<<BBATCH * HH * NGRP * 4, 256, 0, stream>>>(Sbuf, zbuf, cAbuf, GAgg, zGAgg, dpbuf);
  scan_top<<<BBATCH * HH, 1024, 0, stream>>>(GAgg, zGAgg, cAbuf);
  chunk_out<<<BBATCH * HH * CCHUNK, 256, 0, stream>>>(qb, kb, vb, Sbuf, zbuf, cAbuf,
                                                      GAgg, zGAgg, dpbuf);

  gemm8p<4, 0><<<(MM / 256) * 4, 512, 0, stream>>>(qb, WoT, (float*)d_out);
}

// Round 6
// 272.487 us; speedup vs baseline: 1.9815x; 1.0459x over previous
//
#include <hip/hip_runtime.h>
#include <stdint.h>

#define HH 16
#define DH 64
#define DD 1024
#define PP 1024
#define NNLEN 8192
#define BBATCH 2
#define MM (BBATCH*NNLEN)   // 16384 rows
#define CCHUNK 128          // chunks per (b,h)
#define LCH 64              // chunk length
#define NGRP 16             // scan groups per (b,h)
#define GCH 8               // chunks per group
#define EPSV 1e-6f

typedef unsigned short u16;
typedef __attribute__((ext_vector_type(4))) unsigned short u16x4;
typedef __attribute__((ext_vector_type(8))) unsigned short u16x8;
typedef __attribute__((ext_vector_type(8))) __bf16 bf16x8;
typedef __attribute__((ext_vector_type(4))) float f32x4;

__device__ __forceinline__ u16 f2bf(float f) {
  unsigned x = __float_as_uint(f);
  return (u16)((x + 0x7fffu + ((x >> 16) & 1u)) >> 16);
}
__device__ __forceinline__ float bf2f(u16 u) {
  return __uint_as_float(((unsigned)u) << 16);
}

// async global->LDS, 16B per lane. LDS dest must be wave-uniform base.
__device__ __forceinline__ void gl2lds16(const void* g, void* l) {
  __builtin_amdgcn_global_load_lds(
      reinterpret_cast<__attribute__((address_space(1))) void*>(
          reinterpret_cast<uintptr_t>(g)),
      reinterpret_cast<__attribute__((address_space(3))) void*>(
          reinterpret_cast<uintptr_t>(l)),
      16, 0, 0);
}

// swizzled LDS read of a bf16x8 fragment from a [*][64] u16 tile.
// u16 col ^= ((row&7)<<3)  (16B granule involution)
__device__ __forceinline__ bf16x8 ldsw(const u16* base, int row, int col) {
  union { u16x8 u; bf16x8 b; } cv;
  cv.u = *(const u16x8*)&base[row * 64 + (col ^ ((row & 7) << 3))];
  return cv.b;
}

// ---------------------------------------------------------------------------
// x f32 -> bf16, pure streaming (8 elems/thread)
// ---------------------------------------------------------------------------
__global__ __launch_bounds__(256)
void convert_x(const float* __restrict__ in, u16* __restrict__ out) {
  size_t i = ((size_t)blockIdx.x * 256 + threadIdx.x) * 8;
  f32x4 a = *(const f32x4*)(in + i);
  f32x4 b = *(const f32x4*)(in + i + 4);
  u16x8 o;
  o[0] = f2bf(a[0]); o[1] = f2bf(a[1]); o[2] = f2bf(a[2]); o[3] = f2bf(a[3]);
  o[4] = f2bf(b[0]); o[5] = f2bf(b[1]); o[6] = f2bf(b[2]); o[7] = f2bf(b[3]);
  *(u16x8*)(out + i) = o;
}

// Wa[1024][16] f32 -> WaT[16][1024] bf16
__global__ __launch_bounds__(256)
void wa_prep(const float* __restrict__ Wa, u16* __restrict__ WaT) {
  int idx = blockIdx.x * 256 + threadIdx.x;  // 16384
  WaT[idx] = f2bf(Wa[(idx & 1023) * 16 + (idx >> 10)]);
}

// ---------------------------------------------------------------------------
// transpose 1024x1024 f32 -> bf16 (out[n][k] = in[k][n])
// ---------------------------------------------------------------------------
__global__ __launch_bounds__(256)
void transpose_f32_bf16(const float* __restrict__ in, u16* __restrict__ out) {
  __shared__ float tile[32][33];
  int bx = blockIdx.x * 32, by = blockIdx.y * 32;
  int tx = threadIdx.x & 31, ty = threadIdx.x >> 5;  // ty 0..7
  for (int i = ty; i < 32; i += 8)
    tile[i][tx] = in[(size_t)(by + i) * 1024 + bx + tx];
  __syncthreads();
  for (int i = ty; i < 32; i += 8)
    out[(size_t)(bx + i) * 1024 + by + tx] = f2bf(tile[tx][i]);
}

// ---------------------------------------------------------------------------
// a_proj (MFMA skinny GEMM): abuf = sigmoid(xb @ Wa + ba + 2), M=16384 N=16
// ---------------------------------------------------------------------------
__global__ __launch_bounds__(256)
void a_proj(const u16* __restrict__ xb, const u16* __restrict__ WaT,
            const float* __restrict__ ba, float* __restrict__ abuf) {
  __shared__ __align__(16) u16 As[256 * 32];
  __shared__ __align__(16) u16 Bs[16 * 32];
  const int tid = threadIdx.x;
  const int brow = blockIdx.x * 256;
  const int l = tid & 63, wid = tid >> 6;
  const int la = l & 15, kb8 = (l >> 4) * 8;
  const int sr = tid >> 2, se = (tid & 3) * 8;

  f32x4 acc[4];
#pragma unroll
  for (int mi = 0; mi < 4; ++mi) acc[mi] = (f32x4){0.f, 0.f, 0.f, 0.f};

  for (int kt = 0; kt < 32; ++kt) {
    const int k0 = kt * 32;
    __syncthreads();
#pragma unroll
    for (int i = 0; i < 4; ++i)
      gl2lds16(xb + (size_t)(brow + i * 64 + sr) * DD + k0 + se,
               &As[i * 2048 + wid * 512]);
    if (wid == 0)
      gl2lds16(WaT + (size_t)(l >> 2) * DD + k0 + (l & 3) * 8, &Bs[0]);
    __syncthreads();
    union { u16x8 u; bf16x8 b; } cvb;
    cvb.u = *(const u16x8*)&Bs[la * 32 + kb8];
#pragma unroll
    for (int mi = 0; mi < 4; ++mi) {
      union { u16x8 u; bf16x8 b; } cva;
      cva.u = *(const u16x8*)&As[(wid * 64 + mi * 16 + la) * 32 + kb8];
      acc[mi] = __builtin_amdgcn_mfma_f32_16x16x32_bf16(cva.b, cvb.b, acc[mi], 0, 0, 0);
    }
  }
  const float bav = ba[la];
#pragma unroll
  for (int mi = 0; mi < 4; ++mi)
#pragma unroll
    for (int rr = 0; rr < 4; ++rr) {
      int row = brow + wid * 64 + mi * 16 + ((l >> 4) << 2) + rr;
      float t = acc[mi][rr] + bav + 2.0f;
      abuf[(size_t)row * HH + la] = 1.f / (1.f + __expf(-t));
    }
}

// ---------------------------------------------------------------------------
// bf16 MFMA GEMM, minimal-barrier double-buffer: 256x256 tile, BK=64,
// 8 waves, ONE vmcnt(0)+s_barrier per K-tile (staging targets opposite
// buffer; intra-tile ds_reads/MFMAs free to interleave; waves drift ->
// LDS pipe overlaps matrix pipe). B-fragments read once, reused across
// both M-halves (24 ds_read_b128 / wave / K-tile). T2 swizzle via
// pre-swizzled global source. setprio(1) around MFMA clusters (T5).
// ROUTE=1: fused QKV (N=3072) routed bf16 epilogue w/ elu+1 on q/k.
// ROUTE=0: f32 output.  NCT = col-tile count.
// ---------------------------------------------------------------------------
template<int NCT, int ROUTE>
__global__ __launch_bounds__(512)
void gemm_db(const u16* __restrict__ A, const u16* __restrict__ Bt,
             void* __restrict__ Cout) {
  __shared__ __align__(16) u16 As[2][256 * 64];
  __shared__ __align__(16) u16 Bs[2][256 * 64];
  const int tid = threadIdx.x;
  const int nwg = gridDim.x;
  const int f = blockIdx.x;
  const int swz = (f & 7) * (nwg >> 3) + (f >> 3);
  const int brow = (swz / NCT) * 256;
  const int bcol = (swz % NCT) * 256;
  const int l = tid & 63;
  const int wid = tid >> 6;       // 0..7
  const int wr = wid >> 2;        // 0..1  (M half)
  const int wc = wid & 3;         // 0..3  (N quarter)
  const int la = l & 15, kb8 = (l >> 4) * 8;
  const int K = 1024;
  // staging geometry: per K-tile a wave stages 4 A-chunks + 4 B-chunks (16B/lane)
  const int srow = l >> 3;                       // row within 8-row chunk
  const int scol = ((l & 7) * 8) ^ (srow << 3);  // pre-swizzled global col (u16)
  const int ldso = (wid * 2) * 512;              // wave chunk base (u16) within half

  f32x4 acc[8][4];
#pragma unroll
  for (int i = 0; i < 8; ++i)
#pragma unroll
    for (int j = 0; j < 4; ++j) acc[i][j] = (f32x4){0.f, 0.f, 0.f, 0.f};

  // prologue: stage K-tile 0 into buf 0
#pragma unroll
  for (int h = 0; h < 2; ++h)
#pragma unroll
    for (int j = 0; j < 2; ++j) {
      const int r0 = h * 128 + (wid * 2 + j) * 8 + srow;
      gl2lds16(A  + (size_t)(brow + r0) * K + scol, &As[0][h * 8192 + ldso + j * 512]);
      gl2lds16(Bt + (size_t)(bcol + r0) * K + scol, &Bs[0][h * 8192 + ldso + j * 512]);
    }
  asm volatile("s_waitcnt vmcnt(0)" ::: "memory");
  __builtin_amdgcn_s_barrier();

  const int NKT = K / 64;
  for (int kt = 0; kt < NKT; ++kt) {
    const u16* lA = As[kt & 1];
    const u16* lB = Bs[kt & 1];
    u16* nA = As[(kt + 1) & 1];
    u16* nB = Bs[(kt + 1) & 1];
    const int knext = (kt + 1) * 64;
    const bool more = (kt + 1 < NKT);

    bf16x8 af[4][2], bfr[4][2];
    // fragments: M-half 0 + all B quarters
#pragma unroll
    for (int m2 = 0; m2 < 4; ++m2)
#pragma unroll
      for (int kk = 0; kk < 2; ++kk)
        af[m2][kk] = ldsw(lA, wr * 128 + m2 * 16 + la, kk * 32 + kb8);
#pragma unroll
    for (int n2 = 0; n2 < 4; ++n2)
#pragma unroll
      for (int kk = 0; kk < 2; ++kk)
        bfr[n2][kk] = ldsw(lB, wc * 64 + n2 * 16 + la, kk * 32 + kb8);

    __builtin_amdgcn_s_setprio(1);
#pragma unroll
    for (int m2 = 0; m2 < 4; ++m2)
#pragma unroll
      for (int n2 = 0; n2 < 4; ++n2)
#pragma unroll
        for (int kk = 0; kk < 2; ++kk)
          acc[m2][n2] = __builtin_amdgcn_mfma_f32_16x16x32_bf16(
              af[m2][kk], bfr[n2][kk], acc[m2][n2], 0, 0, 0);
    __builtin_amdgcn_s_setprio(0);

    // fragments: M-half 1 (reuse af regs; bfr persists)
#pragma unroll
    for (int m2 = 0; m2 < 4; ++m2)
#pragma unroll
      for (int kk = 0; kk < 2; ++kk)
        af[m2][kk] = ldsw(lA, wr * 128 + 64 + m2 * 16 + la, kk * 32 + kb8);

    // stage next K-tile (no ds_read follows within this tile)
    if (more) {
#pragma unroll
      for (int h = 0; h < 2; ++h)
#pragma unroll
        for (int j = 0; j < 2; ++j) {
          const int r0 = h * 128 + (wid * 2 + j) * 8 + srow;
          gl2lds16(A  + (size_t)(brow + r0) * K + knext + scol,
                   nA + h * 8192 + ldso + j * 512);
          gl2lds16(Bt + (size_t)(bcol + r0) * K + knext + scol,
                   nB + h * 8192 + ldso + j * 512);
        }
    }

    __builtin_amdgcn_s_setprio(1);
#pragma unroll
    for (int m2 = 0; m2 < 4; ++m2)
#pragma unroll
      for (int n2 = 0; n2 < 4; ++n2)
#pragma unroll
        for (int kk = 0; kk < 2; ++kk)
          acc[4 + m2][n2] = __builtin_amdgcn_mfma_f32_16x16x32_bf16(
              af[m2][kk], bfr[n2][kk], acc[4 + m2][n2], 0, 0, 0);
    __builtin_amdgcn_s_setprio(0);

    if (more) {
      asm volatile("s_waitcnt vmcnt(0)" ::: "memory");
      __builtin_amdgcn_s_barrier();
    }
  }

  const int wrow = wr * 128, wcol = wc * 64;
  if (ROUTE) {
    u16* base = (u16*)Cout + (size_t)(bcol >> 10) * ((size_t)MM * 1024);
    const bool act = (bcol < 2048);
#pragma unroll
    for (int mi = 0; mi < 8; ++mi)
#pragma unroll
      for (int ni = 0; ni < 4; ++ni)
#pragma unroll
        for (int rr = 0; rr < 4; ++rr) {
          int row = brow + wrow + mi * 16 + ((l >> 4) << 2) + rr;
          int c2 = (bcol & 1023) + wcol + ni * 16 + la;
          float v = acc[mi][ni][rr];
          if (act) v = v > 0.f ? v + 1.f : __expf(v);
          base[(size_t)row * 1024 + c2] = f2bf(v);
        }
  } else {
#pragma unroll
    for (int mi = 0; mi < 8; ++mi)
#pragma unroll
      for (int ni = 0; ni < 4; ++ni)
#pragma unroll
        for (int rr = 0; rr < 4; ++rr) {
          int row = brow + wrow + mi * 16 + ((l >> 4) << 2) + rr;
          int col = bcol + wcol + ni * 16 + la;
          ((float*)Cout)[(size_t)row * 1024 + col] = acc[mi][ni][rr];
        }
  }
}

// ---------------------------------------------------------------------------
// FUSED Kernel A + scan level 1: one block owns one group of GCH=8 chunks.
// Per chunk: cA prefix (wave0), MFMA local state S^T (bf16 layout in regs),
// running within-group prefix in registers -> write per-chunk prefix (bf16),
// z prefix, dp; at end write group aggregates (f32).
// ---------------------------------------------------------------------------
__global__ __launch_bounds__(256)
void chunk_local_scan(const u16* __restrict__ kb, const u16* __restrict__ vb,
                      const float* __restrict__ abuf,
                      u16* __restrict__ Sbuf, float* __restrict__ zbuf,
                      float* __restrict__ cAbuf,
                      float* __restrict__ GAgg, float* __restrict__ zGAgg,
                      float* __restrict__ dpbuf) {
  const int g = blockIdx.x & (NGRP - 1);
  const int bh = blockIdx.x >> 4;
  const int h = bh & (HH - 1);
  const int b = bh >> 4;
  __shared__ __align__(16) u16 KT[64 * 64];   // KT[dk][t] = w_t*k (swizzled)
  __shared__ __align__(16) u16 VTl[64 * 64];  // VTl[dv][t] (swizzled)
  __shared__ float wsh[64];
  __shared__ float dchs;
  const int tid = threadIdx.x;
  const int r = tid >> 2, e = (tid & 3) * 16;
  const int l = tid & 63, w = tid >> 6;
  const int kb8 = (l >> 4) << 3, la = l & 15;
  const int dw = 16 * w + ((l >> 4) << 2);
  const int dkz = tid >> 2, tqz = (tid & 3) * 16, swkz = (dkz & 7) << 3;

  f32x4 run[4];
#pragma unroll
  for (int ni = 0; ni < 4; ++ni) run[ni] = (f32x4){0.f, 0.f, 0.f, 0.f};
  float zrun = 0.f;
  float rp = 1.f;

  for (int i = 0; i < GCH; ++i) {
    const int c = g * GCH + i;
    const int blkc = bh * CCHUNK + c;
    const int rowbase = b * NNLEN + c * LCH;

    // issue k/v loads early (overlap with cA)
    const u16* kp = kb + (size_t)(rowbase + r) * PP + h * DH + e;
    const u16* vp = vb + (size_t)(rowbase + r) * PP + h * DH + e;
    u16x8 k0 = *(const u16x8*)kp, k1 = *(const u16x8*)(kp + 8);
    u16x8 v0 = *(const u16x8*)vp, v1 = *(const u16x8*)(vp + 8);

    if (tid < 64) {
      float v = __logf(abuf[(size_t)(rowbase + tid) * HH + h]);
#pragma unroll
      for (int d = 1; d < 64; d <<= 1) {
        float u = __shfl_up(v, d);
        if (tid >= d) v += u;
      }
      cAbuf[(size_t)blkc * 64 + tid] = v;
      float tot = __shfl(v, 63);
      wsh[tid] = __expf(tot - v);
      if (tid == 0) dchs = __expf(tot);
    }
    __syncthreads();                    // wsh/dchs ready

    {
      const float wt = wsh[r];
#pragma unroll
      for (int j = 0; j < 8; ++j) {
        int d0 = e + j, d1 = e + 8 + j;
        KT[d0 * 64 + (r ^ ((d0 & 7) << 3))] = f2bf(bf2f(k0[j]) * wt);
        KT[d1 * 64 + (r ^ ((d1 & 7) << 3))] = f2bf(bf2f(k1[j]) * wt);
        VTl[d0 * 64 + (r ^ ((d0 & 7) << 3))] = v0[j];
        VTl[d1 * 64 + (r ^ ((d1 & 7) << 3))] = v1[j];
      }
    }
    __syncthreads();                    // KT/VTl ready
    const float dch = dchs;

    f32x4 s[4];
#pragma unroll
    for (int ni = 0; ni < 4; ++ni) s[ni] = (f32x4){0.f, 0.f, 0.f, 0.f};
#pragma unroll
    for (int kk = 0; kk < 2; ++kk) {
      bf16x8 av = ldsw(VTl, 16 * w + la, kk * 32 + kb8);
#pragma unroll
      for (int ni = 0; ni < 4; ++ni)
        s[ni] = __builtin_amdgcn_mfma_f32_16x16x32_bf16(
            av, ldsw(KT, 16 * ni + la, kk * 32 + kb8), s[ni], 0, 0, 0);
    }

    // write within-group prefix (state BEFORE this chunk), then update
    u16* Sc = Sbuf + (size_t)blkc * 4096;
#pragma unroll
    for (int ni = 0; ni < 4; ++ni)
#pragma unroll
      for (int rr = 0; rr < 4; ++rr)
        Sc[(dw + rr) * 64 + 16 * ni + la] = f2bf(run[ni][rr]);
#pragma unroll
    for (int ni = 0; ni < 4; ++ni)
#pragma unroll
      for (int rr = 0; rr < 4; ++rr)
        run[ni][rr] = dch * run[ni][rr] + s[ni][rr];

    // z: zp[dk] = sum_t w_t k[t][dk]
    {
      float zp = 0.f;
#pragma unroll
      for (int i2 = 0; i2 < 16; ++i2)
        zp += bf2f(KT[dkz * 64 + ((tqz + i2) ^ swkz)]);
      zp += __shfl_xor(zp, 1);
      zp += __shfl_xor(zp, 2);
      if ((tid & 3) == 0) zbuf[(size_t)blkc * 64 + dkz] = zrun;
      zrun = dch * zrun + zp;
    }
    if (tid == 0) dpbuf[blkc] = rp;
    rp *= dch;
    __syncthreads();                    // protect wsh/dchs/KT for next iter
  }

  // group aggregates
  float* Ga = GAgg + ((size_t)bh * NGRP + g) * 4096;
#pragma unroll
  for (int ni = 0; ni < 4; ++ni)
#pragma unroll
    for (int rr = 0; rr < 4; ++rr)
      Ga[(dw + rr) * 64 + 16 * ni + la] = run[ni][rr];
  if ((tid & 3) == 0)
    zGAgg[((size_t)bh * NGRP + g) * 64 + dkz] = zrun;
}

// ---------------------------------------------------------------------------
// Scan level 2: across the 16 group aggregates, in place (GAgg -> Gbegin).
// ---------------------------------------------------------------------------
__global__ __launch_bounds__(1024)
void scan_top(float* __restrict__ GAgg, float* __restrict__ zGAgg,
              const float* __restrict__ cAbuf) {
  const int bh = blockIdx.x;
  const size_t cb = (size_t)bh * CCHUNK;
  __shared__ float Dsh[NGRP];
  if (threadIdx.x < NGRP) {
    float s = 0.f;
#pragma unroll
    for (int i = 0; i < GCH; ++i)
      s += cAbuf[(cb + threadIdx.x * GCH + i) * 64 + 63];
    Dsh[threadIdx.x] = __expf(s);
  }
  __syncthreads();
  const int elem = threadIdx.x * 4;
  float* base = GAgg + (size_t)bh * NGRP * 4096;
  f32x4 run = (f32x4){0.f, 0.f, 0.f, 0.f};
  f32x4 cur = *(const f32x4*)&base[elem];
#pragma unroll
  for (int gg = 0; gg < NGRP; ++gg) {
    f32x4 nxt;
    if (gg + 1 < NGRP) nxt = *(const f32x4*)&base[(gg + 1) * 4096 + elem];
    *(f32x4*)&base[gg * 4096 + elem] = run;
    const float D = Dsh[gg];
#pragma unroll
    for (int jj = 0; jj < 4; ++jj) run[jj] = D * run[jj] + cur[jj];
    cur = nxt;
  }
  if (threadIdx.x < 64) {
    float* zb = zGAgg + (size_t)bh * NGRP * 64;
    float zr = 0.f;
#pragma unroll
    for (int gg = 0; gg < NGRP; ++gg) {
      float a = zb[gg * 64 + threadIdx.x];
      zb[gg * 64 + threadIdx.x] = zr;
      zr = Dsh[gg] * zr + a;
    }
  }
}

// ---------------------------------------------------------------------------
// Kernel C (MFMA): per-chunk output.
// S0 = prefix(bf16) + dp * Gbegin(f32);  z0 = zprefix + dp * zGbegin
// ---------------------------------------------------------------------------
__global__ __launch_bounds__(256)
void chunk_out(u16* __restrict__ qb, const u16* __restrict__ kb,
               const u16* __restrict__ vb, const u16* __restrict__ Sbuf,
               const float* __restrict__ zbuf, const float* __restrict__ cAbuf,
               const float* __restrict__ GAgg, const float* __restrict__ zGAgg,
               const float* __restrict__ dpbuf) {
  const int blk = blockIdx.x;
  const int c = blk & (CCHUNK - 1);
  const int h = (blk >> 7) & (HH - 1);
  const int b = blk >> 11;
  const int bh = blk >> 7;
  const int g = c >> 3;
  const int rowbase = b * NNLEN + c * LCH;

  __shared__ __align__(16) u16 Qs[64 * 64];
  __shared__ __align__(16) u16 Ke[64 * 64];
  __shared__ __align__(16) u16 VT[64 * 64];
  __shared__ __align__(16) u16 STs[64 * 64];
  __shared__ __align__(16) u16 Pb[64 * 64];
  __shared__ float cAsh[64], zsh[64], denP[64], qzs[64];

  const int tid = threadIdx.x;
  const int r = tid >> 2, e = (tid & 3) * 16;
  const float dp = dpbuf[blk];

  const u16* qp = qb + (size_t)(rowbase + r) * PP + h * DH + e;
  const u16* kp = kb + (size_t)(rowbase + r) * PP + h * DH + e;
  const u16* vp = vb + (size_t)(rowbase + r) * PP + h * DH + e;
  u16x8 q0 = *(const u16x8*)qp, q1 = *(const u16x8*)(qp + 8);
  u16x8 k0 = *(const u16x8*)kp, k1 = *(const u16x8*)(kp + 8);
  u16x8 v0 = *(const u16x8*)vp, v1 = *(const u16x8*)(vp + 8);
  const u16* sp = Sbuf + (size_t)blk * 4096 + r * 64 + e;
  u16x8 p0 = *(const u16x8*)sp, p1 = *(const u16x8*)(sp + 8);
  const float* gp = GAgg + ((size_t)bh * NGRP + g) * 4096 + r * 64 + e;
  f32x4 g0 = *(const f32x4*)gp, g1 = *(const f32x4*)(gp + 4),
        g2 = *(const f32x4*)(gp + 8), g3 = *(const f32x4*)(gp + 12);
  if (tid < 64) {
    cAsh[tid] = cAbuf[(size_t)blk * 64 + tid];
    zsh[tid] = zbuf[(size_t)blk * 64 + tid]
             + dp * zGAgg[((size_t)bh * NGRP + g) * 64 + tid];
  }
  __syncthreads();

  {
    const float c0c = cAsh[31];
    const int sw = (r & 7) << 3;
    const float qsc = __expf(cAsh[r] - c0c);
    const float ksc = __expf(c0c - cAsh[r]);
    const float ssc = __expf(c0c);
    u16x8 t0, t1, u0, u1, w0, w1;
#pragma unroll
    for (int j = 0; j < 8; ++j) {
      t0[j] = f2bf(bf2f(q0[j]) * qsc);
      t1[j] = f2bf(bf2f(q1[j]) * qsc);
      u0[j] = f2bf(bf2f(k0[j]) * ksc);
      u1[j] = f2bf(bf2f(k1[j]) * ksc);
    }
#pragma unroll
    for (int j = 0; j < 4; ++j) {
      w0[j]     = f2bf((bf2f(p0[j])     + dp * g0[j]) * ssc);
      w0[4 + j] = f2bf((bf2f(p0[4 + j]) + dp * g1[j]) * ssc);
      w1[j]     = f2bf((bf2f(p1[j])     + dp * g2[j]) * ssc);
      w1[4 + j] = f2bf((bf2f(p1[4 + j]) + dp * g3[j]) * ssc);
    }
    *(u16x8*)&Qs[r * 64 + (e ^ sw)] = t0;
    *(u16x8*)&Qs[r * 64 + ((e + 8) ^ sw)] = t1;
    *(u16x8*)&Ke[r * 64 + (e ^ sw)] = u0;
    *(u16x8*)&Ke[r * 64 + ((e + 8) ^ sw)] = u1;
    *(u16x8*)&STs[r * 64 + (e ^ sw)] = w0;
    *(u16x8*)&STs[r * 64 + ((e + 8) ^ sw)] = w1;
#pragma unroll
    for (int j = 0; j < 8; ++j) {
      int d0 = e + j, d1 = e + 8 + j;
      VT[d0 * 64 + (r ^ ((d0 & 7) << 3))] = v0[j];
      VT[d1 * 64 + (r ^ ((d1 & 7) << 3))] = v1[j];
    }
    if (tid < 64) zsh[tid] *= ssc;
  }
  __syncthreads();

  const int l = tid & 63, w = tid >> 6;
  const int kb8 = (l >> 4) << 3, la = l & 15;

  // --- MFMA1: P = Qe @ Ke^T ---
  bf16x8 aq[2];
  f32x4 p[4];
#pragma unroll
  for (int ni = 0; ni < 4; ++ni) p[ni] = (f32x4){0.f, 0.f, 0.f, 0.f};
#pragma unroll
  for (int kk = 0; kk < 2; ++kk) {
    aq[kk] = ldsw(Qs, 16 * w + la, kk * 32 + kb8);
#pragma unroll
    for (int ni = 0; ni < 4; ++ni)
      p[ni] = __builtin_amdgcn_mfma_f32_16x16x32_bf16(
          aq[kk], ldsw(Ke, 16 * ni + la, kk * 32 + kb8), p[ni], 0, 0, 0);
  }

  const int tw = 16 * w + ((l >> 4) << 2);
  float rsum[4] = {0.f, 0.f, 0.f, 0.f};
#pragma unroll
  for (int ni = 0; ni < 4; ++ni)
#pragma unroll
    for (int rr = 0; rr < 4; ++rr) {
      int s = 16 * ni + la, t = tw + rr;
      float v = (s <= t) ? p[ni][rr] : 0.f;
      p[ni][rr] = v;
      rsum[rr] += v;
    }
#pragma unroll
  for (int d = 1; d < 16; d <<= 1)
#pragma unroll
    for (int rr = 0; rr < 4; ++rr) rsum[rr] += __shfl_xor(rsum[rr], d);
  if (la == 0)
#pragma unroll
    for (int rr = 0; rr < 4; ++rr) denP[tw + rr] = rsum[rr];

#pragma unroll
  for (int ni = 0; ni < 4; ++ni)
#pragma unroll
    for (int rr = 0; rr < 4; ++rr) {
      int t = tw + rr, s = 16 * ni + la;
      Pb[t * 64 + (s ^ ((t & 7) << 3))] = f2bf(p[ni][rr]);
    }

  {
    const int tq = tid >> 2, dq = (tid & 3) * 16, swq = (tq & 7) << 3;
    float qzp = 0.f;
#pragma unroll
    for (int i = 0; i < 16; ++i)
      qzp += bf2f(Qs[tq * 64 + ((dq + i) ^ swq)]) * zsh[dq + i];
    qzp += __shfl_xor(qzp, 1);
    qzp += __shfl_xor(qzp, 2);
    if ((tid & 3) == 0) qzs[tq] = qzp;
  }
  __syncthreads();

  // --- MFMA2: O = P@V + Qe@S0e^T ---
  f32x4 o[4];
#pragma unroll
  for (int ni = 0; ni < 4; ++ni) o[ni] = (f32x4){0.f, 0.f, 0.f, 0.f};
#pragma unroll
  for (int kk = 0; kk < 2; ++kk) {
    bf16x8 ap = ldsw(Pb, 16 * w + la, kk * 32 + kb8);
#pragma unroll
    for (int ni = 0; ni < 4; ++ni)
      o[ni] = __builtin_amdgcn_mfma_f32_16x16x32_bf16(
          ap, ldsw(VT, 16 * ni + la, kk * 32 + kb8), o[ni], 0, 0, 0);
  }
#pragma unroll
  for (int kk = 0; kk < 2; ++kk)
#pragma unroll
    for (int ni = 0; ni < 4; ++ni)
      o[ni] = __builtin_amdgcn_mfma_f32_16x16x32_bf16(
          aq[kk], ldsw(STs, 16 * ni + la, kk * 32 + kb8), o[ni], 0, 0, 0);

  float dn[4];
#pragma unroll
  for (int rr = 0; rr < 4; ++rr) dn[rr] = qzs[tw + rr] + denP[tw + rr] + EPSV;
#pragma unroll
  for (int ni = 0; ni < 4; ++ni)
#pragma unroll
    for (int rr = 0; rr < 4; ++rr) {
      int t = tw + rr, dv = 16 * ni + la;
      qb[(size_t)(rowbase + t) * PP + h * DH + dv] = f2bf(o[ni][rr] / dn[rr]);
    }
}

// ---------------------------------------------------------------------------
extern "C" void kernel_launch(void* const* d_in, const int* in_sizes, int n_in,
                              void* d_out, int out_size, void* d_ws, size_t ws_size,
                              hipStream_t stream) {
  const float* x  = (const float*)d_in[0];
  const float* Wq = (const float*)d_in[1];
  const float* Wk = (const float*)d_in[2];
  const float* Wv = (const float*)d_in[3];
  const float* Wo = (const float*)d_in[4];
  const float* Wa = (const float*)d_in[5];
  const float* ba = (const float*)d_in[6];

  char* ws = (char*)d_ws;
  size_t off = 0;
  auto carve = [&](size_t bytes) {
    void* p = ws + off;
    off += (bytes + 255) & ~(size_t)255;
    return p;
  };
  u16* xb   = (u16*)carve((size_t)MM * DD * 2);
  u16* WqT  = (u16*)carve((size_t)PP * DD * 2);  // WqT/WkT/WvT contiguous
  u16* WkT  = (u16*)carve((size_t)PP * DD * 2);
  u16* WvT  = (u16*)carve((size_t)PP * DD * 2);
  u16* WoT  = (u16*)carve((size_t)DD * PP * 2);
  u16* WaT  = (u16*)carve((size_t)HH * DD * 2);
  u16* qb   = (u16*)carve((size_t)MM * PP * 2);  // qb/kb/vb contiguous
  u16* kb   = (u16*)carve((size_t)MM * PP * 2);
  u16* vb   = (u16*)carve((size_t)MM * PP * 2);
  float* abuf  = (float*)carve((size_t)MM * HH * 4);
  u16*  Sbuf   = (u16*)carve((size_t)BBATCH * HH * CCHUNK * 4096 * 2);
  float* zbuf  = (float*)carve((size_t)BBATCH * HH * CCHUNK * 64 * 4);
  float* cAbuf = (float*)carve((size_t)BBATCH * HH * CCHUNK * 64 * 4);
  float* GAgg  = (float*)carve((size_t)BBATCH * HH * NGRP * 4096 * 4);
  float* zGAgg = (float*)carve((size_t)BBATCH * HH * NGRP * 64 * 4);
  float* dpbuf = (float*)carve((size_t)BBATCH * HH * CCHUNK * 4);

  transpose_f32_bf16<<<dim3(32, 32), 256, 0, stream>>>(Wq, WqT);
  transpose_f32_bf16<<<dim3(32, 32), 256, 0, stream>>>(Wk, WkT);
  transpose_f32_bf16<<<dim3(32, 32), 256, 0, stream>>>(Wv, WvT);
  transpose_f32_bf16<<<dim3(32, 32), 256, 0, stream>>>(Wo, WoT);
  wa_prep<<<64, 256, 0, stream>>>(Wa, WaT);
  convert_x<<<MM * DD / 8 / 256, 256, 0, stream>>>(x, xb);
  a_proj<<<MM / 256, 256, 0, stream>>>(xb, WaT, ba, abuf);

  // fused QKV: M=16384, N=3072 (WqT/WkT/WvT contiguous), routed epilogue
  gemm_db<12, 1><<<(MM / 256) * 12, 512, 0, stream>>>(xb, WqT, qb);

  chunk_local_scan<<<BBATCH * HH * NGRP, 256, 0, stream>>>(
      kb, vb, abuf, Sbuf, zbuf, cAbuf, GAgg, zGAgg, dpbuf);
  scan_top<<<BBATCH * HH, 1024, 0, stream>>>(GAgg, zGAgg, cAbuf);
  chunk_out<<<BBATCH * HH * CCHUNK, 256, 0, stream>>>(qb, kb, vb, Sbuf, zbuf, cAbuf,
                                                      GAgg, zGAgg, dpbuf);

  gemm_db<4, 0><<<(MM / 256) * 4, 512, 0, stream>>>(qb, WoT, (float*)d_out);
}

// Round 7
// 271.644 us; speedup vs baseline: 1.9876x; 1.0031x over previous
//
#include <hip/hip_runtime.h>
#include <stdint.h>

#define HH 16
#define DH 64
#define DD 1024
#define PP 1024
#define NNLEN 8192
#define BBATCH 2
#define MM (BBATCH*NNLEN)   // 16384 rows
#define CCHUNK 128          // chunks per (b,h)
#define LCH 64              // chunk length
#define NGRP 16             // scan groups per (b,h)
#define GCH 8               // chunks per group
#define EPSV 1e-6f

typedef unsigned short u16;
typedef __attribute__((ext_vector_type(4))) unsigned short u16x4;
typedef __attribute__((ext_vector_type(8))) unsigned short u16x8;
typedef __attribute__((ext_vector_type(8))) __bf16 bf16x8;
typedef __attribute__((ext_vector_type(4))) float f32x4;

__device__ __forceinline__ u16 f2bf(float f) {
  unsigned x = __float_as_uint(f);
  return (u16)((x + 0x7fffu + ((x >> 16) & 1u)) >> 16);
}
__device__ __forceinline__ float bf2f(u16 u) {
  return __uint_as_float(((unsigned)u) << 16);
}

// async global->LDS, 16B per lane. LDS dest must be wave-uniform base.
__device__ __forceinline__ void gl2lds16(const void* g, void* l) {
  __builtin_amdgcn_global_load_lds(
      reinterpret_cast<__attribute__((address_space(1))) void*>(
          reinterpret_cast<uintptr_t>(g)),
      reinterpret_cast<__attribute__((address_space(3))) void*>(
          reinterpret_cast<uintptr_t>(l)),
      16, 0, 0);
}

// swizzled LDS read of a bf16x8 fragment from a [*][64] u16 tile.
// u16 col ^= ((row&7)<<3)  (16B granule involution)
__device__ __forceinline__ bf16x8 ldsw(const u16* base, int row, int col) {
  union { u16x8 u; bf16x8 b; } cv;
  cv.u = *(const u16x8*)&base[row * 64 + (col ^ ((row & 7) << 3))];
  return cv.b;
}

// ---------------------------------------------------------------------------
// x f32 -> bf16, pure streaming (8 elems/thread)
// ---------------------------------------------------------------------------
__global__ __launch_bounds__(256)
void convert_x(const float* __restrict__ in, u16* __restrict__ out) {
  size_t i = ((size_t)blockIdx.x * 256 + threadIdx.x) * 8;
  f32x4 a = *(const f32x4*)(in + i);
  f32x4 b = *(const f32x4*)(in + i + 4);
  u16x8 o;
  o[0] = f2bf(a[0]); o[1] = f2bf(a[1]); o[2] = f2bf(a[2]); o[3] = f2bf(a[3]);
  o[4] = f2bf(b[0]); o[5] = f2bf(b[1]); o[6] = f2bf(b[2]); o[7] = f2bf(b[3]);
  *(u16x8*)(out + i) = o;
}

// Wa[1024][16] f32 -> WaT[16][1024] bf16
__global__ __launch_bounds__(256)
void wa_prep(const float* __restrict__ Wa, u16* __restrict__ WaT) {
  int idx = blockIdx.x * 256 + threadIdx.x;  // 16384
  WaT[idx] = f2bf(Wa[(idx & 1023) * 16 + (idx >> 10)]);
}

// ---------------------------------------------------------------------------
// transpose 1024x1024 f32 -> bf16 (out[n][k] = in[k][n])
// ---------------------------------------------------------------------------
__global__ __launch_bounds__(256)
void transpose_f32_bf16(const float* __restrict__ in, u16* __restrict__ out) {
  __shared__ float tile[32][33];
  int bx = blockIdx.x * 32, by = blockIdx.y * 32;
  int tx = threadIdx.x & 31, ty = threadIdx.x >> 5;  // ty 0..7
  for (int i = ty; i < 32; i += 8)
    tile[i][tx] = in[(size_t)(by + i) * 1024 + bx + tx];
  __syncthreads();
  for (int i = ty; i < 32; i += 8)
    out[(size_t)(bx + i) * 1024 + by + tx] = f2bf(tile[tx][i]);
}

// ---------------------------------------------------------------------------
// a_proj (MFMA skinny GEMM): abuf = sigmoid(xb @ Wa + ba + 2), M=16384 N=16
// ---------------------------------------------------------------------------
__global__ __launch_bounds__(256)
void a_proj(const u16* __restrict__ xb, const u16* __restrict__ WaT,
            const float* __restrict__ ba, float* __restrict__ abuf) {
  __shared__ __align__(16) u16 As[256 * 32];
  __shared__ __align__(16) u16 Bs[16 * 32];
  const int tid = threadIdx.x;
  const int brow = blockIdx.x * 256;
  const int l = tid & 63, wid = tid >> 6;
  const int la = l & 15, kb8 = (l >> 4) * 8;
  const int sr = tid >> 2, se = (tid & 3) * 8;

  f32x4 acc[4];
#pragma unroll
  for (int mi = 0; mi < 4; ++mi) acc[mi] = (f32x4){0.f, 0.f, 0.f, 0.f};

  for (int kt = 0; kt < 32; ++kt) {
    const int k0 = kt * 32;
    __syncthreads();
#pragma unroll
    for (int i = 0; i < 4; ++i)
      gl2lds16(xb + (size_t)(brow + i * 64 + sr) * DD + k0 + se,
               &As[i * 2048 + wid * 512]);
    if (wid == 0)
      gl2lds16(WaT + (size_t)(l >> 2) * DD + k0 + (l & 3) * 8, &Bs[0]);
    __syncthreads();
    union { u16x8 u; bf16x8 b; } cvb;
    cvb.u = *(const u16x8*)&Bs[la * 32 + kb8];
#pragma unroll
    for (int mi = 0; mi < 4; ++mi) {
      union { u16x8 u; bf16x8 b; } cva;
      cva.u = *(const u16x8*)&As[(wid * 64 + mi * 16 + la) * 32 + kb8];
      acc[mi] = __builtin_amdgcn_mfma_f32_16x16x32_bf16(cva.b, cvb.b, acc[mi], 0, 0, 0);
    }
  }
  const float bav = ba[la];
#pragma unroll
  for (int mi = 0; mi < 4; ++mi)
#pragma unroll
    for (int rr = 0; rr < 4; ++rr) {
      int row = brow + wid * 64 + mi * 16 + ((l >> 4) << 2) + rr;
      float t = acc[mi][rr] + bav + 2.0f;
      abuf[(size_t)row * HH + la] = 1.f / (1.f + __expf(-t));
    }
}

// ---------------------------------------------------------------------------
// bf16 MFMA GEMM, minimal-barrier double-buffer, STAGE-FIRST:
// 256x256 tile, BK=64, 8 waves. All 8 staging gl2lds for tile t+1 issued at
// the TOP of tile t (full-tile latency cover), ONE vmcnt(0)+s_barrier per
// K-tile. B-fragments read once, reused across both M-halves. T2 swizzle
// via pre-swizzled global source. setprio(1) around MFMA clusters.
// ROUTE=1: fused QKV (N=3072) routed bf16 epilogue w/ elu+1 on q/k.
// ROUTE=0: f32 output.  NCT = col-tile count.
// ---------------------------------------------------------------------------
template<int NCT, int ROUTE>
__global__ __launch_bounds__(512)
void gemm_db(const u16* __restrict__ A, const u16* __restrict__ Bt,
             void* __restrict__ Cout) {
  __shared__ __align__(16) u16 As[2][256 * 64];
  __shared__ __align__(16) u16 Bs[2][256 * 64];
  const int tid = threadIdx.x;
  const int nwg = gridDim.x;
  const int f = blockIdx.x;
  const int swz = (f & 7) * (nwg >> 3) + (f >> 3);
  const int brow = (swz / NCT) * 256;
  const int bcol = (swz % NCT) * 256;
  const int l = tid & 63;
  const int wid = tid >> 6;       // 0..7
  const int wr = wid >> 2;        // 0..1  (M half)
  const int wc = wid & 3;         // 0..3  (N quarter)
  const int la = l & 15, kb8 = (l >> 4) * 8;
  const int K = 1024;
  // staging geometry: per K-tile a wave stages 4 A-chunks + 4 B-chunks (16B/lane)
  const int srow = l >> 3;                       // row within 8-row chunk
  const int scol = ((l & 7) * 8) ^ (srow << 3);  // pre-swizzled global col (u16)
  const int ldso = (wid * 2) * 512;              // wave chunk base (u16) within half

  f32x4 acc[8][4];
#pragma unroll
  for (int i = 0; i < 8; ++i)
#pragma unroll
    for (int j = 0; j < 4; ++j) acc[i][j] = (f32x4){0.f, 0.f, 0.f, 0.f};

  // prologue: stage K-tile 0 into buf 0
#pragma unroll
  for (int h = 0; h < 2; ++h)
#pragma unroll
    for (int j = 0; j < 2; ++j) {
      const int r0 = h * 128 + (wid * 2 + j) * 8 + srow;
      gl2lds16(A  + (size_t)(brow + r0) * K + scol, &As[0][h * 8192 + ldso + j * 512]);
      gl2lds16(Bt + (size_t)(bcol + r0) * K + scol, &Bs[0][h * 8192 + ldso + j * 512]);
    }
  asm volatile("s_waitcnt vmcnt(0)" ::: "memory");
  __builtin_amdgcn_s_barrier();

  const int NKT = K / 64;
  for (int kt = 0; kt < NKT; ++kt) {
    const u16* lA = As[kt & 1];
    const u16* lB = Bs[kt & 1];
    u16* nA = As[(kt + 1) & 1];
    u16* nB = Bs[(kt + 1) & 1];
    const int knext = (kt + 1) * 64;
    const bool more = (kt + 1 < NKT);

    // stage next K-tile FIRST: the whole tile's compute covers the latency,
    // so the end-of-tile vmcnt(0) is ~free.
    if (more) {
#pragma unroll
      for (int h = 0; h < 2; ++h)
#pragma unroll
        for (int j = 0; j < 2; ++j) {
          const int r0 = h * 128 + (wid * 2 + j) * 8 + srow;
          gl2lds16(A  + (size_t)(brow + r0) * K + knext + scol,
                   nA + h * 8192 + ldso + j * 512);
          gl2lds16(Bt + (size_t)(bcol + r0) * K + knext + scol,
                   nB + h * 8192 + ldso + j * 512);
        }
    }

    bf16x8 af[4][2], bfr[4][2];
    // fragments: M-half 0 + all B quarters
#pragma unroll
    for (int m2 = 0; m2 < 4; ++m2)
#pragma unroll
      for (int kk = 0; kk < 2; ++kk)
        af[m2][kk] = ldsw(lA, wr * 128 + m2 * 16 + la, kk * 32 + kb8);
#pragma unroll
    for (int n2 = 0; n2 < 4; ++n2)
#pragma unroll
      for (int kk = 0; kk < 2; ++kk)
        bfr[n2][kk] = ldsw(lB, wc * 64 + n2 * 16 + la, kk * 32 + kb8);

    __builtin_amdgcn_s_setprio(1);
#pragma unroll
    for (int m2 = 0; m2 < 4; ++m2)
#pragma unroll
      for (int n2 = 0; n2 < 4; ++n2)
#pragma unroll
        for (int kk = 0; kk < 2; ++kk)
          acc[m2][n2] = __builtin_amdgcn_mfma_f32_16x16x32_bf16(
              af[m2][kk], bfr[n2][kk], acc[m2][n2], 0, 0, 0);
    __builtin_amdgcn_s_setprio(0);

    // fragments: M-half 1 (reuse af regs; bfr persists)
#pragma unroll
    for (int m2 = 0; m2 < 4; ++m2)
#pragma unroll
      for (int kk = 0; kk < 2; ++kk)
        af[m2][kk] = ldsw(lA, wr * 128 + 64 + m2 * 16 + la, kk * 32 + kb8);

    __builtin_amdgcn_s_setprio(1);
#pragma unroll
    for (int m2 = 0; m2 < 4; ++m2)
#pragma unroll
      for (int n2 = 0; n2 < 4; ++n2)
#pragma unroll
        for (int kk = 0; kk < 2; ++kk)
          acc[4 + m2][n2] = __builtin_amdgcn_mfma_f32_16x16x32_bf16(
              af[m2][kk], bfr[n2][kk], acc[4 + m2][n2], 0, 0, 0);
    __builtin_amdgcn_s_setprio(0);

    if (more) {
      asm volatile("s_waitcnt vmcnt(0)" ::: "memory");
      __builtin_amdgcn_s_barrier();
    }
  }

  const int wrow = wr * 128, wcol = wc * 64;
  if (ROUTE) {
    u16* base = (u16*)Cout + (size_t)(bcol >> 10) * ((size_t)MM * 1024);
    const bool act = (bcol < 2048);
#pragma unroll
    for (int mi = 0; mi < 8; ++mi)
#pragma unroll
      for (int ni = 0; ni < 4; ++ni)
#pragma unroll
        for (int rr = 0; rr < 4; ++rr) {
          int row = brow + wrow + mi * 16 + ((l >> 4) << 2) + rr;
          int c2 = (bcol & 1023) + wcol + ni * 16 + la;
          float v = acc[mi][ni][rr];
          if (act) v = v > 0.f ? v + 1.f : __expf(v);
          base[(size_t)row * 1024 + c2] = f2bf(v);
        }
  } else {
#pragma unroll
    for (int mi = 0; mi < 8; ++mi)
#pragma unroll
      for (int ni = 0; ni < 4; ++ni)
#pragma unroll
        for (int rr = 0; rr < 4; ++rr) {
          int row = brow + wrow + mi * 16 + ((l >> 4) << 2) + rr;
          int col = bcol + wcol + ni * 16 + la;
          ((float*)Cout)[(size_t)row * 1024 + col] = acc[mi][ni][rr];
        }
  }
}

// ---------------------------------------------------------------------------
// FUSED Kernel A + scan level 1: one block owns one group of GCH=8 chunks.
// ---------------------------------------------------------------------------
__global__ __launch_bounds__(256)
void chunk_local_scan(const u16* __restrict__ kb, const u16* __restrict__ vb,
                      const float* __restrict__ abuf,
                      u16* __restrict__ Sbuf, float* __restrict__ zbuf,
                      float* __restrict__ cAbuf,
                      float* __restrict__ GAgg, float* __restrict__ zGAgg,
                      float* __restrict__ dpbuf) {
  const int g = blockIdx.x & (NGRP - 1);
  const int bh = blockIdx.x >> 4;
  const int h = bh & (HH - 1);
  const int b = bh >> 4;
  __shared__ __align__(16) u16 KT[64 * 64];   // KT[dk][t] = w_t*k (swizzled)
  __shared__ __align__(16) u16 VTl[64 * 64];  // VTl[dv][t] (swizzled)
  __shared__ float wsh[64];
  __shared__ float dchs;
  const int tid = threadIdx.x;
  const int r = tid >> 2, e = (tid & 3) * 16;
  const int l = tid & 63, w = tid >> 6;
  const int kb8 = (l >> 4) << 3, la = l & 15;
  const int dw = 16 * w + ((l >> 4) << 2);
  const int dkz = tid >> 2, tqz = (tid & 3) * 16, swkz = (dkz & 7) << 3;

  f32x4 run[4];
#pragma unroll
  for (int ni = 0; ni < 4; ++ni) run[ni] = (f32x4){0.f, 0.f, 0.f, 0.f};
  float zrun = 0.f;
  float rp = 1.f;

  for (int i = 0; i < GCH; ++i) {
    const int c = g * GCH + i;
    const int blkc = bh * CCHUNK + c;
    const int rowbase = b * NNLEN + c * LCH;

    const u16* kp = kb + (size_t)(rowbase + r) * PP + h * DH + e;
    const u16* vp = vb + (size_t)(rowbase + r) * PP + h * DH + e;
    u16x8 k0 = *(const u16x8*)kp, k1 = *(const u16x8*)(kp + 8);
    u16x8 v0 = *(const u16x8*)vp, v1 = *(const u16x8*)(vp + 8);

    if (tid < 64) {
      float v = __logf(abuf[(size_t)(rowbase + tid) * HH + h]);
#pragma unroll
      for (int d = 1; d < 64; d <<= 1) {
        float u = __shfl_up(v, d);
        if (tid >= d) v += u;
      }
      cAbuf[(size_t)blkc * 64 + tid] = v;
      float tot = __shfl(v, 63);
      wsh[tid] = __expf(tot - v);
      if (tid == 0) dchs = __expf(tot);
    }
    __syncthreads();                    // wsh/dchs ready

    {
      const float wt = wsh[r];
#pragma unroll
      for (int j = 0; j < 8; ++j) {
        int d0 = e + j, d1 = e + 8 + j;
        KT[d0 * 64 + (r ^ ((d0 & 7) << 3))] = f2bf(bf2f(k0[j]) * wt);
        KT[d1 * 64 + (r ^ ((d1 & 7) << 3))] = f2bf(bf2f(k1[j]) * wt);
        VTl[d0 * 64 + (r ^ ((d0 & 7) << 3))] = v0[j];
        VTl[d1 * 64 + (r ^ ((d1 & 7) << 3))] = v1[j];
      }
    }
    __syncthreads();                    // KT/VTl ready
    const float dch = dchs;

    f32x4 s[4];
#pragma unroll
    for (int ni = 0; ni < 4; ++ni) s[ni] = (f32x4){0.f, 0.f, 0.f, 0.f};
#pragma unroll
    for (int kk = 0; kk < 2; ++kk) {
      bf16x8 av = ldsw(VTl, 16 * w + la, kk * 32 + kb8);
#pragma unroll
      for (int ni = 0; ni < 4; ++ni)
        s[ni] = __builtin_amdgcn_mfma_f32_16x16x32_bf16(
            av, ldsw(KT, 16 * ni + la, kk * 32 + kb8), s[ni], 0, 0, 0);
    }

    // write within-group prefix (state BEFORE this chunk), then update
    u16* Sc = Sbuf + (size_t)blkc * 4096;
#pragma unroll
    for (int ni = 0; ni < 4; ++ni)
#pragma unroll
      for (int rr = 0; rr < 4; ++rr)
        Sc[(dw + rr) * 64 + 16 * ni + la] = f2bf(run[ni][rr]);
#pragma unroll
    for (int ni = 0; ni < 4; ++ni)
#pragma unroll
      for (int rr = 0; rr < 4; ++rr)
        run[ni][rr] = dch * run[ni][rr] + s[ni][rr];

    // z: zp[dk] = sum_t w_t k[t][dk]
    {
      float zp = 0.f;
#pragma unroll
      for (int i2 = 0; i2 < 16; ++i2)
        zp += bf2f(KT[dkz * 64 + ((tqz + i2) ^ swkz)]);
      zp += __shfl_xor(zp, 1);
      zp += __shfl_xor(zp, 2);
      if ((tid & 3) == 0) zbuf[(size_t)blkc * 64 + dkz] = zrun;
      zrun = dch * zrun + zp;
    }
    if (tid == 0) dpbuf[blkc] = rp;
    rp *= dch;
    __syncthreads();                    // protect wsh/dchs/KT for next iter
  }

  // group aggregates
  float* Ga = GAgg + ((size_t)bh * NGRP + g) * 4096;
#pragma unroll
  for (int ni = 0; ni < 4; ++ni)
#pragma unroll
    for (int rr = 0; rr < 4; ++rr)
      Ga[(dw + rr) * 64 + 16 * ni + la] = run[ni][rr];
  if ((tid & 3) == 0)
    zGAgg[((size_t)bh * NGRP + g) * 64 + dkz] = zrun;
}

// ---------------------------------------------------------------------------
// Scan level 2: across the 16 group aggregates, in place (GAgg -> Gbegin).
// ---------------------------------------------------------------------------
__global__ __launch_bounds__(1024)
void scan_top(float* __restrict__ GAgg, float* __restrict__ zGAgg,
              const float* __restrict__ cAbuf) {
  const int bh = blockIdx.x;
  const size_t cb = (size_t)bh * CCHUNK;
  __shared__ float Dsh[NGRP];
  if (threadIdx.x < NGRP) {
    float s = 0.f;
#pragma unroll
    for (int i = 0; i < GCH; ++i)
      s += cAbuf[(cb + threadIdx.x * GCH + i) * 64 + 63];
    Dsh[threadIdx.x] = __expf(s);
  }
  __syncthreads();
  const int elem = threadIdx.x * 4;
  float* base = GAgg + (size_t)bh * NGRP * 4096;
  f32x4 run = (f32x4){0.f, 0.f, 0.f, 0.f};
  f32x4 cur = *(const f32x4*)&base[elem];
#pragma unroll
  for (int gg = 0; gg < NGRP; ++gg) {
    f32x4 nxt;
    if (gg + 1 < NGRP) nxt = *(const f32x4*)&base[(gg + 1) * 4096 + elem];
    *(f32x4*)&base[gg * 4096 + elem] = run;
    const float D = Dsh[gg];
#pragma unroll
    for (int jj = 0; jj < 4; ++jj) run[jj] = D * run[jj] + cur[jj];
    cur = nxt;
  }
  if (threadIdx.x < 64) {
    float* zb = zGAgg + (size_t)bh * NGRP * 64;
    float zr = 0.f;
#pragma unroll
    for (int gg = 0; gg < NGRP; ++gg) {
      float a = zb[gg * 64 + threadIdx.x];
      zb[gg * 64 + threadIdx.x] = zr;
      zr = Dsh[gg] * zr + a;
    }
  }
}

// ---------------------------------------------------------------------------
// Kernel C (MFMA): per-chunk output.
// S0 = prefix(bf16) + dp * Gbegin(f32);  z0 = zprefix + dp * zGbegin
// LDS-lean version: qz from register fragments (shfl reduce); P tile
// overwrites the dead Ke tile (barrier-protected) -> 33KB LDS, 4 blocks/CU.
// ---------------------------------------------------------------------------
__global__ __launch_bounds__(256)
void chunk_out(u16* __restrict__ qb, const u16* __restrict__ kb,
               const u16* __restrict__ vb, const u16* __restrict__ Sbuf,
               const float* __restrict__ zbuf, const float* __restrict__ cAbuf,
               const float* __restrict__ GAgg, const float* __restrict__ zGAgg,
               const float* __restrict__ dpbuf) {
  const int blk = blockIdx.x;
  const int c = blk & (CCHUNK - 1);
  const int h = (blk >> 7) & (HH - 1);
  const int b = blk >> 11;
  const int bh = blk >> 7;
  const int g = c >> 3;
  const int rowbase = b * NNLEN + c * LCH;

  __shared__ __align__(16) u16 Qs[64 * 64];
  __shared__ __align__(16) u16 Ke[64 * 64];   // Ke, later reused as P tile
  __shared__ __align__(16) u16 VT[64 * 64];
  __shared__ __align__(16) u16 STs[64 * 64];
  __shared__ float cAsh[64], zsh[64], denP[64], qzs[64];

  const int tid = threadIdx.x;
  const int r = tid >> 2, e = (tid & 3) * 16;
  const float dp = dpbuf[blk];

  const u16* qp = qb + (size_t)(rowbase + r) * PP + h * DH + e;
  const u16* kp = kb + (size_t)(rowbase + r) * PP + h * DH + e;
  const u16* vp = vb + (size_t)(rowbase + r) * PP + h * DH + e;
  u16x8 q0 = *(const u16x8*)qp, q1 = *(const u16x8*)(qp + 8);
  u16x8 k0 = *(const u16x8*)kp, k1 = *(const u16x8*)(kp + 8);
  u16x8 v0 = *(const u16x8*)vp, v1 = *(const u16x8*)(vp + 8);
  const u16* sp = Sbuf + (size_t)blk * 4096 + r * 64 + e;
  u16x8 p0 = *(const u16x8*)sp, p1 = *(const u16x8*)(sp + 8);
  const float* gp = GAgg + ((size_t)bh * NGRP + g) * 4096 + r * 64 + e;
  f32x4 g0 = *(const f32x4*)gp, g1 = *(const f32x4*)(gp + 4),
        g2 = *(const f32x4*)(gp + 8), g3 = *(const f32x4*)(gp + 12);
  if (tid < 64) {
    cAsh[tid] = cAbuf[(size_t)blk * 64 + tid];
    zsh[tid] = zbuf[(size_t)blk * 64 + tid]
             + dp * zGAgg[((size_t)bh * NGRP + g) * 64 + tid];
  }
  __syncthreads();

  {
    const float c0c = cAsh[31];
    const int sw = (r & 7) << 3;
    const float qsc = __expf(cAsh[r] - c0c);
    const float ksc = __expf(c0c - cAsh[r]);
    const float ssc = __expf(c0c);
    u16x8 t0, t1, u0, u1, w0, w1;
#pragma unroll
    for (int j = 0; j < 8; ++j) {
      t0[j] = f2bf(bf2f(q0[j]) * qsc);
      t1[j] = f2bf(bf2f(q1[j]) * qsc);
      u0[j] = f2bf(bf2f(k0[j]) * ksc);
      u1[j] = f2bf(bf2f(k1[j]) * ksc);
    }
#pragma unroll
    for (int j = 0; j < 4; ++j) {
      w0[j]     = f2bf((bf2f(p0[j])     + dp * g0[j]) * ssc);
      w0[4 + j] = f2bf((bf2f(p0[4 + j]) + dp * g1[j]) * ssc);
      w1[j]     = f2bf((bf2f(p1[j])     + dp * g2[j]) * ssc);
      w1[4 + j] = f2bf((bf2f(p1[4 + j]) + dp * g3[j]) * ssc);
    }
    *(u16x8*)&Qs[r * 64 + (e ^ sw)] = t0;
    *(u16x8*)&Qs[r * 64 + ((e + 8) ^ sw)] = t1;
    *(u16x8*)&Ke[r * 64 + (e ^ sw)] = u0;
    *(u16x8*)&Ke[r * 64 + ((e + 8) ^ sw)] = u1;
    *(u16x8*)&STs[r * 64 + (e ^ sw)] = w0;
    *(u16x8*)&STs[r * 64 + ((e + 8) ^ sw)] = w1;
#pragma unroll
    for (int j = 0; j < 8; ++j) {
      int d0 = e + j, d1 = e + 8 + j;
      VT[d0 * 64 + (r ^ ((d0 & 7) << 3))] = v0[j];
      VT[d1 * 64 + (r ^ ((d1 & 7) << 3))] = v1[j];
    }
    if (tid < 64) zsh[tid] *= ssc;
  }
  __syncthreads();

  const int l = tid & 63, w = tid >> 6;
  const int kb8 = (l >> 4) << 3, la = l & 15;

  // --- MFMA1: P = Qe @ Ke^T ---
  bf16x8 aq[2];
  f32x4 p[4];
#pragma unroll
  for (int ni = 0; ni < 4; ++ni) p[ni] = (f32x4){0.f, 0.f, 0.f, 0.f};
#pragma unroll
  for (int kk = 0; kk < 2; ++kk) {
    aq[kk] = ldsw(Qs, 16 * w + la, kk * 32 + kb8);
#pragma unroll
    for (int ni = 0; ni < 4; ++ni)
      p[ni] = __builtin_amdgcn_mfma_f32_16x16x32_bf16(
          aq[kk], ldsw(Ke, 16 * ni + la, kk * 32 + kb8), p[ni], 0, 0, 0);
  }

  const int tw = 16 * w + ((l >> 4) << 2);
  float rsum[4] = {0.f, 0.f, 0.f, 0.f};
#pragma unroll
  for (int ni = 0; ni < 4; ++ni)
#pragma unroll
    for (int rr = 0; rr < 4; ++rr) {
      int s = 16 * ni + la, t = tw + rr;
      float v = (s <= t) ? p[ni][rr] : 0.f;
      p[ni][rr] = v;
      rsum[rr] += v;
    }
#pragma unroll
  for (int d = 1; d < 16; d <<= 1)
#pragma unroll
    for (int rr = 0; rr < 4; ++rr) rsum[rr] += __shfl_xor(rsum[rr], d);
  if (la == 0)
#pragma unroll
    for (int rr = 0; rr < 4; ++rr) denP[tw + rr] = rsum[rr];

  // qz[row] = Qe[row] . z0e from register fragments:
  // lane (w, l) holds Q[16w+la][kk*32 + (l>>4)*8 + j]; zsh reads broadcast.
  {
    float qzp = 0.f;
#pragma unroll
    for (int kk = 0; kk < 2; ++kk)
#pragma unroll
      for (int j = 0; j < 8; ++j) {
        union { bf16x8 b; u16x8 u; } cv; cv.b = aq[kk];
        qzp += bf2f(cv.u[j]) * zsh[kk * 32 + kb8 + j];
      }
    qzp += __shfl_xor(qzp, 16);
    qzp += __shfl_xor(qzp, 32);
    if (l < 16) qzs[16 * w + la] = qzp;
  }
  __syncthreads();   // all waves done reading Qs/Ke -> Ke reusable as P

  // write P into (dead) Ke tile, swizzled
#pragma unroll
  for (int ni = 0; ni < 4; ++ni)
#pragma unroll
    for (int rr = 0; rr < 4; ++rr) {
      int t = tw + rr, s = 16 * ni + la;
      Ke[t * 64 + (s ^ ((t & 7) << 3))] = f2bf(p[ni][rr]);
    }
  __syncthreads();

  // --- MFMA2: O = P@V + Qe@S0e^T ---
  f32x4 o[4];
#pragma unroll
  for (int ni = 0; ni < 4; ++ni) o[ni] = (f32x4){0.f, 0.f, 0.f, 0.f};
#pragma unroll
  for (int kk = 0; kk < 2; ++kk) {
    bf16x8 ap = ldsw(Ke, 16 * w + la, kk * 32 + kb8);
#pragma unroll
    for (int ni = 0; ni < 4; ++ni)
      o[ni] = __builtin_amdgcn_mfma_f32_16x16x32_bf16(
          ap, ldsw(VT, 16 * ni + la, kk * 32 + kb8), o[ni], 0, 0, 0);
  }
#pragma unroll
  for (int kk = 0; kk < 2; ++kk)
#pragma unroll
    for (int ni = 0; ni < 4; ++ni)
      o[ni] = __builtin_amdgcn_mfma_f32_16x16x32_bf16(
          aq[kk], ldsw(STs, 16 * ni + la, kk * 32 + kb8), o[ni], 0, 0, 0);

  float dn[4];
#pragma unroll
  for (int rr = 0; rr < 4; ++rr) dn[rr] = qzs[tw + rr] + denP[tw + rr] + EPSV;
#pragma unroll
  for (int ni = 0; ni < 4; ++ni)
#pragma unroll
    for (int rr = 0; rr < 4; ++rr) {
      int t = tw + rr, dv = 16 * ni + la;
      qb[(size_t)(rowbase + t) * PP + h * DH + dv] = f2bf(o[ni][rr] / dn[rr]);
    }
}

// ---------------------------------------------------------------------------
extern "C" void kernel_launch(void* const* d_in, const int* in_sizes, int n_in,
                              void* d_out, int out_size, void* d_ws, size_t ws_size,
                              hipStream_t stream) {
  const float* x  = (const float*)d_in[0];
  const float* Wq = (const float*)d_in[1];
  const float* Wk = (const float*)d_in[2];
  const float* Wv = (const float*)d_in[3];
  const float* Wo = (const float*)d_in[4];
  const float* Wa = (const float*)d_in[5];
  const float* ba = (const float*)d_in[6];

  char* ws = (char*)d_ws;
  size_t off = 0;
  auto carve = [&](size_t bytes) {
    void* p = ws + off;
    off += (bytes + 255) & ~(size_t)255;
    return p;
  };
  u16* xb   = (u16*)carve((size_t)MM * DD * 2);
  u16* WqT  = (u16*)carve((size_t)PP * DD * 2);  // WqT/WkT/WvT contiguous
  u16* WkT  = (u16*)carve((size_t)PP * DD * 2);
  u16* WvT  = (u16*)carve((size_t)PP * DD * 2);
  u16* WoT  = (u16*)carve((size_t)DD * PP * 2);
  u16* WaT  = (u16*)carve((size_t)HH * DD * 2);
  u16* qb   = (u16*)carve((size_t)MM * PP * 2);  // qb/kb/vb contiguous
  u16* kb   = (u16*)carve((size_t)MM * PP * 2);
  u16* vb   = (u16*)carve((size_t)MM * PP * 2);
  float* abuf  = (float*)carve((size_t)MM * HH * 4);
  u16*  Sbuf   = (u16*)carve((size_t)BBATCH * HH * CCHUNK * 4096 * 2);
  float* zbuf  = (float*)carve((size_t)BBATCH * HH * CCHUNK * 64 * 4);
  float* cAbuf = (float*)carve((size_t)BBATCH * HH * CCHUNK * 64 * 4);
  float* GAgg  = (float*)carve((size_t)BBATCH * HH * NGRP * 4096 * 4);
  float* zGAgg = (float*)carve((size_t)BBATCH * HH * NGRP * 64 * 4);
  float* dpbuf = (float*)carve((size_t)BBATCH * HH * CCHUNK * 4);

  transpose_f32_bf16<<<dim3(32, 32), 256, 0, stream>>>(Wq, WqT);
  transpose_f32_bf16<<<dim3(32, 32), 256, 0, stream>>>(Wk, WkT);
  transpose_f32_bf16<<<dim3(32, 32), 256, 0, stream>>>(Wv, WvT);
  transpose_f32_bf16<<<dim3(32, 32), 256, 0, stream>>>(Wo, WoT);
  wa_prep<<<64, 256, 0, stream>>>(Wa, WaT);
  convert_x<<<MM * DD / 8 / 256, 256, 0, stream>>>(x, xb);
  a_proj<<<MM / 256, 256, 0, stream>>>(xb, WaT, ba, abuf);

  // fused QKV: M=16384, N=3072 (WqT/WkT/WvT contiguous), routed epilogue
  gemm_db<12, 1><<<(MM / 256) * 12, 512, 0, stream>>>(xb, WqT, qb);

  chunk_local_scan<<<BBATCH * HH * NGRP, 256, 0, stream>>>(
      kb, vb, abuf, Sbuf, zbuf, cAbuf, GAgg, zGAgg, dpbuf);
  scan_top<<<BBATCH * HH, 1024, 0, stream>>>(GAgg, zGAgg, cAbuf);
  chunk_out<<<BBATCH * HH * CCHUNK, 256, 0, stream>>>(qb, kb, vb, Sbuf, zbuf, cAbuf,
                                                      GAgg, zGAgg, dpbuf);

  gemm_db<4, 0><<<(MM / 256) * 4, 512, 0, stream>>>(qb, WoT, (float*)d_out);
}

// Round 9
// 253.729 us; speedup vs baseline: 2.1280x; 1.0706x over previous
//
#include <hip/hip_runtime.h>
#include <stdint.h>

#define HH 16
#define DH 64
#define DD 1024
#define PP 1024
#define NNLEN 8192
#define BBATCH 2
#define MM (BBATCH*NNLEN)   // 16384 rows
#define CCHUNK 128          // chunks per (b,h)
#define LCH 64              // chunk length
#define NGRP 16             // scan groups per (b,h)
#define GCH 8               // chunks per group
#define EPSV 1e-6f

typedef unsigned short u16;
typedef __attribute__((ext_vector_type(4))) unsigned short u16x4;
typedef __attribute__((ext_vector_type(8))) unsigned short u16x8;
typedef __attribute__((ext_vector_type(8))) __bf16 bf16x8;
typedef __attribute__((ext_vector_type(4))) float f32x4;

__device__ __forceinline__ u16 f2bf(float f) {
  unsigned x = __float_as_uint(f);
  return (u16)((x + 0x7fffu + ((x >> 16) & 1u)) >> 16);
}
__device__ __forceinline__ float bf2f(u16 u) {
  return __uint_as_float(((unsigned)u) << 16);
}

// async global->LDS, 16B per lane. LDS dest must be wave-uniform base.
__device__ __forceinline__ void gl2lds16(const void* g, void* l) {
  __builtin_amdgcn_global_load_lds(
      reinterpret_cast<__attribute__((address_space(1))) void*>(
          reinterpret_cast<uintptr_t>(g)),
      reinterpret_cast<__attribute__((address_space(3))) void*>(
          reinterpret_cast<uintptr_t>(l)),
      16, 0, 0);
}

// swizzled LDS read of a bf16x8 fragment from a [*][64] u16 tile.
// u16 col ^= ((row&7)<<3)  (16B granule involution)
__device__ __forceinline__ bf16x8 ldsw(const u16* base, int row, int col) {
  union { u16x8 u; bf16x8 b; } cv;
  cv.u = *(const u16x8*)&base[row * 64 + (col ^ ((row & 7) << 3))];
  return cv.b;
}

// ---------------------------------------------------------------------------
// prep_all (single launch):
//   blocks [0,8192):      x f32->bf16 streaming (8 elems/thread)
//   blocks [8192,12288):  four 1024x1024 transposes f32->bf16 (Wq,Wk,Wv,Wo)
//   blocks [12288,12352): Wa[1024][16] -> WaT[16][1024] bf16
// ---------------------------------------------------------------------------
__global__ __launch_bounds__(256)
void prep_all(const float* __restrict__ x, u16* __restrict__ xb,
              const float* __restrict__ Wq, u16* __restrict__ WqT,
              const float* __restrict__ Wk, u16* __restrict__ WkT,
              const float* __restrict__ Wv, u16* __restrict__ WvT,
              const float* __restrict__ Wo, u16* __restrict__ WoT,
              const float* __restrict__ Wa, u16* __restrict__ WaT) {
  __shared__ float tile[32][33];
  const int bid = blockIdx.x;
  const int tid = threadIdx.x;
  if (bid < 8192) {
    size_t i = ((size_t)bid * 256 + tid) * 8;
    f32x4 a = *(const f32x4*)(x + i);
    f32x4 b = *(const f32x4*)(x + i + 4);
    u16x8 o;
    o[0] = f2bf(a[0]); o[1] = f2bf(a[1]); o[2] = f2bf(a[2]); o[3] = f2bf(a[3]);
    o[4] = f2bf(b[0]); o[5] = f2bf(b[1]); o[6] = f2bf(b[2]); o[7] = f2bf(b[3]);
    *(u16x8*)(xb + i) = o;
    return;
  }
  if (bid < 12288) {
    const int t = (bid - 8192) >> 10;
    const int sub = (bid - 8192) & 1023;
    const float* in = (t == 0) ? Wq : (t == 1) ? Wk : (t == 2) ? Wv : Wo;
    u16* out = (t == 0) ? WqT : (t == 1) ? WkT : (t == 2) ? WvT : WoT;
    const int bx = (sub & 31) * 32, by = (sub >> 5) * 32;
    const int tx = tid & 31, ty = tid >> 5;  // ty 0..7
    for (int i2 = ty; i2 < 32; i2 += 8)
      tile[i2][tx] = in[(size_t)(by + i2) * 1024 + bx + tx];
    __syncthreads();
    for (int i2 = ty; i2 < 32; i2 += 8)
      out[(size_t)(bx + i2) * 1024 + by + tx] = f2bf(tile[tx][i2]);
    return;
  }
  {
    int idx = (bid - 12288) * 256 + tid;  // 16384
    WaT[idx] = f2bf(Wa[(idx & 1023) * 16 + (idx >> 10)]);
  }
}

// ---------------------------------------------------------------------------
// a_proj (MFMA skinny GEMM): abuf = sigmoid(xb @ Wa + ba + 2), M=16384 N=16
// ---------------------------------------------------------------------------
__global__ __launch_bounds__(256)
void a_proj(const u16* __restrict__ xb, const u16* __restrict__ WaT,
            const float* __restrict__ ba, float* __restrict__ abuf) {
  __shared__ __align__(16) u16 As[256 * 32];
  __shared__ __align__(16) u16 Bs[16 * 32];
  const int tid = threadIdx.x;
  const int brow = blockIdx.x * 256;
  const int l = tid & 63, wid = tid >> 6;
  const int la = l & 15, kb8 = (l >> 4) * 8;
  const int sr = tid >> 2, se = (tid & 3) * 8;

  f32x4 acc[4];
#pragma unroll
  for (int mi = 0; mi < 4; ++mi) acc[mi] = (f32x4){0.f, 0.f, 0.f, 0.f};

  for (int kt = 0; kt < 32; ++kt) {
    const int k0 = kt * 32;
    __syncthreads();
#pragma unroll
    for (int i = 0; i < 4; ++i)
      gl2lds16(xb + (size_t)(brow + i * 64 + sr) * DD + k0 + se,
               &As[i * 2048 + wid * 512]);
    if (wid == 0)
      gl2lds16(WaT + (size_t)(l >> 2) * DD + k0 + (l & 3) * 8, &Bs[0]);
    __syncthreads();
    union { u16x8 u; bf16x8 b; } cvb;
    cvb.u = *(const u16x8*)&Bs[la * 32 + kb8];
#pragma unroll
    for (int mi = 0; mi < 4; ++mi) {
      union { u16x8 u; bf16x8 b; } cva;
      cva.u = *(const u16x8*)&As[(wid * 64 + mi * 16 + la) * 32 + kb8];
      acc[mi] = __builtin_amdgcn_mfma_f32_16x16x32_bf16(cva.b, cvb.b, acc[mi], 0, 0, 0);
    }
  }
  const float bav = ba[la];
#pragma unroll
  for (int mi = 0; mi < 4; ++mi)
#pragma unroll
    for (int rr = 0; rr < 4; ++rr) {
      int row = brow + wid * 64 + mi * 16 + ((l >> 4) << 2) + rr;
      float t = acc[mi][rr] + bav + 2.0f;
      abuf[(size_t)row * HH + la] = 1.f / (1.f + __expf(-t));
    }
}

// ---------------------------------------------------------------------------
// bf16 MFMA GEMM, minimal-barrier double-buffer, STAGE-FIRST (r7-verified):
// 256x256 tile, BK=64, 8 waves, ONE vmcnt(0)+s_barrier per K-tile.
// B-fragments read once, reused across both M-halves. T2 swizzle via
// pre-swizzled global source. setprio(1) around MFMA clusters.
// ROUTE=1: fused QKV (N=3072) routed bf16 epilogue w/ elu+1 on q/k.
// ROUTE=0: f32 output.  NCT = col-tile count.
// ---------------------------------------------------------------------------
template<int NCT, int ROUTE>
__global__ __launch_bounds__(512)
void gemm_db(const u16* __restrict__ A, const u16* __restrict__ Bt,
             void* __restrict__ Cout) {
  __shared__ __align__(16) u16 As[2][256 * 64];
  __shared__ __align__(16) u16 Bs[2][256 * 64];
  const int tid = threadIdx.x;
  const int nwg = gridDim.x;
  const int f = blockIdx.x;
  const int swz = (f & 7) * (nwg >> 3) + (f >> 3);
  const int brow = (swz / NCT) * 256;
  const int bcol = (swz % NCT) * 256;
  const int l = tid & 63;
  const int wid = tid >> 6;       // 0..7
  const int wr = wid >> 2;        // 0..1  (M half)
  const int wc = wid & 3;         // 0..3  (N quarter)
  const int la = l & 15, kb8 = (l >> 4) * 8;
  const int K = 1024;
  const int srow = l >> 3;                       // row within 8-row chunk
  const int scol = ((l & 7) * 8) ^ (srow << 3);  // pre-swizzled global col (u16)
  const int ldso = (wid * 2) * 512;              // wave chunk base (u16) within half

  f32x4 acc[8][4];
#pragma unroll
  for (int i = 0; i < 8; ++i)
#pragma unroll
    for (int j = 0; j < 4; ++j) acc[i][j] = (f32x4){0.f, 0.f, 0.f, 0.f};

  // prologue: stage K-tile 0 into buf 0
#pragma unroll
  for (int h = 0; h < 2; ++h)
#pragma unroll
    for (int j = 0; j < 2; ++j) {
      const int r0 = h * 128 + (wid * 2 + j) * 8 + srow;
      gl2lds16(A  + (size_t)(brow + r0) * K + scol, &As[0][h * 8192 + ldso + j * 512]);
      gl2lds16(Bt + (size_t)(bcol + r0) * K + scol, &Bs[0][h * 8192 + ldso + j * 512]);
    }
  asm volatile("s_waitcnt vmcnt(0)" ::: "memory");
  __builtin_amdgcn_s_barrier();

  const int NKT = K / 64;
  for (int kt = 0; kt < NKT; ++kt) {
    const u16* lA = As[kt & 1];
    const u16* lB = Bs[kt & 1];
    u16* nA = As[(kt + 1) & 1];
    u16* nB = Bs[(kt + 1) & 1];
    const int knext = (kt + 1) * 64;
    const bool more = (kt + 1 < NKT);

    // stage next K-tile FIRST: the whole tile's compute covers the latency.
    if (more) {
#pragma unroll
      for (int h = 0; h < 2; ++h)
#pragma unroll
        for (int j = 0; j < 2; ++j) {
          const int r0 = h * 128 + (wid * 2 + j) * 8 + srow;
          gl2lds16(A  + (size_t)(brow + r0) * K + knext + scol,
                   nA + h * 8192 + ldso + j * 512);
          gl2lds16(Bt + (size_t)(bcol + r0) * K + knext + scol,
                   nB + h * 8192 + ldso + j * 512);
        }
    }

    bf16x8 af[4][2], bfr[4][2];
#pragma unroll
    for (int m2 = 0; m2 < 4; ++m2)
#pragma unroll
      for (int kk = 0; kk < 2; ++kk)
        af[m2][kk] = ldsw(lA, wr * 128 + m2 * 16 + la, kk * 32 + kb8);
#pragma unroll
    for (int n2 = 0; n2 < 4; ++n2)
#pragma unroll
      for (int kk = 0; kk < 2; ++kk)
        bfr[n2][kk] = ldsw(lB, wc * 64 + n2 * 16 + la, kk * 32 + kb8);

    __builtin_amdgcn_s_setprio(1);
#pragma unroll
    for (int m2 = 0; m2 < 4; ++m2)
#pragma unroll
      for (int n2 = 0; n2 < 4; ++n2)
#pragma unroll
        for (int kk = 0; kk < 2; ++kk)
          acc[m2][n2] = __builtin_amdgcn_mfma_f32_16x16x32_bf16(
              af[m2][kk], bfr[n2][kk], acc[m2][n2], 0, 0, 0);
    __builtin_amdgcn_s_setprio(0);

    // fragments: M-half 1 (reuse af regs; bfr persists)
#pragma unroll
    for (int m2 = 0; m2 < 4; ++m2)
#pragma unroll
      for (int kk = 0; kk < 2; ++kk)
        af[m2][kk] = ldsw(lA, wr * 128 + 64 + m2 * 16 + la, kk * 32 + kb8);

    __builtin_amdgcn_s_setprio(1);
#pragma unroll
    for (int m2 = 0; m2 < 4; ++m2)
#pragma unroll
      for (int n2 = 0; n2 < 4; ++n2)
#pragma unroll
        for (int kk = 0; kk < 2; ++kk)
          acc[4 + m2][n2] = __builtin_amdgcn_mfma_f32_16x16x32_bf16(
              af[m2][kk], bfr[n2][kk], acc[4 + m2][n2], 0, 0, 0);
    __builtin_amdgcn_s_setprio(0);

    if (more) {
      asm volatile("s_waitcnt vmcnt(0)" ::: "memory");
      __builtin_amdgcn_s_barrier();
    }
  }

  const int wrow = wr * 128, wcol = wc * 64;
  if (ROUTE) {
    u16* base = (u16*)Cout + (size_t)(bcol >> 10) * ((size_t)MM * 1024);
    const bool act = (bcol < 2048);
#pragma unroll
    for (int mi = 0; mi < 8; ++mi)
#pragma unroll
      for (int ni = 0; ni < 4; ++ni)
#pragma unroll
        for (int rr = 0; rr < 4; ++rr) {
          int row = brow + wrow + mi * 16 + ((l >> 4) << 2) + rr;
          int c2 = (bcol & 1023) + wcol + ni * 16 + la;
          float v = acc[mi][ni][rr];
          if (act) v = v > 0.f ? v + 1.f : __expf(v);
          base[(size_t)row * 1024 + c2] = f2bf(v);
        }
  } else {
#pragma unroll
    for (int mi = 0; mi < 8; ++mi)
#pragma unroll
      for (int ni = 0; ni < 4; ++ni)
#pragma unroll
        for (int rr = 0; rr < 4; ++rr) {
          int row = brow + wrow + mi * 16 + ((l >> 4) << 2) + rr;
          int col = bcol + wcol + ni * 16 + la;
          ((float*)Cout)[(size_t)row * 1024 + col] = acc[mi][ni][rr];
        }
  }
}

// ---------------------------------------------------------------------------
// FUSED Kernel A + scan level 1: one block owns one group of GCH=8 chunks.
// ---------------------------------------------------------------------------
__global__ __launch_bounds__(256)
void chunk_local_scan(const u16* __restrict__ kb, const u16* __restrict__ vb,
                      const float* __restrict__ abuf,
                      u16* __restrict__ Sbuf, float* __restrict__ zbuf,
                      float* __restrict__ cAbuf,
                      float* __restrict__ GAgg, float* __restrict__ zGAgg,
                      float* __restrict__ dpbuf) {
  const int g = blockIdx.x & (NGRP - 1);
  const int bh = blockIdx.x >> 4;
  const int h = bh & (HH - 1);
  const int b = bh >> 4;
  __shared__ __align__(16) u16 KT[64 * 64];   // KT[dk][t] = w_t*k (swizzled)
  __shared__ __align__(16) u16 VTl[64 * 64];  // VTl[dv][t] (swizzled)
  __shared__ float wsh[64];
  __shared__ float dchs;
  const int tid = threadIdx.x;
  const int r = tid >> 2, e = (tid & 3) * 16;
  const int l = tid & 63, w = tid >> 6;
  const int kb8 = (l >> 4) << 3, la = l & 15;
  const int dw = 16 * w + ((l >> 4) << 2);
  const int dkz = tid >> 2, tqz = (tid & 3) * 16, swkz = (dkz & 7) << 3;

  f32x4 run[4];
#pragma unroll
  for (int ni = 0; ni < 4; ++ni) run[ni] = (f32x4){0.f, 0.f, 0.f, 0.f};
  float zrun = 0.f;
  float rp = 1.f;

  for (int i = 0; i < GCH; ++i) {
    const int c = g * GCH + i;
    const int blkc = bh * CCHUNK + c;
    const int rowbase = b * NNLEN + c * LCH;

    const u16* kp = kb + (size_t)(rowbase + r) * PP + h * DH + e;
    const u16* vp = vb + (size_t)(rowbase + r) * PP + h * DH + e;
    u16x8 k0 = *(const u16x8*)kp, k1 = *(const u16x8*)(kp + 8);
    u16x8 v0 = *(const u16x8*)vp, v1 = *(const u16x8*)(vp + 8);

    if (tid < 64) {
      float v = __logf(abuf[(size_t)(rowbase + tid) * HH + h]);
#pragma unroll
      for (int d = 1; d < 64; d <<= 1) {
        float u = __shfl_up(v, d);
        if (tid >= d) v += u;
      }
      cAbuf[(size_t)blkc * 64 + tid] = v;
      float tot = __shfl(v, 63);
      wsh[tid] = __expf(tot - v);
      if (tid == 0) dchs = __expf(tot);
    }
    __syncthreads();                    // wsh/dchs ready

    {
      const float wt = wsh[r];
#pragma unroll
      for (int j = 0; j < 8; ++j) {
        int d0 = e + j, d1 = e + 8 + j;
        KT[d0 * 64 + (r ^ ((d0 & 7) << 3))] = f2bf(bf2f(k0[j]) * wt);
        KT[d1 * 64 + (r ^ ((d1 & 7) << 3))] = f2bf(bf2f(k1[j]) * wt);
        VTl[d0 * 64 + (r ^ ((d0 & 7) << 3))] = v0[j];
        VTl[d1 * 64 + (r ^ ((d1 & 7) << 3))] = v1[j];
      }
    }
    __syncthreads();                    // KT/VTl ready
    const float dch = dchs;

    f32x4 s[4];
#pragma unroll
    for (int ni = 0; ni < 4; ++ni) s[ni] = (f32x4){0.f, 0.f, 0.f, 0.f};
#pragma unroll
    for (int kk = 0; kk < 2; ++kk) {
      bf16x8 av = ldsw(VTl, 16 * w + la, kk * 32 + kb8);
#pragma unroll
      for (int ni = 0; ni < 4; ++ni)
        s[ni] = __builtin_amdgcn_mfma_f32_16x16x32_bf16(
            av, ldsw(KT, 16 * ni + la, kk * 32 + kb8), s[ni], 0, 0, 0);
    }

    // write within-group prefix (state BEFORE this chunk), then update
    u16* Sc = Sbuf + (size_t)blkc * 4096;
#pragma unroll
    for (int ni = 0; ni < 4; ++ni)
#pragma unroll
      for (int rr = 0; rr < 4; ++rr)
        Sc[(dw + rr) * 64 + 16 * ni + la] = f2bf(run[ni][rr]);
#pragma unroll
    for (int ni = 0; ni < 4; ++ni)
#pragma unroll
      for (int rr = 0; rr < 4; ++rr)
        run[ni][rr] = dch * run[ni][rr] + s[ni][rr];

    // z: zp[dk] = sum_t w_t k[t][dk]
    {
      float zp = 0.f;
#pragma unroll
      for (int i2 = 0; i2 < 16; ++i2)
        zp += bf2f(KT[dkz * 64 + ((tqz + i2) ^ swkz)]);
      zp += __shfl_xor(zp, 1);
      zp += __shfl_xor(zp, 2);
      if ((tid & 3) == 0) zbuf[(size_t)blkc * 64 + dkz] = zrun;
      zrun = dch * zrun + zp;
    }
    if (tid == 0) dpbuf[blkc] = rp;
    rp *= dch;
    __syncthreads();                    // protect wsh/dchs/KT for next iter
  }

  // group aggregates
  float* Ga = GAgg + ((size_t)bh * NGRP + g) * 4096;
#pragma unroll
  for (int ni = 0; ni < 4; ++ni)
#pragma unroll
    for (int rr = 0; rr < 4; ++rr)
      Ga[(dw + rr) * 64 + 16 * ni + la] = run[ni][rr];
  if ((tid & 3) == 0)
    zGAgg[((size_t)bh * NGRP + g) * 64 + dkz] = zrun;
}

// ---------------------------------------------------------------------------
// Scan level 2: across the 16 group aggregates. GAgg(f32) -> GBeg (bf16).
// z in place (f32).
// ---------------------------------------------------------------------------
__global__ __launch_bounds__(1024)
void scan_top(const float* __restrict__ GAgg, u16* __restrict__ GBeg,
              float* __restrict__ zGAgg, const float* __restrict__ cAbuf) {
  const int bh = blockIdx.x;
  const size_t cb = (size_t)bh * CCHUNK;
  __shared__ float Dsh[NGRP];
  if (threadIdx.x < NGRP) {
    float s = 0.f;
#pragma unroll
    for (int i = 0; i < GCH; ++i)
      s += cAbuf[(cb + threadIdx.x * GCH + i) * 64 + 63];
    Dsh[threadIdx.x] = __expf(s);
  }
  __syncthreads();
  const int elem = threadIdx.x * 4;
  const float* base = GAgg + (size_t)bh * NGRP * 4096;
  u16* gb = GBeg + (size_t)bh * NGRP * 4096;
  f32x4 run = (f32x4){0.f, 0.f, 0.f, 0.f};
  f32x4 cur = *(const f32x4*)&base[elem];
#pragma unroll
  for (int gg = 0; gg < NGRP; ++gg) {
    f32x4 nxt;
    if (gg + 1 < NGRP) nxt = *(const f32x4*)&base[(gg + 1) * 4096 + elem];
    u16x4 o;
#pragma unroll
    for (int jj = 0; jj < 4; ++jj) o[jj] = f2bf(run[jj]);
    *(u16x4*)&gb[gg * 4096 + elem] = o;
    const float D = Dsh[gg];
#pragma unroll
    for (int jj = 0; jj < 4; ++jj) run[jj] = D * run[jj] + cur[jj];
    cur = nxt;
  }
  if (threadIdx.x < 64) {
    float* zb = zGAgg + (size_t)bh * NGRP * 64;
    float zr = 0.f;
#pragma unroll
    for (int gg = 0; gg < NGRP; ++gg) {
      float a = zb[gg * 64 + threadIdx.x];
      zb[gg * 64 + threadIdx.x] = zr;
      zr = Dsh[gg] * zr + a;
    }
  }
}

// ---------------------------------------------------------------------------
// Kernel C (MFMA): per-chunk output.
// S0 = prefix(bf16) + dp * Gbegin(bf16);  z0 = zprefix + dp * zGbegin
// qz from register fragments; P reuses dead Ke tile; 33KB LDS.
// ---------------------------------------------------------------------------
__global__ __launch_bounds__(256)
void chunk_out(u16* __restrict__ qb, const u16* __restrict__ kb,
               const u16* __restrict__ vb, const u16* __restrict__ Sbuf,
               const float* __restrict__ zbuf, const float* __restrict__ cAbuf,
               const u16* __restrict__ GBeg, const float* __restrict__ zGAgg,
               const float* __restrict__ dpbuf) {
  const int blk = blockIdx.x;
  const int c = blk & (CCHUNK - 1);
  const int h = (blk >> 7) & (HH - 1);
  const int b = blk >> 11;
  const int bh = blk >> 7;
  const int g = c >> 3;
  const int rowbase = b * NNLEN + c * LCH;

  __shared__ __align__(16) u16 Qs[64 * 64];
  __shared__ __align__(16) u16 Ke[64 * 64];   // Ke, later reused as P tile
  __shared__ __align__(16) u16 VT[64 * 64];
  __shared__ __align__(16) u16 STs[64 * 64];
  __shared__ float cAsh[64], zsh[64], denP[64], qzs[64];

  const int tid = threadIdx.x;
  const int r = tid >> 2, e = (tid & 3) * 16;
  const float dp = dpbuf[blk];

  const u16* qp = qb + (size_t)(rowbase + r) * PP + h * DH + e;
  const u16* kp = kb + (size_t)(rowbase + r) * PP + h * DH + e;
  const u16* vp = vb + (size_t)(rowbase + r) * PP + h * DH + e;
  u16x8 q0 = *(const u16x8*)qp, q1 = *(const u16x8*)(qp + 8);
  u16x8 k0 = *(const u16x8*)kp, k1 = *(const u16x8*)(kp + 8);
  u16x8 v0 = *(const u16x8*)vp, v1 = *(const u16x8*)(vp + 8);
  const u16* sp = Sbuf + (size_t)blk * 4096 + r * 64 + e;
  u16x8 p0 = *(const u16x8*)sp, p1 = *(const u16x8*)(sp + 8);
  const u16* gp = GBeg + ((size_t)bh * NGRP + g) * 4096 + r * 64 + e;
  u16x8 gb0 = *(const u16x8*)gp, gb1 = *(const u16x8*)(gp + 8);
  if (tid < 64) {
    cAsh[tid] = cAbuf[(size_t)blk * 64 + tid];
    zsh[tid] = zbuf[(size_t)blk * 64 + tid]
             + dp * zGAgg[((size_t)bh * NGRP + g) * 64 + tid];
  }
  __syncthreads();

  {
    const float c0c = cAsh[31];
    const int sw = (r & 7) << 3;
    const float qsc = __expf(cAsh[r] - c0c);
    const float ksc = __expf(c0c - cAsh[r]);
    const float ssc = __expf(c0c);
    u16x8 t0, t1, u0, u1, w0, w1;
#pragma unroll
    for (int j = 0; j < 8; ++j) {
      t0[j] = f2bf(bf2f(q0[j]) * qsc);
      t1[j] = f2bf(bf2f(q1[j]) * qsc);
      u0[j] = f2bf(bf2f(k0[j]) * ksc);
      u1[j] = f2bf(bf2f(k1[j]) * ksc);
    }
#pragma unroll
    for (int j = 0; j < 8; ++j) {
      w0[j] = f2bf((bf2f(p0[j]) + dp * bf2f(gb0[j])) * ssc);
      w1[j] = f2bf((bf2f(p1[j]) + dp * bf2f(gb1[j])) * ssc);
    }
    *(u16x8*)&Qs[r * 64 + (e ^ sw)] = t0;
    *(u16x8*)&Qs[r * 64 + ((e + 8) ^ sw)] = t1;
    *(u16x8*)&Ke[r * 64 + (e ^ sw)] = u0;
    *(u16x8*)&Ke[r * 64 + ((e + 8) ^ sw)] = u1;
    *(u16x8*)&STs[r * 64 + (e ^ sw)] = w0;
    *(u16x8*)&STs[r * 64 + ((e + 8) ^ sw)] = w1;
#pragma unroll
    for (int j = 0; j < 8; ++j) {
      int d0 = e + j, d1 = e + 8 + j;
      VT[d0 * 64 + (r ^ ((d0 & 7) << 3))] = v0[j];
      VT[d1 * 64 + (r ^ ((d1 & 7) << 3))] = v1[j];
    }
    if (tid < 64) zsh[tid] *= ssc;
  }
  __syncthreads();

  const int l = tid & 63, w = tid >> 6;
  const int kb8 = (l >> 4) << 3, la = l & 15;

  // --- MFMA1: P = Qe @ Ke^T ---
  bf16x8 aq[2];
  f32x4 p[4];
#pragma unroll
  for (int ni = 0; ni < 4; ++ni) p[ni] = (f32x4){0.f, 0.f, 0.f, 0.f};
#pragma unroll
  for (int kk = 0; kk < 2; ++kk) {
    aq[kk] = ldsw(Qs, 16 * w + la, kk * 32 + kb8);
#pragma unroll
    for (int ni = 0; ni < 4; ++ni)
      p[ni] = __builtin_amdgcn_mfma_f32_16x16x32_bf16(
          aq[kk], ldsw(Ke, 16 * ni + la, kk * 32 + kb8), p[ni], 0, 0, 0);
  }

  const int tw = 16 * w + ((l >> 4) << 2);
  float rsum[4] = {0.f, 0.f, 0.f, 0.f};
#pragma unroll
  for (int ni = 0; ni < 4; ++ni)
#pragma unroll
    for (int rr = 0; rr < 4; ++rr) {
      int s = 16 * ni + la, t = tw + rr;
      float v = (s <= t) ? p[ni][rr] : 0.f;
      p[ni][rr] = v;
      rsum[rr] += v;
    }
#pragma unroll
  for (int d = 1; d < 16; d <<= 1)
#pragma unroll
    for (int rr = 0; rr < 4; ++rr) rsum[rr] += __shfl_xor(rsum[rr], d);
  if (la == 0)
#pragma unroll
    for (int rr = 0; rr < 4; ++rr) denP[tw + rr] = rsum[rr];

  // qz[row] = Qe[row] . z0e from register fragments
  {
    float qzp = 0.f;
#pragma unroll
    for (int kk = 0; kk < 2; ++kk)
#pragma unroll
      for (int j = 0; j < 8; ++j) {
        union { bf16x8 b; u16x8 u; } cv; cv.b = aq[kk];
        qzp += bf2f(cv.u[j]) * zsh[kk * 32 + kb8 + j];
      }
    qzp += __shfl_xor(qzp, 16);
    qzp += __shfl_xor(qzp, 32);
    if (l < 16) qzs[16 * w + la] = qzp;
  }
  __syncthreads();   // all waves done reading Qs/Ke -> Ke reusable as P

  // write P into (dead) Ke tile, swizzled
#pragma unroll
  for (int ni = 0; ni < 4; ++ni)
#pragma unroll
    for (int rr = 0; rr < 4; ++rr) {
      int t = tw + rr, s = 16 * ni + la;
      Ke[t * 64 + (s ^ ((t & 7) << 3))] = f2bf(p[ni][rr]);
    }
  __syncthreads();

  // --- MFMA2: O = P@V + Qe@S0e^T ---
  f32x4 o[4];
#pragma unroll
  for (int ni = 0; ni < 4; ++ni) o[ni] = (f32x4){0.f, 0.f, 0.f, 0.f};
#pragma unroll
  for (int kk = 0; kk < 2; ++kk) {
    bf16x8 ap = ldsw(Ke, 16 * w + la, kk * 32 + kb8);
#pragma unroll
    for (int ni = 0; ni < 4; ++ni)
      o[ni] = __builtin_amdgcn_mfma_f32_16x16x32_bf16(
          ap, ldsw(VT, 16 * ni + la, kk * 32 + kb8), o[ni], 0, 0, 0);
  }
#pragma unroll
  for (int kk = 0; kk < 2; ++kk)
#pragma unroll
    for (int ni = 0; ni < 4; ++ni)
      o[ni] = __builtin_amdgcn_mfma_f32_16x16x32_bf16(
          aq[kk], ldsw(STs, 16 * ni + la, kk * 32 + kb8), o[ni], 0, 0, 0);

  float dn[4];
#pragma unroll
  for (int rr = 0; rr < 4; ++rr) dn[rr] = qzs[tw + rr] + denP[tw + rr] + EPSV;
#pragma unroll
  for (int ni = 0; ni < 4; ++ni)
#pragma unroll
    for (int rr = 0; rr < 4; ++rr) {
      int t = tw + rr, dv = 16 * ni + la;
      qb[(size_t)(rowbase + t) * PP + h * DH + dv] = f2bf(o[ni][rr] / dn[rr]);
    }
}

// ---------------------------------------------------------------------------
extern "C" void kernel_launch(void* const* d_in, const int* in_sizes, int n_in,
                              void* d_out, int out_size, void* d_ws, size_t ws_size,
                              hipStream_t stream) {
  const float* x  = (const float*)d_in[0];
  const float* Wq = (const float*)d_in[1];
  const float* Wk = (const float*)d_in[2];
  const float* Wv = (const float*)d_in[3];
  const float* Wo = (const float*)d_in[4];
  const float* Wa = (const float*)d_in[5];
  const float* ba = (const float*)d_in[6];

  char* ws = (char*)d_ws;
  size_t off = 0;
  auto carve = [&](size_t bytes) {
    void* p = ws + off;
    off += (bytes + 255) & ~(size_t)255;
    return p;
  };
  u16* xb   = (u16*)carve((size_t)MM * DD * 2);
  u16* WqT  = (u16*)carve((size_t)PP * DD * 2);  // WqT/WkT/WvT contiguous
  u16* WkT  = (u16*)carve((size_t)PP * DD * 2);
  u16* WvT  = (u16*)carve((size_t)PP * DD * 2);
  u16* WoT  = (u16*)carve((size_t)DD * PP * 2);
  u16* WaT  = (u16*)carve((size_t)HH * DD * 2);
  u16* qb   = (u16*)carve((size_t)MM * PP * 2);  // qb/kb/vb contiguous
  u16* kb   = (u16*)carve((size_t)MM * PP * 2);
  u16* vb   = (u16*)carve((size_t)MM * PP * 2);
  float* abuf  = (float*)carve((size_t)MM * HH * 4);
  u16*  Sbuf   = (u16*)carve((size_t)BBATCH * HH * CCHUNK * 4096 * 2);
  float* zbuf  = (float*)carve((size_t)BBATCH * HH * CCHUNK * 64 * 4);
  float* cAbuf = (float*)carve((size_t)BBATCH * HH * CCHUNK * 64 * 4);
  float* GAgg  = (float*)carve((size_t)BBATCH * HH * NGRP * 4096 * 4);
  u16*  GBeg   = (u16*)carve((size_t)BBATCH * HH * NGRP * 4096 * 2);
  float* zGAgg = (float*)carve((size_t)BBATCH * HH * NGRP * 64 * 4);
  float* dpbuf = (float*)carve((size_t)BBATCH * HH * CCHUNK * 4);

  prep_all<<<12352, 256, 0, stream>>>(x, xb, Wq, WqT, Wk, WkT, Wv, WvT,
                                      Wo, WoT, Wa, WaT);
  a_proj<<<MM / 256, 256, 0, stream>>>(xb, WaT, ba, abuf);

  // fused QKV: M=16384, N=3072 (WqT/WkT/WvT contiguous), routed epilogue
  gemm_db<12, 1><<<(MM / 256) * 12, 512, 0, stream>>>(xb, WqT, qb);

  chunk_local_scan<<<BBATCH * HH * NGRP, 256, 0, stream>>>(
      kb, vb, abuf, Sbuf, zbuf, cAbuf, GAgg, zGAgg, dpbuf);
  scan_top<<<BBATCH * HH, 1024, 0, stream>>>(GAgg, GBeg, zGAgg, cAbuf);
  chunk_out<<<BBATCH * HH * CCHUNK, 256, 0, stream>>>(qb, kb, vb, Sbuf, zbuf, cAbuf,
                                                      GBeg, zGAgg, dpbuf);

  gemm_db<4, 0><<<(MM / 256) * 4, 512, 0, stream>>>(qb, WoT, (float*)d_out);
}